// Round 14
// baseline (531.307 us; speedup 1.0000x reference)
//
#include <hip/hip_runtime.h>

#define Hc 96
#define Wc 96
#define Cc 256
#define Bc 4
#define KK 9
#define HW 9216          // Hc*Wc
#define PIX 36864        // Bc*HW
#define CK 2304          // Cc*KK

typedef _Float16 f16;
typedef __attribute__((ext_vector_type(4))) _Float16 f16x4;
typedef __attribute__((ext_vector_type(8))) _Float16 f16x8;
typedef __attribute__((ext_vector_type(4))) float f32x4;

__device__ __forceinline__ int clampi(int v, int lo, int hi) {
    return v < lo ? lo : (v > hi ? hi : v);
}

#define SB() __builtin_amdgcn_sched_barrier(0)

// ---------- prep: NCHW fp32 -> NHWC f16 (layer 0 input) ----------
__global__ __launch_bounds__(256) void nhwc_prep_kernel(
    const float* __restrict__ x0, f16* __restrict__ x16)
{
    __shared__ float st[64][65];
    const int hw0 = blockIdx.x * 64;
    const int c0  = blockIdx.y * 64;
    const int b   = blockIdx.z;
    const int tid = threadIdx.x;
    const int a = tid & 63, r = tid >> 6;
#pragma unroll
    for (int it = 0; it < 16; ++it) {
        int cl = it * 4 + r;
        st[cl][a] = x0[((size_t)(b * Cc + c0 + cl)) * HW + hw0 + a];
    }
    __syncthreads();
#pragma unroll
    for (int it = 0; it < 16; ++it) {
        int hwl = it * 4 + r;
        x16[((size_t)(b * HW + hw0 + hwl)) * Cc + c0 + a] = (f16)st[a][hwl];
    }
}

// wT2[(k*256 + o)*256 + c] = (f16) w[(o*256 + c)*9 + k]
__global__ __launch_bounds__(256) void transpose_w_kernel(
    const float* __restrict__ w, f16* __restrict__ wT2)
{
    int u = blockIdx.x * 256 + threadIdx.x;   // < 589824
    int c = u & 255, o = (u >> 8) & 255, k = u >> 16;
    wT2[u] = (f16)w[(o * Cc + c) * KK + k];
}

// woffT[(k*32 + j)*256 + c] = (f16) w_off[(j*256 + c)*9 + k], rows 18..31 = 0
__global__ __launch_bounds__(256) void woff_prep_kernel(
    const float* __restrict__ w_off, f16* __restrict__ woffT)
{
    int u = blockIdx.x * 256 + threadIdx.x;   // < 73728
    int c = u & 255, j = (u >> 8) & 31, k = u >> 13;
    float v = (j < 18) ? w_off[((size_t)j * Cc + c) * KK + k] : 0.f;
    woffT[u] = (f16)v;
}

// bilinear decomposition for one tap -> idx4/wt4 (tap-major layout)
__device__ __forceinline__ void store_tap(int k, int h, int w, float offy, float offx,
    int p, int4* __restrict__ idx4t, float4* __restrict__ wt4t)
{
    float py = (float)(h - 1 + k / 3) + offy;
    float px = (float)(w - 1 + k % 3) + offx;
    float y0f = floorf(py), x0f = floorf(px);
    float wy = py - y0f, wx = px - x0f;
    int iy0 = (int)y0f, ix0 = (int)x0f;
    float vy0 = (y0f >= 0.f && y0f <= 95.f) ? 1.f : 0.f;
    float vy1 = (y0f + 1.f >= 0.f && y0f + 1.f <= 95.f) ? 1.f : 0.f;
    float vx0 = (x0f >= 0.f && x0f <= 95.f) ? 1.f : 0.f;
    float vx1 = (x0f + 1.f >= 0.f && x0f + 1.f <= 95.f) ? 1.f : 0.f;
    int cy0 = clampi(iy0, 0, 95), cy1 = clampi(iy0 + 1, 0, 95);
    int cx0 = clampi(ix0, 0, 95), cx1 = clampi(ix0 + 1, 0, 95);
    idx4t[(size_t)k * PIX + p] = make_int4(cy0 * Wc + cx0, cy0 * Wc + cx1,
                                           cy1 * Wc + cx0, cy1 * Wc + cx1);
    wt4t[(size_t)k * PIX + p] = make_float4((1.f - wy) * (1.f - wx) * vy0 * vx0,
                                            (1.f - wy) * wx * vy0 * vx1,
                                            wy * (1.f - wx) * vy1 * vx0,
                                            wy * wx * vy1 * vx1);
}

// Offset conv as f16 MFMA GEMM, reg-staged double-buffered pipeline.
// Block: 256 threads (4 waves = 2M x 2N), tile 32 out x 64 pixels. 576 blocks.
__global__ __launch_bounds__(256) void conv_off_mfma_kernel(
    const f16* __restrict__ x16, const f16* __restrict__ woffT,
    const float* __restrict__ b_off,
    int4* __restrict__ idx4t, float4* __restrict__ wt4t)
{
    __shared__ __align__(16) f16 s_a[2][32 * 32];   // 2 x 2KB
    __shared__ __align__(16) f16 s_b[2][64 * 32];   // 2 x 4KB
    const int bid = blockIdx.x;
    const int swz = (bid & 7) * 72 + (bid >> 3);    // 576 blocks, XCD-chunked
    const int p0 = swz * 64;
    const int imgb = (p0 / HW) * HW;
    const int tid = threadIdx.x, lane = tid & 63, wid = tid >> 6;
    const int wm = wid >> 1, wn = wid & 1;
    const int qa = ((lane >> 4) ^ ((lane >> 1) & 3)) * 8;
    // A-stage mapping: row/col-quad
    const int arow = tid >> 3, acb = tid & 7;
    const int adst = arow * 32 + (((acb >> 1) ^ ((arow >> 1) & 3)) * 8) + (acb & 1) * 4;
    // B-stage mapping: 4 lanes per pixel (coalesced 64B), pixel ps, group cg
    const int ps = tid >> 2, cg = tid & 3;
    const int bdst = ps * 32 + ((cg ^ ((ps >> 1) & 3)) * 8);
    const int hwp = p0 + ps - imgb;
    const int hp = hwp / Wc, wp = hwp - hp * Wc;

#define CLOAD(q, aD, bD) do {                                                  \
    int p2_ = (q) > 71 ? 71 : (q);                                             \
    int k2_ = p2_ >> 3, c2_ = p2_ & 7;                                         \
    int ky_ = k2_ / 3, kx_ = k2_ - ky_ * 3;                                    \
    int yy_ = hp + ky_ - 1, xx_ = wp + kx_ - 1;                                \
    bool v_ = (yy_ >= 0 && yy_ < Hc && xx_ >= 0 && xx_ < Wc);                  \
    aD = *(const f16x4*)(woffT + ((size_t)(k2_ * 32 + arow)) * Cc + c2_ * 32 + acb * 4); \
    f16x8 t_ = {0, 0, 0, 0, 0, 0, 0, 0};                                       \
    if (v_) t_ = *(const f16x8*)(x16 + ((size_t)(imgb + yy_ * Wc + xx_)) * Cc + c2_ * 32 + cg * 8); \
    bD = t_;                                                                   \
} while (0)

    f32x4 acc[2];
    acc[0] = (f32x4){0.f, 0.f, 0.f, 0.f};
    acc[1] = (f32x4){0.f, 0.f, 0.f, 0.f};

    f16x4 aR0, aR1;
    f16x8 bR0, bR1;
    // prologue: phase 0 -> slot0 -> s[0]; phase 1 -> slot1 (held in regs)
    CLOAD(0, aR0, bR0);
    CLOAD(1, aR1, bR1);
    *(f16x4*)&s_a[0][adst] = aR0;
    *(f16x8*)&s_b[0][bdst] = bR0;
    asm volatile("s_waitcnt lgkmcnt(0)" ::: "memory"); SB();
    __builtin_amdgcn_s_barrier(); SB();

#define CBODY(p, aCur, bCur, aNxt, bNxt, bc, bn) do {                          \
    f16x8 af = *(const f16x8*)&s_a[bc][(wm * 16 + (lane & 15)) * 32 + qa];     \
    f16x8 bf0 = *(const f16x8*)&s_b[bc][(wn * 32 + (lane & 15)) * 32 + qa];    \
    f16x8 bf1 = *(const f16x8*)&s_b[bc][(wn * 32 + 16 + (lane & 15)) * 32 + qa];\
    CLOAD((p) + 2, aCur, bCur);                                                \
    acc[0] = __builtin_amdgcn_mfma_f32_16x16x32_f16(af, bf0, acc[0], 0, 0, 0); \
    acc[1] = __builtin_amdgcn_mfma_f32_16x16x32_f16(af, bf1, acc[1], 0, 0, 0); \
    *(f16x4*)&s_a[bn][adst] = aNxt;                                            \
    *(f16x8*)&s_b[bn][bdst] = bNxt;                                            \
    asm volatile("s_waitcnt lgkmcnt(0)" ::: "memory"); SB();                   \
    __builtin_amdgcn_s_barrier(); SB();                                        \
} while (0)

    for (int p = 0; p < 72; p += 2) {
        CBODY(p,     aR0, bR0, aR1, bR1, 0, 1);
        CBODY(p + 1, aR1, bR1, aR0, bR0, 1, 0);
    }

    // epilogue: wm=0 -> taps 0..7 (rows 4g..4g+3), wm=1 -> tap 8 (rows 16,17)
    const int g = lane >> 4;
#pragma unroll
    for (int ni = 0; ni < 2; ++ni) {
        const int p = p0 + wn * 32 + ni * 16 + (lane & 15);
        const int hwq = p - imgb;
        const int hq = hwq / Wc, wq = hwq - hq * Wc;
        if (wm == 0) {
            store_tap(2 * g,     hq, wq, acc[ni][0] + b_off[4 * g],
                                         acc[ni][1] + b_off[4 * g + 1], p, idx4t, wt4t);
            store_tap(2 * g + 1, hq, wq, acc[ni][2] + b_off[4 * g + 2],
                                         acc[ni][3] + b_off[4 * g + 3], p, idx4t, wt4t);
        } else if (g == 0) {
            store_tap(8, hq, wq, acc[ni][0] + b_off[16],
                                 acc[ni][1] + b_off[17], p, idx4t, wt4t);
        }
    }
#undef CLOAD
#undef CBODY
}

// Fused deformable sampling (f16 NHWC gathers) + f16 MFMA GEMM + ReLU.
// Block: 256 threads (4 waves), tile 256 out x 32 pix; wave = 64out x 32pix
// (acc = 8 f32x4 = 32 regs — HALF of R7, so 3 waves/SIMD fit without any
// register squeeze; R10/R11/R13 all died forcing 64-acc kernels to 3+).
// 1152 blocks -> 3 blocks/CU resident (12 waves/CU). LDS 36KB.
// Load roles by wave: waves 0-1 sample (16 pix x 4 chan-grps each; blend's
// counted vmcnt covers corners), waves 2-3 stage 16KB weights (8 gload_lds
// each, drained by own vmcnt(0) BEFORE the end-of-chunk barrier — R6-proven
// race-free since only waves 2-3 write s_w).
__global__ __launch_bounds__(256, 3) void deform_mfma_kernel(
    const f16* __restrict__ x16, const f16* __restrict__ wT2,
    const int4* __restrict__ idx4t, const float4* __restrict__ wt4t,
    f16* __restrict__ o16, float* __restrict__ oN, int last)
{
    __shared__ __align__(16) f16 s_w[2][8192];  // 2 x 16KB [o(256)][kk(32)] swz
    __shared__ __align__(16) f16 s_s[2][1024];  // 2 x 2KB  [pix(32)][kk(32)] swz

    const int bid = blockIdx.x;
    const int swz = (bid & 7) * 144 + (bid >> 3); // 1152 blocks, XCD-chunked
    const int p0 = swz * 32;
    const int imgb = (p0 / HW) * HW;
    const int tid = threadIdx.x, lane = tid & 63, wid = tid >> 6;
    const bool sampler = (wid < 2);
    const int ps = (tid >> 2) & 31, cg = tid & 3;  // sampling slot (tid<128)
    const int qa = ((lane >> 4) ^ ((lane >> 1) & 3)) * 8;
    const int qs = (cg ^ ((ps >> 1) & 3)) * 8;
    const int wu = tid & 127;                      // weight-stage slot (tid>=128)
    const f16* xb = x16 + (size_t)imgb * Cc;

// stage 16KB weights for (tap kt, chunk cw) -> buf nb; 128 threads x 8 loads
#define ISSUE_W(kt, cw, nb) do {                                               \
    _Pragma("unroll")                                                          \
    for (int i_ = 0; i_ < 8; ++i_) {                                           \
        int u_ = i_ * 128 + wu;                                                \
        int wr_ = u_ >> 2;                                                     \
        int wc_ = ((u_ & 3) ^ ((u_ >> 3) & 3)) * 8;                            \
        const f16* g_ = wT2 + ((size_t)((kt) * 256 + wr_)) * Cc + (cw) * 32 + wc_; \
        __builtin_amdgcn_global_load_lds(                                      \
            (const __attribute__((address_space(1))) void*)g_,                 \
            (__attribute__((address_space(3))) void*)&s_w[nb][u_ * 8], 16, 0, 0); \
    }                                                                          \
} while (0)

// 4 lanes (cg=0..3) of pixel ps read contiguous 64B per corner
#define ISSUE_C(dst, idv, co) do {                                             \
    (dst)[0] = *(const f16x8*)(xb + (size_t)(idv).x * Cc + (co) + cg * 8);     \
    (dst)[1] = *(const f16x8*)(xb + (size_t)(idv).y * Cc + (co) + cg * 8);     \
    (dst)[2] = *(const f16x8*)(xb + (size_t)(idv).z * Cc + (co) + cg * 8);     \
    (dst)[3] = *(const f16x8*)(xb + (size_t)(idv).w * Cc + (co) + cg * 8);     \
} while (0)

#define BLEND_WRITE(src, wvv, nb) do {                                         \
    f16x8 sv_;                                                                 \
    _Pragma("unroll")                                                          \
    for (int j_ = 0; j_ < 8; ++j_) {                                           \
        float s_ = (wvv).x * (float)(src)[0][j_] + (wvv).y * (float)(src)[1][j_]\
                 + (wvv).z * (float)(src)[2][j_] + (wvv).w * (float)(src)[3][j_];\
        sv_[j_] = (f16)s_;                                                     \
    }                                                                          \
    *(f16x8*)&s_s[nb][ps * 32 + qs] = sv_;                                     \
} while (0)

    f32x4 acc[4][2];
#pragma unroll
    for (int mi = 0; mi < 4; ++mi)
#pragma unroll
        for (int ni = 0; ni < 2; ++ni) acc[mi][ni] = (f32x4){0.f, 0.f, 0.f, 0.f};

    f16x8 c4[4];                 // next chunk's corners (sampler waves only)
    int4 id = make_int4(0, 0, 0, 0);
    float4 wv = make_float4(0.f, 0.f, 0.f, 0.f);
    int4 idN;
    float4 wvN;
    if (sampler) {
        id = idx4t[p0 + ps];
        wv = wt4t[p0 + ps];
    }

    // prologue: waves 2-3 stage W(chunk0); waves 0-1 sample chunk0, blend,
    // then issue chunk1's corners. Both drain their own VMEM before barrier.
    if (!sampler) {
        ISSUE_W(0, 0, 0);
        asm volatile("s_waitcnt vmcnt(0)" ::: "memory"); SB();
    } else {
        ISSUE_C(c4, id, 0);                // corners for chunk 0
        BLEND_WRITE(c4, wv, 0);            // counted vmcnt waits C(0)
        ISSUE_C(c4, id, 32);               // corners for chunk 1 (in flight)
        asm volatile("s_waitcnt lgkmcnt(0)" ::: "memory"); SB();
    }
    __builtin_amdgcn_s_barrier(); SB();

    for (int k = 0; k < 9; ++k) {
        const int kn = (k < 8) ? k + 1 : 8;
#pragma unroll
        for (int ch = 0; ch < 8; ++ch) {
            const int bb = ch & 1, nb = bb ^ 1;
            f16x8 af[4], bf[2];
#pragma unroll
            for (int mi = 0; mi < 4; ++mi)
                af[mi] = *(const f16x8*)&s_w[bb][(wid * 64 + mi * 16 + (lane & 15)) * 32 + qa];
#pragma unroll
            for (int ni = 0; ni < 2; ++ni)
                bf[ni] = *(const f16x8*)&s_s[bb][(ni * 16 + (lane & 15)) * 32 + qa];
            if (!sampler) {
                // weights for chunk t+1 into the buffer read at t-1
                ISSUE_W((ch == 7) ? kn : k, (ch + 1) & 7, nb);
                SB();
            } else {
                if (ch == 0) {
                    idN = idx4t[(size_t)kn * PIX + p0 + ps];
                    wvN = wt4t[(size_t)kn * PIX + p0 + ps];
                }
                // blend corners for chunk t+1 (issued last chunk; counted vmcnt)
                const float4 wvu = (ch == 7) ? wvN : wv;
                BLEND_WRITE(c4, wvu, nb);
                // corners for chunk t+2 into the SAME regs (WAR after blend)
                const int4 idu = (ch >= 6) ? idN : id;
                ISSUE_C(c4, idu, ((ch + 2) & 7) * 32);
                asm volatile("s_waitcnt lgkmcnt(0)" ::: "memory"); SB();
            }
#pragma unroll
            for (int ni = 0; ni < 2; ++ni)
#pragma unroll
                for (int mi = 0; mi < 4; ++mi)
                    acc[mi][ni] = __builtin_amdgcn_mfma_f32_16x16x32_f16(
                        af[mi], bf[ni], acc[mi][ni], 0, 0, 0);
            if (!sampler) {
                // RACE-FREE POINT: drain this wave's W(t+1) LDS writes before
                // the barrier that precedes any wave's s_w[nb] reads.
                asm volatile("s_waitcnt vmcnt(0)" ::: "memory"); SB();
            }
            __builtin_amdgcn_s_barrier(); SB();
        }
        if (sampler) { id = idN; wv = wvN; }
    }

    // epilogue: ReLU; D row = output = (lane>>4)*4+j, col = pixel = lane&15
    if (!last) {
#pragma unroll
        for (int ni = 0; ni < 2; ++ni) {
            const int p = p0 + ni * 16 + (lane & 15);
#pragma unroll
            for (int mi = 0; mi < 4; ++mi) {
                const int o0 = wid * 64 + mi * 16 + (lane >> 4) * 4;
                f32x4 v = acc[mi][ni];
                f16x4 h = {(f16)fmaxf(v[0], 0.f), (f16)fmaxf(v[1], 0.f),
                           (f16)fmaxf(v[2], 0.f), (f16)fmaxf(v[3], 0.f)};
                *(f16x4*)&o16[(size_t)p * Cc + o0] = h;
            }
        }
    } else {
        const int bimg = imgb / HW;
#pragma unroll
        for (int ni = 0; ni < 2; ++ni) {
            const int p = p0 + ni * 16 + (lane & 15);
            const int hwl = p - imgb;
#pragma unroll
            for (int mi = 0; mi < 4; ++mi) {
                const int o0 = wid * 64 + mi * 16 + (lane >> 4) * 4;
#pragma unroll
                for (int j = 0; j < 4; ++j)
                    oN[((size_t)(bimg * Cc + o0 + j)) * HW + hwl] =
                        fmaxf(acc[mi][ni][j], 0.f);
            }
        }
    }
#undef ISSUE_W
#undef ISSUE_C
#undef BLEND_WRITE
}

extern "C" void kernel_launch(void* const* d_in, const int* in_sizes, int n_in,
                              void* d_out, int out_size, void* d_ws, size_t ws_size,
                              hipStream_t stream)
{
    const float* x0 = (const float*)d_in[0];
    float* out = (float*)d_out;

    f16*   x16a = (f16*)d_ws;                          // PIX*Cc f16
    f16*   x16b = x16a + (size_t)PIX * Cc;             // PIX*Cc f16
    f16*   wT2  = x16b + (size_t)PIX * Cc;             // CK*Cc f16
    f16*   woffT = wT2 + (size_t)CK * Cc;              // 9*32*256 f16
    int4*  idx4t = (int4*)(woffT + (size_t)9 * 32 * Cc);
    float4* wt4t = (float4*)(idx4t + (size_t)KK * PIX);

    nhwc_prep_kernel<<<dim3(HW / 64, Cc / 64, Bc), 256, 0, stream>>>(x0, x16a);

    const f16* xin = x16a;
    for (int L = 0; L < 3; ++L) {
        const float* w_off = (const float*)d_in[1 + 3 * L];
        const float* b_off = (const float*)d_in[2 + 3 * L];
        const float* w     = (const float*)d_in[3 + 3 * L];
        const int last = (L == 2);
        f16* xo = (L == 0) ? x16b : x16a;

        transpose_w_kernel<<<(CK * Cc) / 256, 256, 0, stream>>>(w, wT2);
        woff_prep_kernel<<<(9 * 32 * Cc) / 256, 256, 0, stream>>>(w_off, woffT);
        conv_off_mfma_kernel<<<PIX / 64, 256, 0, stream>>>(xin, woffT, b_off, idx4t, wt4t);
        deform_mfma_kernel<<<PIX / 32, 256, 0, stream>>>(
            xin, wT2, idx4t, wt4t, xo, out, last);

        xin = xo;
    }
}

// Round 15
// 397.196 us; speedup vs baseline: 1.3376x; 1.3376x over previous
//
#include <hip/hip_runtime.h>

#define Hc 96
#define Wc 96
#define Cc 256
#define Bc 4
#define KK 9
#define HW 9216          // Hc*Wc
#define PIX 36864        // Bc*HW
#define CK 2304          // Cc*KK

typedef _Float16 f16;
typedef __attribute__((ext_vector_type(4))) _Float16 f16x4;
typedef __attribute__((ext_vector_type(8))) _Float16 f16x8;
typedef __attribute__((ext_vector_type(4))) float f32x4;

__device__ __forceinline__ int clampi(int v, int lo, int hi) {
    return v < lo ? lo : (v > hi ? hi : v);
}

#define SB() __builtin_amdgcn_sched_barrier(0)

// ---------- prep: NCHW fp32 -> NHWC f16 (layer 0 input) ----------
__global__ __launch_bounds__(256) void nhwc_prep_kernel(
    const float* __restrict__ x0, f16* __restrict__ x16)
{
    __shared__ float st[64][65];
    const int hw0 = blockIdx.x * 64;
    const int c0  = blockIdx.y * 64;
    const int b   = blockIdx.z;
    const int tid = threadIdx.x;
    const int a = tid & 63, r = tid >> 6;
#pragma unroll
    for (int it = 0; it < 16; ++it) {
        int cl = it * 4 + r;
        st[cl][a] = x0[((size_t)(b * Cc + c0 + cl)) * HW + hw0 + a];
    }
    __syncthreads();
#pragma unroll
    for (int it = 0; it < 16; ++it) {
        int hwl = it * 4 + r;
        x16[((size_t)(b * HW + hw0 + hwl)) * Cc + c0 + a] = (f16)st[a][hwl];
    }
}

// wT2[(k*256 + o)*256 + c] = (f16) w[(o*256 + c)*9 + k]
__global__ __launch_bounds__(256) void transpose_w_kernel(
    const float* __restrict__ w, f16* __restrict__ wT2)
{
    int u = blockIdx.x * 256 + threadIdx.x;   // < 589824
    int c = u & 255, o = (u >> 8) & 255, k = u >> 16;
    wT2[u] = (f16)w[(o * Cc + c) * KK + k];
}

// woffT[(k*32 + j)*256 + c] = (f16) w_off[(j*256 + c)*9 + k], rows 18..31 = 0
__global__ __launch_bounds__(256) void woff_prep_kernel(
    const float* __restrict__ w_off, f16* __restrict__ woffT)
{
    int u = blockIdx.x * 256 + threadIdx.x;   // < 73728
    int c = u & 255, j = (u >> 8) & 31, k = u >> 13;
    float v = (j < 18) ? w_off[((size_t)j * Cc + c) * KK + k] : 0.f;
    woffT[u] = (f16)v;
}

// bilinear decomposition for one tap -> idx4/wt4 (tap-major layout)
__device__ __forceinline__ void store_tap(int k, int h, int w, float offy, float offx,
    int p, int4* __restrict__ idx4t, float4* __restrict__ wt4t)
{
    float py = (float)(h - 1 + k / 3) + offy;
    float px = (float)(w - 1 + k % 3) + offx;
    float y0f = floorf(py), x0f = floorf(px);
    float wy = py - y0f, wx = px - x0f;
    int iy0 = (int)y0f, ix0 = (int)x0f;
    float vy0 = (y0f >= 0.f && y0f <= 95.f) ? 1.f : 0.f;
    float vy1 = (y0f + 1.f >= 0.f && y0f + 1.f <= 95.f) ? 1.f : 0.f;
    float vx0 = (x0f >= 0.f && x0f <= 95.f) ? 1.f : 0.f;
    float vx1 = (x0f + 1.f >= 0.f && x0f + 1.f <= 95.f) ? 1.f : 0.f;
    int cy0 = clampi(iy0, 0, 95), cy1 = clampi(iy0 + 1, 0, 95);
    int cx0 = clampi(ix0, 0, 95), cx1 = clampi(ix0 + 1, 0, 95);
    idx4t[(size_t)k * PIX + p] = make_int4(cy0 * Wc + cx0, cy0 * Wc + cx1,
                                           cy1 * Wc + cx0, cy1 * Wc + cx1);
    wt4t[(size_t)k * PIX + p] = make_float4((1.f - wy) * (1.f - wx) * vy0 * vx0,
                                            (1.f - wy) * wx * vy0 * vx1,
                                            wy * (1.f - wx) * vy1 * vx0,
                                            wy * wx * vy1 * vx1);
}

// Offset conv as f16 MFMA GEMM, reg-staged double-buffered pipeline.
// Block: 256 threads (4 waves = 2M x 2N), tile 32 out x 64 pixels. 576 blocks.
__global__ __launch_bounds__(256) void conv_off_mfma_kernel(
    const f16* __restrict__ x16, const f16* __restrict__ woffT,
    const float* __restrict__ b_off,
    int4* __restrict__ idx4t, float4* __restrict__ wt4t)
{
    __shared__ __align__(16) f16 s_a[2][32 * 32];   // 2 x 2KB
    __shared__ __align__(16) f16 s_b[2][64 * 32];   // 2 x 4KB
    const int bid = blockIdx.x;
    const int swz = (bid & 7) * 72 + (bid >> 3);    // 576 blocks, XCD-chunked
    const int p0 = swz * 64;
    const int imgb = (p0 / HW) * HW;
    const int tid = threadIdx.x, lane = tid & 63, wid = tid >> 6;
    const int wm = wid >> 1, wn = wid & 1;
    const int qa = ((lane >> 4) ^ ((lane >> 1) & 3)) * 8;
    // A-stage mapping: row/col-quad
    const int arow = tid >> 3, acb = tid & 7;
    const int adst = arow * 32 + (((acb >> 1) ^ ((arow >> 1) & 3)) * 8) + (acb & 1) * 4;
    // B-stage mapping: 4 lanes per pixel (coalesced 64B), pixel ps, group cg
    const int ps = tid >> 2, cg = tid & 3;
    const int bdst = ps * 32 + ((cg ^ ((ps >> 1) & 3)) * 8);
    const int hwp = p0 + ps - imgb;
    const int hp = hwp / Wc, wp = hwp - hp * Wc;

#define CLOAD(q, aD, bD) do {                                                  \
    int p2_ = (q) > 71 ? 71 : (q);                                             \
    int k2_ = p2_ >> 3, c2_ = p2_ & 7;                                         \
    int ky_ = k2_ / 3, kx_ = k2_ - ky_ * 3;                                    \
    int yy_ = hp + ky_ - 1, xx_ = wp + kx_ - 1;                                \
    bool v_ = (yy_ >= 0 && yy_ < Hc && xx_ >= 0 && xx_ < Wc);                  \
    aD = *(const f16x4*)(woffT + ((size_t)(k2_ * 32 + arow)) * Cc + c2_ * 32 + acb * 4); \
    f16x8 t_ = {0, 0, 0, 0, 0, 0, 0, 0};                                       \
    if (v_) t_ = *(const f16x8*)(x16 + ((size_t)(imgb + yy_ * Wc + xx_)) * Cc + c2_ * 32 + cg * 8); \
    bD = t_;                                                                   \
} while (0)

    f32x4 acc[2];
    acc[0] = (f32x4){0.f, 0.f, 0.f, 0.f};
    acc[1] = (f32x4){0.f, 0.f, 0.f, 0.f};

    f16x4 aR0, aR1;
    f16x8 bR0, bR1;
    // prologue: phase 0 -> slot0 -> s[0]; phase 1 -> slot1 (held in regs)
    CLOAD(0, aR0, bR0);
    CLOAD(1, aR1, bR1);
    *(f16x4*)&s_a[0][adst] = aR0;
    *(f16x8*)&s_b[0][bdst] = bR0;
    asm volatile("s_waitcnt lgkmcnt(0)" ::: "memory"); SB();
    __builtin_amdgcn_s_barrier(); SB();

#define CBODY(p, aCur, bCur, aNxt, bNxt, bc, bn) do {                          \
    f16x8 af = *(const f16x8*)&s_a[bc][(wm * 16 + (lane & 15)) * 32 + qa];     \
    f16x8 bf0 = *(const f16x8*)&s_b[bc][(wn * 32 + (lane & 15)) * 32 + qa];    \
    f16x8 bf1 = *(const f16x8*)&s_b[bc][(wn * 32 + 16 + (lane & 15)) * 32 + qa];\
    CLOAD((p) + 2, aCur, bCur);                                                \
    acc[0] = __builtin_amdgcn_mfma_f32_16x16x32_f16(af, bf0, acc[0], 0, 0, 0); \
    acc[1] = __builtin_amdgcn_mfma_f32_16x16x32_f16(af, bf1, acc[1], 0, 0, 0); \
    *(f16x4*)&s_a[bn][adst] = aNxt;                                            \
    *(f16x8*)&s_b[bn][bdst] = bNxt;                                            \
    asm volatile("s_waitcnt lgkmcnt(0)" ::: "memory"); SB();                   \
    __builtin_amdgcn_s_barrier(); SB();                                        \
} while (0)

    for (int p = 0; p < 72; p += 2) {
        CBODY(p,     aR0, bR0, aR1, bR1, 0, 1);
        CBODY(p + 1, aR1, bR1, aR0, bR0, 1, 0);
    }

    // epilogue: wm=0 -> taps 0..7 (rows 4g..4g+3), wm=1 -> tap 8 (rows 16,17)
    const int g = lane >> 4;
#pragma unroll
    for (int ni = 0; ni < 2; ++ni) {
        const int p = p0 + wn * 32 + ni * 16 + (lane & 15);
        const int hwq = p - imgb;
        const int hq = hwq / Wc, wq = hwq - hq * Wc;
        if (wm == 0) {
            store_tap(2 * g,     hq, wq, acc[ni][0] + b_off[4 * g],
                                         acc[ni][1] + b_off[4 * g + 1], p, idx4t, wt4t);
            store_tap(2 * g + 1, hq, wq, acc[ni][2] + b_off[4 * g + 2],
                                         acc[ni][3] + b_off[4 * g + 3], p, idx4t, wt4t);
        } else if (g == 0) {
            store_tap(8, hq, wq, acc[ni][0] + b_off[16],
                                 acc[ni][1] + b_off[17], p, idx4t, wt4t);
        }
    }
#undef CLOAD
#undef CBODY
}

// Fused deformable sampling (f16 NHWC gathers) + f16 MFMA GEMM + ReLU.
// Block: 256 threads (4 waves), tile 256 out x 64 pix; wave = 64x64. 576 blocks.
// R13 structure (passing, race-free: own-wave vmcnt(4) drains W writes BEFORE
// the end-of-chunk barrier) with register shaving for TRUE 3 blocks/CU
// (arch cap for (256,3) is ~84; R13's ~92 natural spilled):
//  - single corner buffer c4 (blend-then-reissue)        [-16 vs R7]
//  - idN/wvN loaded at ch==5, not ch==0 (lifetime 8->3)  [-8]
//  - ISSUE_W per-lane address folded to one hoisted wlo  [-4]
//  - af fragments streamed per-mi inside the MFMA loop    [peak -16]
// 576 blocks <= 768 slots -> ONE block-wave (R7 ran 2, second 12.5% full).
__global__ __launch_bounds__(256, 3) void deform_mfma_kernel(
    const f16* __restrict__ x16, const f16* __restrict__ wT2,
    const int4* __restrict__ idx4t, const float4* __restrict__ wt4t,
    f16* __restrict__ o16, float* __restrict__ oN, int last)
{
    __shared__ __align__(16) f16 s_w[2][8192];  // 2 x 16KB [o(256)][kk(32)] swz
    __shared__ __align__(16) f16 s_s[2][2048];  // 2 x 4KB  [pix(64)][kk(32)] swz

    const int bid = blockIdx.x;
    const int swz = (bid & 7) * 72 + (bid >> 3); // 576 blocks, XCD-chunked
    const int p0 = swz * 64;
    const int imgb = (p0 / HW) * HW;
    const int tid = threadIdx.x, lane = tid & 63, wid = tid >> 6;
    const int ps = tid >> 2, cg = tid & 3;       // sampling: pixel ps, 8-ch grp cg
    const int qa = ((lane >> 4) ^ ((lane >> 1) & 3)) * 8;
    const int qs = (cg ^ ((ps >> 1) & 3)) * 8;
    const f16* xb = x16 + (size_t)imgb * Cc;
    // hoisted lane-variant part of the weight-stage address (elements)
    const int wlo = (tid >> 2) * Cc + ((tid & 3) ^ ((tid >> 3) & 3)) * 8;
    const int wds = tid * 8;                     // lane's LDS slot base (elems)

// stage 16KB weights for (tap kt, chunk cw) -> buf nb; addr = lane part (wlo)
// + uniform part (kt,i_,cw) so the compiler keeps one VGPR offset + SGPR adds
#define ISSUE_W(kt, cw, nb) do {                                               \
    _Pragma("unroll")                                                          \
    for (int i_ = 0; i_ < 4; ++i_) {                                           \
        const f16* g_ = wT2 + wlo + ((size_t)((kt) * 256 + i_ * 64)) * Cc + (cw) * 32; \
        __builtin_amdgcn_global_load_lds(                                      \
            (const __attribute__((address_space(1))) void*)g_,                 \
            (__attribute__((address_space(3))) void*)&s_w[nb][i_ * 2048 + wds],\
            16, 0, 0);                                                         \
    }                                                                          \
} while (0)

// 4 lanes (cg=0..3) of pixel ps read contiguous 64B per corner
#define ISSUE_C(dst, idv, co) do {                                             \
    (dst)[0] = *(const f16x8*)(xb + (size_t)(idv).x * Cc + (co) + cg * 8);     \
    (dst)[1] = *(const f16x8*)(xb + (size_t)(idv).y * Cc + (co) + cg * 8);     \
    (dst)[2] = *(const f16x8*)(xb + (size_t)(idv).z * Cc + (co) + cg * 8);     \
    (dst)[3] = *(const f16x8*)(xb + (size_t)(idv).w * Cc + (co) + cg * 8);     \
} while (0)

#define BLEND_WRITE(src, wvv, nb) do {                                         \
    f16x8 sv_;                                                                 \
    _Pragma("unroll")                                                          \
    for (int j_ = 0; j_ < 8; ++j_) {                                           \
        float s_ = (wvv).x * (float)(src)[0][j_] + (wvv).y * (float)(src)[1][j_]\
                 + (wvv).z * (float)(src)[2][j_] + (wvv).w * (float)(src)[3][j_];\
        sv_[j_] = (f16)s_;                                                     \
    }                                                                          \
    *(f16x8*)&s_s[nb][ps * 32 + qs] = sv_;                                     \
} while (0)

    f32x4 acc[4][4];
#pragma unroll
    for (int mi = 0; mi < 4; ++mi)
#pragma unroll
        for (int ni = 0; ni < 4; ++ni) acc[mi][ni] = (f32x4){0.f, 0.f, 0.f, 0.f};

    f16x8 c4[4];                 // single corner buffer (next chunk's corners)
    int4 id = idx4t[p0 + ps];
    float4 wv = wt4t[p0 + ps];
    int4 idN;
    float4 wvN;

    // prologue: W(chunk0)->buf0; C(0)->blend->s_s[0] (waits C(0), which also
    // retires W(0) in-order); then C(1) into the same regs. Queue at loop
    // entry: C(1)x4 — the steady-state invariant.
    ISSUE_W(0, 0, 0);
    SB();
    ISSUE_C(c4, id, 0);                    // corners for chunk 0
    BLEND_WRITE(c4, wv, 0);
    ISSUE_C(c4, id, 32);                   // corners for chunk 1
    asm volatile("s_waitcnt lgkmcnt(0)" ::: "memory"); SB();
    __builtin_amdgcn_s_barrier(); SB();

    for (int k = 0; k < 9; ++k) {
        const int kn = (k < 8) ? k + 1 : 8;
#pragma unroll
        for (int ch = 0; ch < 8; ++ch) {
            const int bb = ch & 1, nb = bb ^ 1;
            f16x8 bf[4];
#pragma unroll
            for (int ni = 0; ni < 4; ++ni)
                bf[ni] = *(const f16x8*)&s_s[bb][(ni * 16 + (lane & 15)) * 32 + qa];
            if (ch == 5) {                 // late load: lifetime ch5..ch8 only
                idN = idx4t[(size_t)kn * PIX + p0 + ps];
                wvN = wt4t[(size_t)kn * PIX + p0 + ps];
            }
            // weights for chunk t+1 into the buffer read at t-1
            ISSUE_W((ch == 7) ? kn : k, (ch + 1) & 7, nb);
            SB();
            // blend corners for chunk t+1 (c4, issued last chunk; compiler's
            // counted vmcnt retires C(t+1) — oldest in queue)
            {
                const float4 wvu = (ch == 7) ? wvN : wv;
                BLEND_WRITE(c4, wvu, nb);
            }
            // corners for chunk t+2 into the SAME regs (after blend's reads).
            // At ch==6/7 idN is ready: ch5's vmcnt(4) below retired its load.
            {
                const int4 idu = (ch >= 6) ? idN : id;
                ISSUE_C(c4, idu, ((ch + 2) & 7) * 32);
            }
            asm volatile("s_waitcnt lgkmcnt(0)" ::: "memory"); SB();
            // MFMAs: af streamed per-mi (peak frag-live 48 not 64)
#pragma unroll
            for (int mi = 0; mi < 4; ++mi) {
                f16x8 af = *(const f16x8*)&s_w[bb][(wid * 64 + mi * 16 + (lane & 15)) * 32 + qa];
#pragma unroll
                for (int ni = 0; ni < 4; ++ni)
                    acc[mi][ni] = __builtin_amdgcn_mfma_f32_16x16x32_f16(
                        af, bf[ni], acc[mi][ni], 0, 0, 0);
            }
            // RACE-FREE POINT: retire this wave's W(t+1) writes (outstanding
            // here = [W(t+1)x4 oldest (+id/wv at ch5), C(t+2)x4]) BEFORE the
            // barrier, so all s_w[nb] writes land before anyone reads them.
            asm volatile("s_waitcnt vmcnt(4)" ::: "memory"); SB();
            __builtin_amdgcn_s_barrier(); SB();
        }
        id = idN;
        wv = wvN;
    }

    // epilogue: ReLU; D row = output = (lane>>4)*4+j, col = pixel = lane&15
    if (!last) {
#pragma unroll
        for (int ni = 0; ni < 4; ++ni) {
            const int p = p0 + ni * 16 + (lane & 15);
#pragma unroll
            for (int mi = 0; mi < 4; ++mi) {
                const int o0 = wid * 64 + mi * 16 + (lane >> 4) * 4;
                f32x4 v = acc[mi][ni];
                f16x4 h = {(f16)fmaxf(v[0], 0.f), (f16)fmaxf(v[1], 0.f),
                           (f16)fmaxf(v[2], 0.f), (f16)fmaxf(v[3], 0.f)};
                *(f16x4*)&o16[(size_t)p * Cc + o0] = h;
            }
        }
    } else {
        const int bimg = imgb / HW;
#pragma unroll
        for (int ni = 0; ni < 4; ++ni) {
            const int p = p0 + ni * 16 + (lane & 15);
            const int hwl = p - imgb;
#pragma unroll
            for (int mi = 0; mi < 4; ++mi) {
                const int o0 = wid * 64 + mi * 16 + (lane >> 4) * 4;
#pragma unroll
                for (int j = 0; j < 4; ++j)
                    oN[((size_t)(bimg * Cc + o0 + j)) * HW + hwl] =
                        fmaxf(acc[mi][ni][j], 0.f);
            }
        }
    }
#undef ISSUE_W
#undef ISSUE_C
#undef BLEND_WRITE
}

extern "C" void kernel_launch(void* const* d_in, const int* in_sizes, int n_in,
                              void* d_out, int out_size, void* d_ws, size_t ws_size,
                              hipStream_t stream)
{
    const float* x0 = (const float*)d_in[0];
    float* out = (float*)d_out;

    f16*   x16a = (f16*)d_ws;                          // PIX*Cc f16
    f16*   x16b = x16a + (size_t)PIX * Cc;             // PIX*Cc f16
    f16*   wT2  = x16b + (size_t)PIX * Cc;             // CK*Cc f16
    f16*   woffT = wT2 + (size_t)CK * Cc;              // 9*32*256 f16
    int4*  idx4t = (int4*)(woffT + (size_t)9 * 32 * Cc);
    float4* wt4t = (float4*)(idx4t + (size_t)KK * PIX);

    nhwc_prep_kernel<<<dim3(HW / 64, Cc / 64, Bc), 256, 0, stream>>>(x0, x16a);

    const f16* xin = x16a;
    for (int L = 0; L < 3; ++L) {
        const float* w_off = (const float*)d_in[1 + 3 * L];
        const float* b_off = (const float*)d_in[2 + 3 * L];
        const float* w     = (const float*)d_in[3 + 3 * L];
        const int last = (L == 2);
        f16* xo = (L == 0) ? x16b : x16a;

        transpose_w_kernel<<<(CK * Cc) / 256, 256, 0, stream>>>(w, wT2);
        woff_prep_kernel<<<(9 * 32 * Cc) / 256, 256, 0, stream>>>(w_off, woffT);
        conv_off_mfma_kernel<<<PIX / 64, 256, 0, stream>>>(xin, woffT, b_off, idx4t, wt4t);
        deform_mfma_kernel<<<PIX / 64, 256, 0, stream>>>(
            xin, wT2, idx4t, wt4t, xo, out, last);

        xin = xo;
    }
}

// Round 16
// 380.679 us; speedup vs baseline: 1.3957x; 1.0434x over previous
//
#include <hip/hip_runtime.h>

#define Hc 96
#define Wc 96
#define Cc 256
#define Bc 4
#define KK 9
#define HW 9216          // Hc*Wc
#define PIX 36864        // Bc*HW
#define CK 2304          // Cc*KK

typedef _Float16 f16;
typedef __attribute__((ext_vector_type(4))) _Float16 f16x4;
typedef __attribute__((ext_vector_type(8))) _Float16 f16x8;
typedef __attribute__((ext_vector_type(4))) float f32x4;

__device__ __forceinline__ int clampi(int v, int lo, int hi) {
    return v < lo ? lo : (v > hi ? hi : v);
}

#define SB() __builtin_amdgcn_sched_barrier(0)

// ---------- prep: NCHW fp32 -> NHWC f16 (layer 0 input) ----------
__global__ __launch_bounds__(256) void nhwc_prep_kernel(
    const float* __restrict__ x0, f16* __restrict__ x16)
{
    __shared__ float st[64][65];
    const int hw0 = blockIdx.x * 64;
    const int c0  = blockIdx.y * 64;
    const int b   = blockIdx.z;
    const int tid = threadIdx.x;
    const int a = tid & 63, r = tid >> 6;
#pragma unroll
    for (int it = 0; it < 16; ++it) {
        int cl = it * 4 + r;
        st[cl][a] = x0[((size_t)(b * Cc + c0 + cl)) * HW + hw0 + a];
    }
    __syncthreads();
#pragma unroll
    for (int it = 0; it < 16; ++it) {
        int hwl = it * 4 + r;
        x16[((size_t)(b * HW + hw0 + hwl)) * Cc + c0 + a] = (f16)st[a][hwl];
    }
}

// wT2[(k*256 + o)*256 + c] = (f16) w[(o*256 + c)*9 + k]
__global__ __launch_bounds__(256) void transpose_w_kernel(
    const float* __restrict__ w, f16* __restrict__ wT2)
{
    int u = blockIdx.x * 256 + threadIdx.x;   // < 589824
    int c = u & 255, o = (u >> 8) & 255, k = u >> 16;
    wT2[u] = (f16)w[(o * Cc + c) * KK + k];
}

// woffT[(k*32 + j)*256 + c] = (f16) w_off[(j*256 + c)*9 + k], rows 18..31 = 0
__global__ __launch_bounds__(256) void woff_prep_kernel(
    const float* __restrict__ w_off, f16* __restrict__ woffT)
{
    int u = blockIdx.x * 256 + threadIdx.x;   // < 73728
    int c = u & 255, j = (u >> 8) & 31, k = u >> 13;
    float v = (j < 18) ? w_off[((size_t)j * Cc + c) * KK + k] : 0.f;
    woffT[u] = (f16)v;
}

// bilinear decomposition for one tap -> idx4/wt4 (tap-major layout)
__device__ __forceinline__ void store_tap(int k, int h, int w, float offy, float offx,
    int p, int4* __restrict__ idx4t, float4* __restrict__ wt4t)
{
    float py = (float)(h - 1 + k / 3) + offy;
    float px = (float)(w - 1 + k % 3) + offx;
    float y0f = floorf(py), x0f = floorf(px);
    float wy = py - y0f, wx = px - x0f;
    int iy0 = (int)y0f, ix0 = (int)x0f;
    float vy0 = (y0f >= 0.f && y0f <= 95.f) ? 1.f : 0.f;
    float vy1 = (y0f + 1.f >= 0.f && y0f + 1.f <= 95.f) ? 1.f : 0.f;
    float vx0 = (x0f >= 0.f && x0f <= 95.f) ? 1.f : 0.f;
    float vx1 = (x0f + 1.f >= 0.f && x0f + 1.f <= 95.f) ? 1.f : 0.f;
    int cy0 = clampi(iy0, 0, 95), cy1 = clampi(iy0 + 1, 0, 95);
    int cx0 = clampi(ix0, 0, 95), cx1 = clampi(ix0 + 1, 0, 95);
    idx4t[(size_t)k * PIX + p] = make_int4(cy0 * Wc + cx0, cy0 * Wc + cx1,
                                           cy1 * Wc + cx0, cy1 * Wc + cx1);
    wt4t[(size_t)k * PIX + p] = make_float4((1.f - wy) * (1.f - wx) * vy0 * vx0,
                                            (1.f - wy) * wx * vy0 * vx1,
                                            wy * (1.f - wx) * vy1 * vx0,
                                            wy * wx * vy1 * vx1);
}

// Offset conv as f16 MFMA GEMM, reg-staged double-buffered pipeline.
// Block: 256 threads (4 waves = 2M x 2N), tile 32 out x 64 pixels. 576 blocks.
__global__ __launch_bounds__(256) void conv_off_mfma_kernel(
    const f16* __restrict__ x16, const f16* __restrict__ woffT,
    const float* __restrict__ b_off,
    int4* __restrict__ idx4t, float4* __restrict__ wt4t)
{
    __shared__ __align__(16) f16 s_a[2][32 * 32];   // 2 x 2KB
    __shared__ __align__(16) f16 s_b[2][64 * 32];   // 2 x 4KB
    const int bid = blockIdx.x;
    const int swz = (bid & 7) * 72 + (bid >> 3);    // 576 blocks, XCD-chunked
    const int p0 = swz * 64;
    const int imgb = (p0 / HW) * HW;
    const int tid = threadIdx.x, lane = tid & 63, wid = tid >> 6;
    const int wm = wid >> 1, wn = wid & 1;
    const int qa = ((lane >> 4) ^ ((lane >> 1) & 3)) * 8;
    // A-stage mapping: row/col-quad
    const int arow = tid >> 3, acb = tid & 7;
    const int adst = arow * 32 + (((acb >> 1) ^ ((arow >> 1) & 3)) * 8) + (acb & 1) * 4;
    // B-stage mapping: 4 lanes per pixel (coalesced 64B), pixel ps, group cg
    const int ps = tid >> 2, cg = tid & 3;
    const int bdst = ps * 32 + ((cg ^ ((ps >> 1) & 3)) * 8);
    const int hwp = p0 + ps - imgb;
    const int hp = hwp / Wc, wp = hwp - hp * Wc;

#define CLOAD(q, aD, bD) do {                                                  \
    int p2_ = (q) > 71 ? 71 : (q);                                             \
    int k2_ = p2_ >> 3, c2_ = p2_ & 7;                                         \
    int ky_ = k2_ / 3, kx_ = k2_ - ky_ * 3;                                    \
    int yy_ = hp + ky_ - 1, xx_ = wp + kx_ - 1;                                \
    bool v_ = (yy_ >= 0 && yy_ < Hc && xx_ >= 0 && xx_ < Wc);                  \
    aD = *(const f16x4*)(woffT + ((size_t)(k2_ * 32 + arow)) * Cc + c2_ * 32 + acb * 4); \
    f16x8 t_ = {0, 0, 0, 0, 0, 0, 0, 0};                                       \
    if (v_) t_ = *(const f16x8*)(x16 + ((size_t)(imgb + yy_ * Wc + xx_)) * Cc + c2_ * 32 + cg * 8); \
    bD = t_;                                                                   \
} while (0)

    f32x4 acc[2];
    acc[0] = (f32x4){0.f, 0.f, 0.f, 0.f};
    acc[1] = (f32x4){0.f, 0.f, 0.f, 0.f};

    f16x4 aR0, aR1;
    f16x8 bR0, bR1;
    // prologue: phase 0 -> slot0 -> s[0]; phase 1 -> slot1 (held in regs)
    CLOAD(0, aR0, bR0);
    CLOAD(1, aR1, bR1);
    *(f16x4*)&s_a[0][adst] = aR0;
    *(f16x8*)&s_b[0][bdst] = bR0;
    asm volatile("s_waitcnt lgkmcnt(0)" ::: "memory"); SB();
    __builtin_amdgcn_s_barrier(); SB();

#define CBODY(p, aCur, bCur, aNxt, bNxt, bc, bn) do {                          \
    f16x8 af = *(const f16x8*)&s_a[bc][(wm * 16 + (lane & 15)) * 32 + qa];     \
    f16x8 bf0 = *(const f16x8*)&s_b[bc][(wn * 32 + (lane & 15)) * 32 + qa];    \
    f16x8 bf1 = *(const f16x8*)&s_b[bc][(wn * 32 + 16 + (lane & 15)) * 32 + qa];\
    CLOAD((p) + 2, aCur, bCur);                                                \
    acc[0] = __builtin_amdgcn_mfma_f32_16x16x32_f16(af, bf0, acc[0], 0, 0, 0); \
    acc[1] = __builtin_amdgcn_mfma_f32_16x16x32_f16(af, bf1, acc[1], 0, 0, 0); \
    *(f16x4*)&s_a[bn][adst] = aNxt;                                            \
    *(f16x8*)&s_b[bn][bdst] = bNxt;                                            \
    asm volatile("s_waitcnt lgkmcnt(0)" ::: "memory"); SB();                   \
    __builtin_amdgcn_s_barrier(); SB();                                        \
} while (0)

    for (int p = 0; p < 72; p += 2) {
        CBODY(p,     aR0, bR0, aR1, bR1, 0, 1);
        CBODY(p + 1, aR1, bR1, aR0, bR0, 1, 0);
    }

    // epilogue: wm=0 -> taps 0..7 (rows 4g..4g+3), wm=1 -> tap 8 (rows 16,17)
    const int g = lane >> 4;
#pragma unroll
    for (int ni = 0; ni < 2; ++ni) {
        const int p = p0 + wn * 32 + ni * 16 + (lane & 15);
        const int hwq = p - imgb;
        const int hq = hwq / Wc, wq = hwq - hq * Wc;
        if (wm == 0) {
            store_tap(2 * g,     hq, wq, acc[ni][0] + b_off[4 * g],
                                         acc[ni][1] + b_off[4 * g + 1], p, idx4t, wt4t);
            store_tap(2 * g + 1, hq, wq, acc[ni][2] + b_off[4 * g + 2],
                                         acc[ni][3] + b_off[4 * g + 3], p, idx4t, wt4t);
        } else if (g == 0) {
            store_tap(8, hq, wq, acc[ni][0] + b_off[16],
                                 acc[ni][1] + b_off[17], p, idx4t, wt4t);
        }
    }
#undef CLOAD
#undef CBODY
}

// Fused deformable sampling (f16 NHWC gathers) + f16 MFMA GEMM + ReLU.
// Block: 256 threads (4 waves), tile 256 out x 48 pix; wave = 64out x 48pix
// (acc = 12 f32x4 = 48 regs). Grid = PIX/48 = 768 = EXACTLY 3 blocks per CU
// -> perfectly balanced makespan (R15's 576 grid gave 64 CUs 3 blocks and
// 192 CUs 2 -> 33% tail idle on most of the chip).
// Sampling: 48 pix x 4 chan-grps = 192 threads = waves 0-2 (wave-uniform);
// wave 3 only stages weights + MFMAs. Race-free discipline per R15: every
// wave drains its own W(t+1) gload_lds writes BEFORE the end-of-chunk
// barrier — samplers via vmcnt(4) (queue = [W x4, C(t+2) x4]), wave 3 via
// vmcnt(0) (queue = [W x4] only).
__global__ __launch_bounds__(256, 3) void deform_mfma_kernel(
    const f16* __restrict__ x16, const f16* __restrict__ wT2,
    const int4* __restrict__ idx4t, const float4* __restrict__ wt4t,
    f16* __restrict__ o16, float* __restrict__ oN, int last)
{
    __shared__ __align__(16) f16 s_w[2][8192];  // 2 x 16KB [o(256)][kk(32)] swz
    __shared__ __align__(16) f16 s_s[2][1536];  // 2 x 3KB  [pix(48)][kk(32)] swz

    const int bid = blockIdx.x;
    const int swz = (bid & 7) * 96 + (bid >> 3); // 768 blocks, XCD-chunked
    const int p0 = swz * 48;
    const int imgb = (p0 / HW) * HW;
    const int tid = threadIdx.x, lane = tid & 63, wid = tid >> 6;
    const bool sampler = (wid < 3);              // threads 0..191 <=> ps 0..47
    const int ps = tid >> 2, cg = tid & 3;
    const int qa = ((lane >> 4) ^ ((lane >> 1) & 3)) * 8;
    const int qs = (cg ^ ((ps >> 1) & 3)) * 8;
    const f16* xb = x16 + (size_t)imgb * Cc;
    // hoisted lane-variant part of the weight-stage address (elements)
    const int wlo = (tid >> 2) * Cc + ((tid & 3) ^ ((tid >> 3) & 3)) * 8;
    const int wds = tid * 8;                     // lane's LDS slot base (elems)

#define ISSUE_W(kt, cw, nb) do {                                               \
    _Pragma("unroll")                                                          \
    for (int i_ = 0; i_ < 4; ++i_) {                                           \
        const f16* g_ = wT2 + wlo + ((size_t)((kt) * 256 + i_ * 64)) * Cc + (cw) * 32; \
        __builtin_amdgcn_global_load_lds(                                      \
            (const __attribute__((address_space(1))) void*)g_,                 \
            (__attribute__((address_space(3))) void*)&s_w[nb][i_ * 2048 + wds],\
            16, 0, 0);                                                         \
    }                                                                          \
} while (0)

// 4 lanes (cg=0..3) of pixel ps read contiguous 64B per corner
#define ISSUE_C(dst, idv, co) do {                                             \
    (dst)[0] = *(const f16x8*)(xb + (size_t)(idv).x * Cc + (co) + cg * 8);     \
    (dst)[1] = *(const f16x8*)(xb + (size_t)(idv).y * Cc + (co) + cg * 8);     \
    (dst)[2] = *(const f16x8*)(xb + (size_t)(idv).z * Cc + (co) + cg * 8);     \
    (dst)[3] = *(const f16x8*)(xb + (size_t)(idv).w * Cc + (co) + cg * 8);     \
} while (0)

#define BLEND_WRITE(src, wvv, nb) do {                                         \
    f16x8 sv_;                                                                 \
    _Pragma("unroll")                                                          \
    for (int j_ = 0; j_ < 8; ++j_) {                                           \
        float s_ = (wvv).x * (float)(src)[0][j_] + (wvv).y * (float)(src)[1][j_]\
                 + (wvv).z * (float)(src)[2][j_] + (wvv).w * (float)(src)[3][j_];\
        sv_[j_] = (f16)s_;                                                     \
    }                                                                          \
    *(f16x8*)&s_s[nb][ps * 32 + qs] = sv_;                                     \
} while (0)

    f32x4 acc[4][3];
#pragma unroll
    for (int mi = 0; mi < 4; ++mi)
#pragma unroll
        for (int ni = 0; ni < 3; ++ni) acc[mi][ni] = (f32x4){0.f, 0.f, 0.f, 0.f};

    f16x8 c4[4];                 // single corner buffer (next chunk's corners)
    int4 id;
    float4 wv;
    int4 idN;
    float4 wvN;
    if (sampler) {
        id = idx4t[p0 + ps];
        wv = wt4t[p0 + ps];
    }

    // prologue: all waves stage W(chunk0); samplers fill s_s[0] and leave
    // C(chunk1) in flight; wave 3 drains its W with vmcnt(0).
    ISSUE_W(0, 0, 0);
    SB();
    if (sampler) {
        ISSUE_C(c4, id, 0);                // corners for chunk 0
        BLEND_WRITE(c4, wv, 0);            // counted vmcnt retires W(0)+C(0)
        ISSUE_C(c4, id, 32);               // corners for chunk 1
        asm volatile("s_waitcnt lgkmcnt(0)" ::: "memory"); SB();
    } else {
        asm volatile("s_waitcnt vmcnt(0)" ::: "memory"); SB();
    }
    __builtin_amdgcn_s_barrier(); SB();

    for (int k = 0; k < 9; ++k) {
        const int kn = (k < 8) ? k + 1 : 8;
#pragma unroll
        for (int ch = 0; ch < 8; ++ch) {
            const int bb = ch & 1, nb = bb ^ 1;
            f16x8 bf[3];
#pragma unroll
            for (int ni = 0; ni < 3; ++ni)
                bf[ni] = *(const f16x8*)&s_s[bb][(ni * 16 + (lane & 15)) * 32 + qa];
            if (sampler) {
                if (ch == 5) {             // late load: lifetime ch5..ch8 only
                    idN = idx4t[(size_t)kn * PIX + p0 + ps];
                    wvN = wt4t[(size_t)kn * PIX + p0 + ps];
                }
                ISSUE_W((ch == 7) ? kn : k, (ch + 1) & 7, nb);
                SB();
                // blend corners for chunk t+1 (issued last chunk; counted vmcnt)
                {
                    const float4 wvu = (ch == 7) ? wvN : wv;
                    BLEND_WRITE(c4, wvu, nb);
                }
                // corners for chunk t+2 into the SAME regs (WAR after blend);
                // at ch>=6 idN is ready (ch5's vmcnt(4) retired it)
                {
                    const int4 idu = (ch >= 6) ? idN : id;
                    ISSUE_C(c4, idu, ((ch + 2) & 7) * 32);
                }
                asm volatile("s_waitcnt lgkmcnt(0)" ::: "memory"); SB();
            } else {
                ISSUE_W((ch == 7) ? kn : k, (ch + 1) & 7, nb);
                SB();
                asm volatile("s_waitcnt lgkmcnt(0)" ::: "memory"); SB();
            }
            // MFMAs: af streamed per-mi (peak frag-live bounded)
#pragma unroll
            for (int mi = 0; mi < 4; ++mi) {
                f16x8 af = *(const f16x8*)&s_w[bb][(wid * 64 + mi * 16 + (lane & 15)) * 32 + qa];
#pragma unroll
                for (int ni = 0; ni < 3; ++ni)
                    acc[mi][ni] = __builtin_amdgcn_mfma_f32_16x16x32_f16(
                        af, bf[ni], acc[mi][ni], 0, 0, 0);
            }
            // RACE-FREE POINT: drain this wave's W(t+1) writes before the
            // barrier. Samplers: queue = [W x4 oldest (+id/wv at ch5), C x4]
            // -> vmcnt(4). Wave 3: queue = [W x4] -> vmcnt(0).
            if (sampler) {
                asm volatile("s_waitcnt vmcnt(4)" ::: "memory"); SB();
            } else {
                asm volatile("s_waitcnt vmcnt(0)" ::: "memory"); SB();
            }
            __builtin_amdgcn_s_barrier(); SB();
        }
        if (sampler) { id = idN; wv = wvN; }
    }

    // epilogue: ReLU; D row = output = (lane>>4)*4+j, col = pixel = lane&15
    if (!last) {
#pragma unroll
        for (int ni = 0; ni < 3; ++ni) {
            const int p = p0 + ni * 16 + (lane & 15);
#pragma unroll
            for (int mi = 0; mi < 4; ++mi) {
                const int o0 = wid * 64 + mi * 16 + (lane >> 4) * 4;
                f32x4 v = acc[mi][ni];
                f16x4 h = {(f16)fmaxf(v[0], 0.f), (f16)fmaxf(v[1], 0.f),
                           (f16)fmaxf(v[2], 0.f), (f16)fmaxf(v[3], 0.f)};
                *(f16x4*)&o16[(size_t)p * Cc + o0] = h;
            }
        }
    } else {
        const int bimg = imgb / HW;
#pragma unroll
        for (int ni = 0; ni < 3; ++ni) {
            const int p = p0 + ni * 16 + (lane & 15);
            const int hwl = p - imgb;
#pragma unroll
            for (int mi = 0; mi < 4; ++mi) {
                const int o0 = wid * 64 + mi * 16 + (lane >> 4) * 4;
#pragma unroll
                for (int j = 0; j < 4; ++j)
                    oN[((size_t)(bimg * Cc + o0 + j)) * HW + hwl] =
                        fmaxf(acc[mi][ni][j], 0.f);
            }
        }
    }
#undef ISSUE_W
#undef ISSUE_C
#undef BLEND_WRITE
}

extern "C" void kernel_launch(void* const* d_in, const int* in_sizes, int n_in,
                              void* d_out, int out_size, void* d_ws, size_t ws_size,
                              hipStream_t stream)
{
    const float* x0 = (const float*)d_in[0];
    float* out = (float*)d_out;

    f16*   x16a = (f16*)d_ws;                          // PIX*Cc f16
    f16*   x16b = x16a + (size_t)PIX * Cc;             // PIX*Cc f16
    f16*   wT2  = x16b + (size_t)PIX * Cc;             // CK*Cc f16
    f16*   woffT = wT2 + (size_t)CK * Cc;              // 9*32*256 f16
    int4*  idx4t = (int4*)(woffT + (size_t)9 * 32 * Cc);
    float4* wt4t = (float4*)(idx4t + (size_t)KK * PIX);

    nhwc_prep_kernel<<<dim3(HW / 64, Cc / 64, Bc), 256, 0, stream>>>(x0, x16a);

    const f16* xin = x16a;
    for (int L = 0; L < 3; ++L) {
        const float* w_off = (const float*)d_in[1 + 3 * L];
        const float* b_off = (const float*)d_in[2 + 3 * L];
        const float* w     = (const float*)d_in[3 + 3 * L];
        const int last = (L == 2);
        f16* xo = (L == 0) ? x16b : x16a;

        transpose_w_kernel<<<(CK * Cc) / 256, 256, 0, stream>>>(w, wT2);
        woff_prep_kernel<<<(9 * 32 * Cc) / 256, 256, 0, stream>>>(w_off, woffT);
        conv_off_mfma_kernel<<<PIX / 64, 256, 0, stream>>>(xin, woffT, b_off, idx4t, wt4t);
        deform_mfma_kernel<<<PIX / 48, 256, 0, stream>>>(
            xin, wT2, idx4t, wt4t, xo, out, last);

        xin = xo;
    }
}

// Round 17
// 336.213 us; speedup vs baseline: 1.5803x; 1.1323x over previous
//
#include <hip/hip_runtime.h>

#define Hc 96
#define Wc 96
#define Cc 256
#define Bc 4
#define KK 9
#define HW 9216          // Hc*Wc
#define PIX 36864        // Bc*HW
#define CK 2304          // Cc*KK

typedef _Float16 f16;
typedef __attribute__((ext_vector_type(4))) _Float16 f16x4;
typedef __attribute__((ext_vector_type(8))) _Float16 f16x8;
typedef __attribute__((ext_vector_type(4))) float f32x4;

__device__ __forceinline__ int clampi(int v, int lo, int hi) {
    return v < lo ? lo : (v > hi ? hi : v);
}

#define SB() __builtin_amdgcn_sched_barrier(0)

// ---------- prep: NCHW fp32 -> NHWC f16 (layer 0 input) ----------
__global__ __launch_bounds__(256) void nhwc_prep_kernel(
    const float* __restrict__ x0, f16* __restrict__ x16)
{
    __shared__ float st[64][65];
    const int hw0 = blockIdx.x * 64;
    const int c0  = blockIdx.y * 64;
    const int b   = blockIdx.z;
    const int tid = threadIdx.x;
    const int a = tid & 63, r = tid >> 6;
#pragma unroll
    for (int it = 0; it < 16; ++it) {
        int cl = it * 4 + r;
        st[cl][a] = x0[((size_t)(b * Cc + c0 + cl)) * HW + hw0 + a];
    }
    __syncthreads();
#pragma unroll
    for (int it = 0; it < 16; ++it) {
        int hwl = it * 4 + r;
        x16[((size_t)(b * HW + hw0 + hwl)) * Cc + c0 + a] = (f16)st[a][hwl];
    }
}

// wT2[(k*256 + o)*256 + c] = (f16) w[(o*256 + c)*9 + k]
__global__ __launch_bounds__(256) void transpose_w_kernel(
    const float* __restrict__ w, f16* __restrict__ wT2)
{
    int u = blockIdx.x * 256 + threadIdx.x;   // < 589824
    int c = u & 255, o = (u >> 8) & 255, k = u >> 16;
    wT2[u] = (f16)w[(o * Cc + c) * KK + k];
}

// woffT[(k*32 + j)*256 + c] = (f16) w_off[(j*256 + c)*9 + k], rows 18..31 = 0
__global__ __launch_bounds__(256) void woff_prep_kernel(
    const float* __restrict__ w_off, f16* __restrict__ woffT)
{
    int u = blockIdx.x * 256 + threadIdx.x;   // < 73728
    int c = u & 255, j = (u >> 8) & 31, k = u >> 13;
    float v = (j < 18) ? w_off[((size_t)j * Cc + c) * KK + k] : 0.f;
    woffT[u] = (f16)v;
}

// bilinear decomposition for one tap -> idx4/wt4 (tap-major layout)
__device__ __forceinline__ void store_tap(int k, int h, int w, float offy, float offx,
    int p, int4* __restrict__ idx4t, float4* __restrict__ wt4t)
{
    float py = (float)(h - 1 + k / 3) + offy;
    float px = (float)(w - 1 + k % 3) + offx;
    float y0f = floorf(py), x0f = floorf(px);
    float wy = py - y0f, wx = px - x0f;
    int iy0 = (int)y0f, ix0 = (int)x0f;
    float vy0 = (y0f >= 0.f && y0f <= 95.f) ? 1.f : 0.f;
    float vy1 = (y0f + 1.f >= 0.f && y0f + 1.f <= 95.f) ? 1.f : 0.f;
    float vx0 = (x0f >= 0.f && x0f <= 95.f) ? 1.f : 0.f;
    float vx1 = (x0f + 1.f >= 0.f && x0f + 1.f <= 95.f) ? 1.f : 0.f;
    int cy0 = clampi(iy0, 0, 95), cy1 = clampi(iy0 + 1, 0, 95);
    int cx0 = clampi(ix0, 0, 95), cx1 = clampi(ix0 + 1, 0, 95);
    idx4t[(size_t)k * PIX + p] = make_int4(cy0 * Wc + cx0, cy0 * Wc + cx1,
                                           cy1 * Wc + cx0, cy1 * Wc + cx1);
    wt4t[(size_t)k * PIX + p] = make_float4((1.f - wy) * (1.f - wx) * vy0 * vx0,
                                            (1.f - wy) * wx * vy0 * vx1,
                                            wy * (1.f - wx) * vy1 * vx0,
                                            wy * wx * vy1 * vx1);
}

// Offset conv as f16 MFMA GEMM, reg-staged double-buffered pipeline.
// Block: 256 threads (4 waves = 2M x 2N), tile 32 out x 64 pixels. 576 blocks.
__global__ __launch_bounds__(256) void conv_off_mfma_kernel(
    const f16* __restrict__ x16, const f16* __restrict__ woffT,
    const float* __restrict__ b_off,
    int4* __restrict__ idx4t, float4* __restrict__ wt4t)
{
    __shared__ __align__(16) f16 s_a[2][32 * 32];   // 2 x 2KB
    __shared__ __align__(16) f16 s_b[2][64 * 32];   // 2 x 4KB
    const int bid = blockIdx.x;
    const int swz = (bid & 7) * 72 + (bid >> 3);    // 576 blocks, XCD-chunked
    const int p0 = swz * 64;
    const int imgb = (p0 / HW) * HW;
    const int tid = threadIdx.x, lane = tid & 63, wid = tid >> 6;
    const int wm = wid >> 1, wn = wid & 1;
    const int qa = ((lane >> 4) ^ ((lane >> 1) & 3)) * 8;
    // A-stage mapping: row/col-quad
    const int arow = tid >> 3, acb = tid & 7;
    const int adst = arow * 32 + (((acb >> 1) ^ ((arow >> 1) & 3)) * 8) + (acb & 1) * 4;
    // B-stage mapping: 4 lanes per pixel (coalesced 64B), pixel ps, group cg
    const int ps = tid >> 2, cg = tid & 3;
    const int bdst = ps * 32 + ((cg ^ ((ps >> 1) & 3)) * 8);
    const int hwp = p0 + ps - imgb;
    const int hp = hwp / Wc, wp = hwp - hp * Wc;

#define CLOAD(q, aD, bD) do {                                                  \
    int p2_ = (q) > 71 ? 71 : (q);                                             \
    int k2_ = p2_ >> 3, c2_ = p2_ & 7;                                         \
    int ky_ = k2_ / 3, kx_ = k2_ - ky_ * 3;                                    \
    int yy_ = hp + ky_ - 1, xx_ = wp + kx_ - 1;                                \
    bool v_ = (yy_ >= 0 && yy_ < Hc && xx_ >= 0 && xx_ < Wc);                  \
    aD = *(const f16x4*)(woffT + ((size_t)(k2_ * 32 + arow)) * Cc + c2_ * 32 + acb * 4); \
    f16x8 t_ = {0, 0, 0, 0, 0, 0, 0, 0};                                       \
    if (v_) t_ = *(const f16x8*)(x16 + ((size_t)(imgb + yy_ * Wc + xx_)) * Cc + c2_ * 32 + cg * 8); \
    bD = t_;                                                                   \
} while (0)

    f32x4 acc[2];
    acc[0] = (f32x4){0.f, 0.f, 0.f, 0.f};
    acc[1] = (f32x4){0.f, 0.f, 0.f, 0.f};

    f16x4 aR0, aR1;
    f16x8 bR0, bR1;
    // prologue: phase 0 -> slot0 -> s[0]; phase 1 -> slot1 (held in regs)
    CLOAD(0, aR0, bR0);
    CLOAD(1, aR1, bR1);
    *(f16x4*)&s_a[0][adst] = aR0;
    *(f16x8*)&s_b[0][bdst] = bR0;
    asm volatile("s_waitcnt lgkmcnt(0)" ::: "memory"); SB();
    __builtin_amdgcn_s_barrier(); SB();

#define CBODY(p, aCur, bCur, aNxt, bNxt, bc, bn) do {                          \
    f16x8 af = *(const f16x8*)&s_a[bc][(wm * 16 + (lane & 15)) * 32 + qa];     \
    f16x8 bf0 = *(const f16x8*)&s_b[bc][(wn * 32 + (lane & 15)) * 32 + qa];    \
    f16x8 bf1 = *(const f16x8*)&s_b[bc][(wn * 32 + 16 + (lane & 15)) * 32 + qa];\
    CLOAD((p) + 2, aCur, bCur);                                                \
    acc[0] = __builtin_amdgcn_mfma_f32_16x16x32_f16(af, bf0, acc[0], 0, 0, 0); \
    acc[1] = __builtin_amdgcn_mfma_f32_16x16x32_f16(af, bf1, acc[1], 0, 0, 0); \
    *(f16x4*)&s_a[bn][adst] = aNxt;                                            \
    *(f16x8*)&s_b[bn][bdst] = bNxt;                                            \
    asm volatile("s_waitcnt lgkmcnt(0)" ::: "memory"); SB();                   \
    __builtin_amdgcn_s_barrier(); SB();                                        \
} while (0)

    for (int p = 0; p < 72; p += 2) {
        CBODY(p,     aR0, bR0, aR1, bR1, 0, 1);
        CBODY(p + 1, aR1, bR1, aR0, bR0, 1, 0);
    }

    // epilogue: wm=0 -> taps 0..7 (rows 4g..4g+3), wm=1 -> tap 8 (rows 16,17)
    const int g = lane >> 4;
#pragma unroll
    for (int ni = 0; ni < 2; ++ni) {
        const int p = p0 + wn * 32 + ni * 16 + (lane & 15);
        const int hwq = p - imgb;
        const int hq = hwq / Wc, wq = hwq - hq * Wc;
        if (wm == 0) {
            store_tap(2 * g,     hq, wq, acc[ni][0] + b_off[4 * g],
                                         acc[ni][1] + b_off[4 * g + 1], p, idx4t, wt4t);
            store_tap(2 * g + 1, hq, wq, acc[ni][2] + b_off[4 * g + 2],
                                         acc[ni][3] + b_off[4 * g + 3], p, idx4t, wt4t);
        } else if (g == 0) {
            store_tap(8, hq, wq, acc[ni][0] + b_off[16],
                                 acc[ni][1] + b_off[17], p, idx4t, wt4t);
        }
    }
#undef CLOAD
#undef CBODY
}

// Fused deformable sampling (f16 NHWC gathers) + f16 MFMA GEMM + ReLU.
// Block: 768 threads (12 waves), tile 256 out x 144 pix; wave = 64out x 48pix
// (wo = wid&3 out-group, wp = wid>>2 pix-group; per-wave work IDENTICAL to
// the passing R16 kernel: acc 4x3 f32x4 = 48 regs, same swizzles).
// Grid = PIX/144 = 256 = exactly 1 block/CU -> the CU's weight stream is
// staged ONCE per chunk instead of 3x (R16's 3 blocks/CU each streamed the
// same 16KB): L2 segment-requests/chunk-round 1344 -> 832 (-38%), which is
// the measured bottleneck (R16: occupancy +60% moved time only 3%).
// Samplers = waves 0-8 (144 px x 4 grps). Weight staging: 1024 lane-loads
// over 768 threads - waves 0-3 take 2, waves 4-11 take 1 (wave-uniform).
// Race-free discipline per R15/R16: every wave drains its own W(t+1) writes
// BEFORE the end-of-chunk barrier - samplers vmcnt(4) (leaves C(t+2) x4),
// non-samplers vmcnt(0).
__global__ __launch_bounds__(768, 3) void deform_mfma_kernel(
    const f16* __restrict__ x16, const f16* __restrict__ wT2,
    const int4* __restrict__ idx4t, const float4* __restrict__ wt4t,
    f16* __restrict__ o16, float* __restrict__ oN, int last)
{
    __shared__ __align__(16) f16 s_w[2][8192];  // 2 x 16KB [o(256)][kk(32)] swz
    __shared__ __align__(16) f16 s_s[2][4608];  // 2 x 9KB  [pix(144)][kk(32)] swz

    const int bid = blockIdx.x;
    const int swz = (bid & 7) * 32 + (bid >> 3); // 256 blocks, XCD-chunked
    const int p0 = swz * 144;                    // 9216/144=64 -> no straddle
    const int imgb = (p0 / HW) * HW;
    const int tid = threadIdx.x, lane = tid & 63, wid = tid >> 6;
    const int wo = wid & 3, wp = wid >> 2;       // out-group, pix-group
    const bool sampler = (wid < 9);              // tids 0..575 <=> ps 0..143
    const int ps = tid >> 2, cg = tid & 3;
    const int qa = ((lane >> 4) ^ ((lane >> 1) & 3)) * 8;
    const int qs = (cg ^ ((ps >> 1) & 3)) * 8;
    const f16* xb = x16 + (size_t)imgb * Cc;
    // hoisted lane-variant part of the weight-stage address (elements);
    // for u1 = 768+tid the colq term is unchanged (768>>3=96, 96&3=0)
    const int wlo = (tid >> 2) * Cc + ((tid & 3) ^ ((tid >> 3) & 3)) * 8;
    const int wds = tid * 8;                     // u0 LDS slot base (elems)

// stage 16KB weights for (tap kt, chunk cw) -> buf nb.
// u0 = tid (all 768); u1 = 768 + tid (tids 0..255 only, wave-uniform).
#define ISSUE_W(kt, cw, nb) do {                                               \
    const f16* g0_ = wT2 + wlo + ((size_t)((kt) * 256)) * Cc + (cw) * 32;      \
    __builtin_amdgcn_global_load_lds(                                          \
        (const __attribute__((address_space(1))) void*)g0_,                    \
        (__attribute__((address_space(3))) void*)&s_w[nb][wds], 16, 0, 0);     \
    if (wid < 4) {                                                             \
        const f16* g1_ = wT2 + wlo + ((size_t)((kt) * 256 + 192)) * Cc + (cw) * 32; \
        __builtin_amdgcn_global_load_lds(                                      \
            (const __attribute__((address_space(1))) void*)g1_,                \
            (__attribute__((address_space(3))) void*)&s_w[nb][6144 + wds], 16, 0, 0); \
    }                                                                          \
} while (0)

// 4 lanes (cg=0..3) of pixel ps read contiguous 64B per corner
#define ISSUE_C(dst, idv, co) do {                                             \
    (dst)[0] = *(const f16x8*)(xb + (size_t)(idv).x * Cc + (co) + cg * 8);     \
    (dst)[1] = *(const f16x8*)(xb + (size_t)(idv).y * Cc + (co) + cg * 8);     \
    (dst)[2] = *(const f16x8*)(xb + (size_t)(idv).z * Cc + (co) + cg * 8);     \
    (dst)[3] = *(const f16x8*)(xb + (size_t)(idv).w * Cc + (co) + cg * 8);     \
} while (0)

#define BLEND_WRITE(src, wvv, nb) do {                                         \
    f16x8 sv_;                                                                 \
    _Pragma("unroll")                                                          \
    for (int j_ = 0; j_ < 8; ++j_) {                                           \
        float s_ = (wvv).x * (float)(src)[0][j_] + (wvv).y * (float)(src)[1][j_]\
                 + (wvv).z * (float)(src)[2][j_] + (wvv).w * (float)(src)[3][j_];\
        sv_[j_] = (f16)s_;                                                     \
    }                                                                          \
    *(f16x8*)&s_s[nb][ps * 32 + qs] = sv_;                                     \
} while (0)

    f32x4 acc[4][3];
#pragma unroll
    for (int mi = 0; mi < 4; ++mi)
#pragma unroll
        for (int ni = 0; ni < 3; ++ni) acc[mi][ni] = (f32x4){0.f, 0.f, 0.f, 0.f};

    f16x8 c4[4];                 // single corner buffer (next chunk's corners)
    int4 id;
    float4 wv;
    int4 idN;
    float4 wvN;
    if (sampler) {
        id = idx4t[p0 + ps];
        wv = wt4t[p0 + ps];
    }

    // prologue: all waves stage their share of W(chunk0); samplers fill
    // s_s[0] and leave C(chunk1) in flight; non-samplers drain W.
    ISSUE_W(0, 0, 0);
    SB();
    if (sampler) {
        ISSUE_C(c4, id, 0);                // corners for chunk 0
        BLEND_WRITE(c4, wv, 0);            // counted vmcnt retires W+C(0)
        ISSUE_C(c4, id, 32);               // corners for chunk 1
        asm volatile("s_waitcnt lgkmcnt(0)" ::: "memory"); SB();
    } else {
        asm volatile("s_waitcnt vmcnt(0)" ::: "memory"); SB();
    }
    __builtin_amdgcn_s_barrier(); SB();

    for (int k = 0; k < 9; ++k) {
        const int kn = (k < 8) ? k + 1 : 8;
#pragma unroll
        for (int ch = 0; ch < 8; ++ch) {
            const int bb = ch & 1, nb = bb ^ 1;
            f16x8 bf[3];
#pragma unroll
            for (int ni = 0; ni < 3; ++ni)
                bf[ni] = *(const f16x8*)&s_s[bb][(wp * 48 + ni * 16 + (lane & 15)) * 32 + qa];
            if (sampler) {
                if (ch == 5) {             // late load: lifetime ch5..ch8 only
                    idN = idx4t[(size_t)kn * PIX + p0 + ps];
                    wvN = wt4t[(size_t)kn * PIX + p0 + ps];
                }
                ISSUE_W((ch == 7) ? kn : k, (ch + 1) & 7, nb);
                SB();
                // blend corners for chunk t+1 (issued last chunk; counted vmcnt)
                {
                    const float4 wvu = (ch == 7) ? wvN : wv;
                    BLEND_WRITE(c4, wvu, nb);
                }
                // corners for chunk t+2 into the SAME regs (WAR after blend);
                // at ch>=6 idN is ready (ch5's vmcnt(4) retired it)
                {
                    const int4 idu = (ch >= 6) ? idN : id;
                    ISSUE_C(c4, idu, ((ch + 2) & 7) * 32);
                }
                asm volatile("s_waitcnt lgkmcnt(0)" ::: "memory"); SB();
            } else {
                ISSUE_W((ch == 7) ? kn : k, (ch + 1) & 7, nb);
                SB();
                asm volatile("s_waitcnt lgkmcnt(0)" ::: "memory"); SB();
            }
            // MFMAs: af streamed per-mi (peak frag-live bounded)
#pragma unroll
            for (int mi = 0; mi < 4; ++mi) {
                f16x8 af = *(const f16x8*)&s_w[bb][(wo * 64 + mi * 16 + (lane & 15)) * 32 + qa];
#pragma unroll
                for (int ni = 0; ni < 3; ++ni)
                    acc[mi][ni] = __builtin_amdgcn_mfma_f32_16x16x32_f16(
                        af, bf[ni], acc[mi][ni], 0, 0, 0);
            }
            // RACE-FREE POINT: drain this wave's W(t+1) writes before the
            // barrier. Samplers: queue = [(id/wv at ch5,) W x1-2 old, C x4]
            // -> vmcnt(4). Non-samplers: queue = [W x1] -> vmcnt(0).
            if (sampler) {
                asm volatile("s_waitcnt vmcnt(4)" ::: "memory"); SB();
            } else {
                asm volatile("s_waitcnt vmcnt(0)" ::: "memory"); SB();
            }
            __builtin_amdgcn_s_barrier(); SB();
        }
        if (sampler) { id = idN; wv = wvN; }
    }

    // epilogue: ReLU; D row = output = (lane>>4)*4+j, col = pixel = lane&15
    if (!last) {
#pragma unroll
        for (int ni = 0; ni < 3; ++ni) {
            const int p = p0 + wp * 48 + ni * 16 + (lane & 15);
#pragma unroll
            for (int mi = 0; mi < 4; ++mi) {
                const int o0 = wo * 64 + mi * 16 + (lane >> 4) * 4;
                f32x4 v = acc[mi][ni];
                f16x4 h = {(f16)fmaxf(v[0], 0.f), (f16)fmaxf(v[1], 0.f),
                           (f16)fmaxf(v[2], 0.f), (f16)fmaxf(v[3], 0.f)};
                *(f16x4*)&o16[(size_t)p * Cc + o0] = h;
            }
        }
    } else {
        const int bimg = imgb / HW;
#pragma unroll
        for (int ni = 0; ni < 3; ++ni) {
            const int p = p0 + wp * 48 + ni * 16 + (lane & 15);
            const int hwl = p - imgb;
#pragma unroll
            for (int mi = 0; mi < 4; ++mi) {
                const int o0 = wo * 64 + mi * 16 + (lane >> 4) * 4;
#pragma unroll
                for (int j = 0; j < 4; ++j)
                    oN[((size_t)(bimg * Cc + o0 + j)) * HW + hwl] =
                        fmaxf(acc[mi][ni][j], 0.f);
            }
        }
    }
#undef ISSUE_W
#undef ISSUE_C
#undef BLEND_WRITE
}

extern "C" void kernel_launch(void* const* d_in, const int* in_sizes, int n_in,
                              void* d_out, int out_size, void* d_ws, size_t ws_size,
                              hipStream_t stream)
{
    const float* x0 = (const float*)d_in[0];
    float* out = (float*)d_out;

    f16*   x16a = (f16*)d_ws;                          // PIX*Cc f16
    f16*   x16b = x16a + (size_t)PIX * Cc;             // PIX*Cc f16
    f16*   wT2  = x16b + (size_t)PIX * Cc;             // CK*Cc f16
    f16*   woffT = wT2 + (size_t)CK * Cc;              // 9*32*256 f16
    int4*  idx4t = (int4*)(woffT + (size_t)9 * 32 * Cc);
    float4* wt4t = (float4*)(idx4t + (size_t)KK * PIX);

    nhwc_prep_kernel<<<dim3(HW / 64, Cc / 64, Bc), 256, 0, stream>>>(x0, x16a);

    const f16* xin = x16a;
    for (int L = 0; L < 3; ++L) {
        const float* w_off = (const float*)d_in[1 + 3 * L];
        const float* b_off = (const float*)d_in[2 + 3 * L];
        const float* w     = (const float*)d_in[3 + 3 * L];
        const int last = (L == 2);
        f16* xo = (L == 0) ? x16b : x16a;

        transpose_w_kernel<<<(CK * Cc) / 256, 256, 0, stream>>>(w, wT2);
        woff_prep_kernel<<<(9 * 32 * Cc) / 256, 256, 0, stream>>>(w_off, woffT);
        conv_off_mfma_kernel<<<PIX / 64, 256, 0, stream>>>(xin, woffT, b_off, idx4t, wt4t);
        deform_mfma_kernel<<<PIX / 144, 768, 0, stream>>>(
            xin, wT2, idx4t, wt4t, xo, out, last);

        xin = xo;
    }
}

// Round 18
// 323.243 us; speedup vs baseline: 1.6437x; 1.0401x over previous
//
#include <hip/hip_runtime.h>

#define Hc 96
#define Wc 96
#define Cc 256
#define Bc 4
#define KK 9
#define HW 9216          // Hc*Wc
#define PIX 36864        // Bc*HW
#define CK 2304          // Cc*KK

typedef _Float16 f16;
typedef __attribute__((ext_vector_type(4))) _Float16 f16x4;
typedef __attribute__((ext_vector_type(8))) _Float16 f16x8;
typedef __attribute__((ext_vector_type(4))) float f32x4;

__device__ __forceinline__ int clampi(int v, int lo, int hi) {
    return v < lo ? lo : (v > hi ? hi : v);
}

#define SB() __builtin_amdgcn_sched_barrier(0)

// ---------- prep: NCHW fp32 -> NHWC f16 (layer 0 input) ----------
__global__ __launch_bounds__(256) void nhwc_prep_kernel(
    const float* __restrict__ x0, f16* __restrict__ x16)
{
    __shared__ float st[64][65];
    const int hw0 = blockIdx.x * 64;
    const int c0  = blockIdx.y * 64;
    const int b   = blockIdx.z;
    const int tid = threadIdx.x;
    const int a = tid & 63, r = tid >> 6;
#pragma unroll
    for (int it = 0; it < 16; ++it) {
        int cl = it * 4 + r;
        st[cl][a] = x0[((size_t)(b * Cc + c0 + cl)) * HW + hw0 + a];
    }
    __syncthreads();
#pragma unroll
    for (int it = 0; it < 16; ++it) {
        int hwl = it * 4 + r;
        x16[((size_t)(b * HW + hw0 + hwl)) * Cc + c0 + a] = (f16)st[a][hwl];
    }
}

// wT2[(k*256 + o)*256 + c] = (f16) w[(o*256 + c)*9 + k]
__global__ __launch_bounds__(256) void transpose_w_kernel(
    const float* __restrict__ w, f16* __restrict__ wT2)
{
    int u = blockIdx.x * 256 + threadIdx.x;   // < 589824
    int c = u & 255, o = (u >> 8) & 255, k = u >> 16;
    wT2[u] = (f16)w[(o * Cc + c) * KK + k];
}

// woffT[(k*32 + j)*256 + c] = (f16) w_off[(j*256 + c)*9 + k], rows 18..31 = 0
__global__ __launch_bounds__(256) void woff_prep_kernel(
    const float* __restrict__ w_off, f16* __restrict__ woffT)
{
    int u = blockIdx.x * 256 + threadIdx.x;   // < 73728
    int c = u & 255, j = (u >> 8) & 31, k = u >> 13;
    float v = (j < 18) ? w_off[((size_t)j * Cc + c) * KK + k] : 0.f;
    woffT[u] = (f16)v;
}

// bilinear decomposition for one tap -> idx4/wt4 (tap-major layout)
__device__ __forceinline__ void store_tap(int k, int h, int w, float offy, float offx,
    int p, int4* __restrict__ idx4t, float4* __restrict__ wt4t)
{
    float py = (float)(h - 1 + k / 3) + offy;
    float px = (float)(w - 1 + k % 3) + offx;
    float y0f = floorf(py), x0f = floorf(px);
    float wy = py - y0f, wx = px - x0f;
    int iy0 = (int)y0f, ix0 = (int)x0f;
    float vy0 = (y0f >= 0.f && y0f <= 95.f) ? 1.f : 0.f;
    float vy1 = (y0f + 1.f >= 0.f && y0f + 1.f <= 95.f) ? 1.f : 0.f;
    float vx0 = (x0f >= 0.f && x0f <= 95.f) ? 1.f : 0.f;
    float vx1 = (x0f + 1.f >= 0.f && x0f + 1.f <= 95.f) ? 1.f : 0.f;
    int cy0 = clampi(iy0, 0, 95), cy1 = clampi(iy0 + 1, 0, 95);
    int cx0 = clampi(ix0, 0, 95), cx1 = clampi(ix0 + 1, 0, 95);
    idx4t[(size_t)k * PIX + p] = make_int4(cy0 * Wc + cx0, cy0 * Wc + cx1,
                                           cy1 * Wc + cx0, cy1 * Wc + cx1);
    wt4t[(size_t)k * PIX + p] = make_float4((1.f - wy) * (1.f - wx) * vy0 * vx0,
                                            (1.f - wy) * wx * vy0 * vx1,
                                            wy * (1.f - wx) * vy1 * vx0,
                                            wy * wx * vy1 * vx1);
}

// Offset conv as f16 MFMA GEMM, reg-staged double-buffered pipeline.
// Block: 256 threads (4 waves = 2M x 2N), tile 32 out x 64 pixels. 576 blocks.
__global__ __launch_bounds__(256) void conv_off_mfma_kernel(
    const f16* __restrict__ x16, const f16* __restrict__ woffT,
    const float* __restrict__ b_off,
    int4* __restrict__ idx4t, float4* __restrict__ wt4t)
{
    __shared__ __align__(16) f16 s_a[2][32 * 32];   // 2 x 2KB
    __shared__ __align__(16) f16 s_b[2][64 * 32];   // 2 x 4KB
    const int bid = blockIdx.x;
    const int swz = (bid & 7) * 72 + (bid >> 3);    // 576 blocks, XCD-chunked
    const int p0 = swz * 64;
    const int imgb = (p0 / HW) * HW;
    const int tid = threadIdx.x, lane = tid & 63, wid = tid >> 6;
    const int wm = wid >> 1, wn = wid & 1;
    const int qa = ((lane >> 4) ^ ((lane >> 1) & 3)) * 8;
    // A-stage mapping: row/col-quad
    const int arow = tid >> 3, acb = tid & 7;
    const int adst = arow * 32 + (((acb >> 1) ^ ((arow >> 1) & 3)) * 8) + (acb & 1) * 4;
    // B-stage mapping: 4 lanes per pixel (coalesced 64B), pixel ps, group cg
    const int ps = tid >> 2, cg = tid & 3;
    const int bdst = ps * 32 + ((cg ^ ((ps >> 1) & 3)) * 8);
    const int hwp = p0 + ps - imgb;
    const int hp = hwp / Wc, wp = hwp - hp * Wc;

#define CLOAD(q, aD, bD) do {                                                  \
    int p2_ = (q) > 71 ? 71 : (q);                                             \
    int k2_ = p2_ >> 3, c2_ = p2_ & 7;                                         \
    int ky_ = k2_ / 3, kx_ = k2_ - ky_ * 3;                                    \
    int yy_ = hp + ky_ - 1, xx_ = wp + kx_ - 1;                                \
    bool v_ = (yy_ >= 0 && yy_ < Hc && xx_ >= 0 && xx_ < Wc);                  \
    aD = *(const f16x4*)(woffT + ((size_t)(k2_ * 32 + arow)) * Cc + c2_ * 32 + acb * 4); \
    f16x8 t_ = {0, 0, 0, 0, 0, 0, 0, 0};                                       \
    if (v_) t_ = *(const f16x8*)(x16 + ((size_t)(imgb + yy_ * Wc + xx_)) * Cc + c2_ * 32 + cg * 8); \
    bD = t_;                                                                   \
} while (0)

    f32x4 acc[2];
    acc[0] = (f32x4){0.f, 0.f, 0.f, 0.f};
    acc[1] = (f32x4){0.f, 0.f, 0.f, 0.f};

    f16x4 aR0, aR1;
    f16x8 bR0, bR1;
    // prologue: phase 0 -> slot0 -> s[0]; phase 1 -> slot1 (held in regs)
    CLOAD(0, aR0, bR0);
    CLOAD(1, aR1, bR1);
    *(f16x4*)&s_a[0][adst] = aR0;
    *(f16x8*)&s_b[0][bdst] = bR0;
    asm volatile("s_waitcnt lgkmcnt(0)" ::: "memory"); SB();
    __builtin_amdgcn_s_barrier(); SB();

#define CBODY(p, aCur, bCur, aNxt, bNxt, bc, bn) do {                          \
    f16x8 af = *(const f16x8*)&s_a[bc][(wm * 16 + (lane & 15)) * 32 + qa];     \
    f16x8 bf0 = *(const f16x8*)&s_b[bc][(wn * 32 + (lane & 15)) * 32 + qa];    \
    f16x8 bf1 = *(const f16x8*)&s_b[bc][(wn * 32 + 16 + (lane & 15)) * 32 + qa];\
    CLOAD((p) + 2, aCur, bCur);                                                \
    acc[0] = __builtin_amdgcn_mfma_f32_16x16x32_f16(af, bf0, acc[0], 0, 0, 0); \
    acc[1] = __builtin_amdgcn_mfma_f32_16x16x32_f16(af, bf1, acc[1], 0, 0, 0); \
    *(f16x4*)&s_a[bn][adst] = aNxt;                                            \
    *(f16x8*)&s_b[bn][bdst] = bNxt;                                            \
    asm volatile("s_waitcnt lgkmcnt(0)" ::: "memory"); SB();                   \
    __builtin_amdgcn_s_barrier(); SB();                                        \
} while (0)

    for (int p = 0; p < 72; p += 2) {
        CBODY(p,     aR0, bR0, aR1, bR1, 0, 1);
        CBODY(p + 1, aR1, bR1, aR0, bR0, 1, 0);
    }

    // epilogue: wm=0 -> taps 0..7 (rows 4g..4g+3), wm=1 -> tap 8 (rows 16,17)
    const int g = lane >> 4;
#pragma unroll
    for (int ni = 0; ni < 2; ++ni) {
        const int p = p0 + wn * 32 + ni * 16 + (lane & 15);
        const int hwq = p - imgb;
        const int hq = hwq / Wc, wq = hwq - hq * Wc;
        if (wm == 0) {
            store_tap(2 * g,     hq, wq, acc[ni][0] + b_off[4 * g],
                                         acc[ni][1] + b_off[4 * g + 1], p, idx4t, wt4t);
            store_tap(2 * g + 1, hq, wq, acc[ni][2] + b_off[4 * g + 2],
                                         acc[ni][3] + b_off[4 * g + 3], p, idx4t, wt4t);
        } else if (g == 0) {
            store_tap(8, hq, wq, acc[ni][0] + b_off[16],
                                 acc[ni][1] + b_off[17], p, idx4t, wt4t);
        }
    }
#undef CLOAD
#undef CBODY
}

// Fused deformable sampling (f16 NHWC gathers) + f16 MFMA GEMM + ReLU.
// Block: 768 threads (12 waves), tile 256 out x 144 pix; wave = 64out x 48pix.
// K=64 per chunk (two 32-chan halves, existing swizzle verbatim) -> 36 chunks
// (9 taps x 4), HALF the barriers/waits of R17's 72. LDS 100KB (1 block/CU;
// grid = 256 = exactly 1/CU so nothing is lost). Roles as R17: samplers =
// waves 0-8, weight staging spread waves 0-3 x2-per-half / others x1.
// vmcnt per class (R15-proven race-free: drain own W BEFORE the barrier):
// samplers end-of-chunk queue = [W x2..4 oldest, C(t+2) x8] -> vmcnt(8);
// non-samplers [W x2] -> vmcnt(0). idN/wvN at ch==1 (retired by ch1's
// vmcnt(8) before ch2 use). Blend waits are compiler-counted.
__global__ __launch_bounds__(768, 3) void deform_mfma_kernel(
    const f16* __restrict__ x16, const f16* __restrict__ wT2,
    const int4* __restrict__ idx4t, const float4* __restrict__ wt4t,
    f16* __restrict__ o16, float* __restrict__ oN, int last)
{
    __shared__ __align__(16) f16 s_w[2][2][8192];  // [buf][half][256o x 32c swz] 64KB
    __shared__ __align__(16) f16 s_s[2][2][4608];  // [buf][half][144p x 32c swz] 36KB

    const int bid = blockIdx.x;
    const int swz = (bid & 7) * 32 + (bid >> 3); // 256 blocks, XCD-chunked
    const int p0 = swz * 144;                    // 9216/144=64 -> no straddle
    const int imgb = (p0 / HW) * HW;
    const int tid = threadIdx.x, lane = tid & 63, wid = tid >> 6;
    const int wo = wid & 3, wp = wid >> 2;       // out-group, pix-group
    const bool sampler = (wid < 9);              // tids 0..575 <=> ps 0..143
    const int ps = tid >> 2, cg = tid & 3;
    const int qa = ((lane >> 4) ^ ((lane >> 1) & 3)) * 8;
    const int qs = (cg ^ ((ps >> 1) & 3)) * 8;
    const f16* xb = x16 + (size_t)imgb * Cc;
    // hoisted lane-variant part of the weight-stage address (elements);
    // for u1 = 768+tid the colq term is unchanged (768>>3=96, 96&3=0)
    const int wlo = (tid >> 2) * Cc + ((tid & 3) ^ ((tid >> 3) & 3)) * 8;
    const int wds = tid * 8;                     // u0 LDS slot base (elems)

// stage 16KB weights (one 32-chan half) for (tap kt, chunk cq, half h) -> nb
#define ISSUE_W(kt, cq, h, nb) do {                                            \
    const f16* g0_ = wT2 + wlo + ((size_t)((kt) * 256)) * Cc + (cq) * 64 + (h) * 32; \
    __builtin_amdgcn_global_load_lds(                                          \
        (const __attribute__((address_space(1))) void*)g0_,                    \
        (__attribute__((address_space(3))) void*)&s_w[nb][h][wds], 16, 0, 0);  \
    if (wid < 4) {                                                             \
        const f16* g1_ = wT2 + wlo + ((size_t)((kt) * 256 + 192)) * Cc + (cq) * 64 + (h) * 32; \
        __builtin_amdgcn_global_load_lds(                                      \
            (const __attribute__((address_space(1))) void*)g1_,                \
            (__attribute__((address_space(3))) void*)&s_w[nb][h][6144 + wds], 16, 0, 0); \
    }                                                                          \
} while (0)

// 4 lanes (cg=0..3) of pixel ps read contiguous 64B per corner
#define ISSUE_C(dst, idv, co) do {                                             \
    (dst)[0] = *(const f16x8*)(xb + (size_t)(idv).x * Cc + (co) + cg * 8);     \
    (dst)[1] = *(const f16x8*)(xb + (size_t)(idv).y * Cc + (co) + cg * 8);     \
    (dst)[2] = *(const f16x8*)(xb + (size_t)(idv).z * Cc + (co) + cg * 8);     \
    (dst)[3] = *(const f16x8*)(xb + (size_t)(idv).w * Cc + (co) + cg * 8);     \
} while (0)

#define BLEND_WRITE(src, wvv, h, nb) do {                                      \
    f16x8 sv_;                                                                 \
    _Pragma("unroll")                                                          \
    for (int j_ = 0; j_ < 8; ++j_) {                                           \
        float s_ = (wvv).x * (float)(src)[0][j_] + (wvv).y * (float)(src)[1][j_]\
                 + (wvv).z * (float)(src)[2][j_] + (wvv).w * (float)(src)[3][j_];\
        sv_[j_] = (f16)s_;                                                     \
    }                                                                          \
    *(f16x8*)&s_s[nb][h][ps * 32 + qs] = sv_;                                  \
} while (0)

    f32x4 acc[4][3];
#pragma unroll
    for (int mi = 0; mi < 4; ++mi)
#pragma unroll
        for (int ni = 0; ni < 3; ++ni) acc[mi][ni] = (f32x4){0.f, 0.f, 0.f, 0.f};

    f16x8 c4a[4], c4b[4];        // next chunk's corners, one buffer per half
    int4 id;
    float4 wv;
    int4 idN;
    float4 wvN;
    if (sampler) {
        id = idx4t[p0 + ps];
        wv = wt4t[p0 + ps];
    }

    // prologue: stage W(chunk0) both halves; samplers fill s_s[0][*] from
    // C(chunk0) and leave C(chunk1) x8 in flight; non-samplers drain W.
    ISSUE_W(0, 0, 0, 0);
    ISSUE_W(0, 0, 1, 0);
    SB();
    if (sampler) {
        ISSUE_C(c4a, id, 0);               // chunk0 half0
        ISSUE_C(c4b, id, 32);              // chunk0 half1
        BLEND_WRITE(c4a, wv, 0, 0);        // counted vmcnt retires W+C as needed
        BLEND_WRITE(c4b, wv, 1, 0);
        ISSUE_C(c4a, id, 64);              // chunk1 half0
        ISSUE_C(c4b, id, 96);              // chunk1 half1
        asm volatile("s_waitcnt lgkmcnt(0)" ::: "memory"); SB();
    } else {
        asm volatile("s_waitcnt vmcnt(0)" ::: "memory"); SB();
    }
    __builtin_amdgcn_s_barrier(); SB();

    for (int k = 0; k < 9; ++k) {
        const int kn = (k < 8) ? k + 1 : 8;
#pragma unroll
        for (int ch = 0; ch < 4; ++ch) {   // chunk = 64 chans
            const int bb = ch & 1, nb = bb ^ 1;
            f16x8 bf0[3], bf1[3];
#pragma unroll
            for (int ni = 0; ni < 3; ++ni) {
                bf0[ni] = *(const f16x8*)&s_s[bb][0][(wp * 48 + ni * 16 + (lane & 15)) * 32 + qa];
                bf1[ni] = *(const f16x8*)&s_s[bb][1][(wp * 48 + ni * 16 + (lane & 15)) * 32 + qa];
            }
            if (sampler) {
                if (ch == 1) {             // late load: needed from ch2
                    idN = idx4t[(size_t)kn * PIX + p0 + ps];
                    wvN = wt4t[(size_t)kn * PIX + p0 + ps];
                }
                ISSUE_W((ch == 3) ? kn : k, (ch + 1) & 3, 0, nb);
                ISSUE_W((ch == 3) ? kn : k, (ch + 1) & 3, 1, nb);
                SB();
                // blend corners for chunk t+1 (issued last chunk; counted
                // vmcnt), then reissue same regs for chunk t+2 (WAR)
                {
                    const float4 wvu = (ch == 3) ? wvN : wv;
                    const int4 idu = (ch >= 2) ? idN : id;
                    const int co2 = ((ch + 2) & 3) * 64;
                    BLEND_WRITE(c4a, wvu, 0, nb);
                    ISSUE_C(c4a, idu, co2);
                    BLEND_WRITE(c4b, wvu, 1, nb);
                    ISSUE_C(c4b, idu, co2 + 32);
                }
                asm volatile("s_waitcnt lgkmcnt(0)" ::: "memory"); SB();
            } else {
                ISSUE_W((ch == 3) ? kn : k, (ch + 1) & 3, 0, nb);
                ISSUE_W((ch == 3) ? kn : k, (ch + 1) & 3, 1, nb);
                SB();
                asm volatile("s_waitcnt lgkmcnt(0)" ::: "memory"); SB();
            }
            // MFMAs: 24 (two halves), af streamed per-mi
#pragma unroll
            for (int mi = 0; mi < 4; ++mi) {
                f16x8 af = *(const f16x8*)&s_w[bb][0][(wo * 64 + mi * 16 + (lane & 15)) * 32 + qa];
#pragma unroll
                for (int ni = 0; ni < 3; ++ni)
                    acc[mi][ni] = __builtin_amdgcn_mfma_f32_16x16x32_f16(
                        af, bf0[ni], acc[mi][ni], 0, 0, 0);
            }
#pragma unroll
            for (int mi = 0; mi < 4; ++mi) {
                f16x8 af = *(const f16x8*)&s_w[bb][1][(wo * 64 + mi * 16 + (lane & 15)) * 32 + qa];
#pragma unroll
                for (int ni = 0; ni < 3; ++ni)
                    acc[mi][ni] = __builtin_amdgcn_mfma_f32_16x16x32_f16(
                        af, bf1[ni], acc[mi][ni], 0, 0, 0);
            }
            // RACE-FREE POINT: drain this wave's W(t+1) writes before the
            // barrier. Samplers: queue = [(idwv,) W x2-4 old, C x8] ->
            // vmcnt(8). Non-samplers: [W x2] -> vmcnt(0).
            if (sampler) {
                asm volatile("s_waitcnt vmcnt(8)" ::: "memory"); SB();
            } else {
                asm volatile("s_waitcnt vmcnt(0)" ::: "memory"); SB();
            }
            __builtin_amdgcn_s_barrier(); SB();
        }
        if (sampler) { id = idN; wv = wvN; }
    }

    // epilogue: ReLU; D row = output = (lane>>4)*4+j, col = pixel = lane&15
    if (!last) {
#pragma unroll
        for (int ni = 0; ni < 3; ++ni) {
            const int p = p0 + wp * 48 + ni * 16 + (lane & 15);
#pragma unroll
            for (int mi = 0; mi < 4; ++mi) {
                const int o0 = wo * 64 + mi * 16 + (lane >> 4) * 4;
                f32x4 v = acc[mi][ni];
                f16x4 h = {(f16)fmaxf(v[0], 0.f), (f16)fmaxf(v[1], 0.f),
                           (f16)fmaxf(v[2], 0.f), (f16)fmaxf(v[3], 0.f)};
                *(f16x4*)&o16[(size_t)p * Cc + o0] = h;
            }
        }
    } else {
        const int bimg = imgb / HW;
#pragma unroll
        for (int ni = 0; ni < 3; ++ni) {
            const int p = p0 + wp * 48 + ni * 16 + (lane & 15);
            const int hwl = p - imgb;
#pragma unroll
            for (int mi = 0; mi < 4; ++mi) {
                const int o0 = wo * 64 + mi * 16 + (lane >> 4) * 4;
#pragma unroll
                for (int j = 0; j < 4; ++j)
                    oN[((size_t)(bimg * Cc + o0 + j)) * HW + hwl] =
                        fmaxf(acc[mi][ni][j], 0.f);
            }
        }
    }
#undef ISSUE_W
#undef ISSUE_C
#undef BLEND_WRITE
}

extern "C" void kernel_launch(void* const* d_in, const int* in_sizes, int n_in,
                              void* d_out, int out_size, void* d_ws, size_t ws_size,
                              hipStream_t stream)
{
    const float* x0 = (const float*)d_in[0];
    float* out = (float*)d_out;

    f16*   x16a = (f16*)d_ws;                          // PIX*Cc f16
    f16*   x16b = x16a + (size_t)PIX * Cc;             // PIX*Cc f16
    f16*   wT2  = x16b + (size_t)PIX * Cc;             // CK*Cc f16
    f16*   woffT = wT2 + (size_t)CK * Cc;              // 9*32*256 f16
    int4*  idx4t = (int4*)(woffT + (size_t)9 * 32 * Cc);
    float4* wt4t = (float4*)(idx4t + (size_t)KK * PIX);

    nhwc_prep_kernel<<<dim3(HW / 64, Cc / 64, Bc), 256, 0, stream>>>(x0, x16a);

    const f16* xin = x16a;
    for (int L = 0; L < 3; ++L) {
        const float* w_off = (const float*)d_in[1 + 3 * L];
        const float* b_off = (const float*)d_in[2 + 3 * L];
        const float* w     = (const float*)d_in[3 + 3 * L];
        const int last = (L == 2);
        f16* xo = (L == 0) ? x16b : x16a;

        transpose_w_kernel<<<(CK * Cc) / 256, 256, 0, stream>>>(w, wT2);
        woff_prep_kernel<<<(9 * 32 * Cc) / 256, 256, 0, stream>>>(w_off, woffT);
        conv_off_mfma_kernel<<<PIX / 64, 256, 0, stream>>>(xin, woffT, b_off, idx4t, wt4t);
        deform_mfma_kernel<<<PIX / 144, 768, 0, stream>>>(
            xin, wT2, idx4t, wt4t, xo, out, last);

        xin = xo;
    }
}

// Round 19
// 320.265 us; speedup vs baseline: 1.6590x; 1.0093x over previous
//
#include <hip/hip_runtime.h>

#define Hc 96
#define Wc 96
#define Cc 256
#define Bc 4
#define KK 9
#define HW 9216          // Hc*Wc
#define PIX 36864        // Bc*HW
#define CK 2304          // Cc*KK

typedef _Float16 f16;
typedef __attribute__((ext_vector_type(4))) _Float16 f16x4;
typedef __attribute__((ext_vector_type(8))) _Float16 f16x8;
typedef __attribute__((ext_vector_type(4))) float f32x4;

__device__ __forceinline__ int clampi(int v, int lo, int hi) {
    return v < lo ? lo : (v > hi ? hi : v);
}

#define SB() __builtin_amdgcn_sched_barrier(0)

// ---------- prep: NCHW fp32 -> NHWC f16 (layer 0 input) ----------
__global__ __launch_bounds__(256) void nhwc_prep_kernel(
    const float* __restrict__ x0, f16* __restrict__ x16)
{
    __shared__ float st[64][65];
    const int hw0 = blockIdx.x * 64;
    const int c0  = blockIdx.y * 64;
    const int b   = blockIdx.z;
    const int tid = threadIdx.x;
    const int a = tid & 63, r = tid >> 6;
#pragma unroll
    for (int it = 0; it < 16; ++it) {
        int cl = it * 4 + r;
        st[cl][a] = x0[((size_t)(b * Cc + c0 + cl)) * HW + hw0 + a];
    }
    __syncthreads();
#pragma unroll
    for (int it = 0; it < 16; ++it) {
        int hwl = it * 4 + r;
        x16[((size_t)(b * HW + hw0 + hwl)) * Cc + c0 + a] = (f16)st[a][hwl];
    }
}

// merged weight prep:
//  blocks 0..2303:  wT2[(k*256+o)*256+c] = (f16) w[(o*256+c)*9+k]
//  blocks 2304..2591: woffT[(k*32+j)*256+c] = (f16) w_off[(j*256+c)*9+k] (j<18)
__global__ __launch_bounds__(256) void wprep_kernel(
    const float* __restrict__ w, const float* __restrict__ w_off,
    f16* __restrict__ wT2, f16* __restrict__ woffT)
{
    int b = blockIdx.x;
    if (b < 2304) {
        int u = b * 256 + threadIdx.x;        // < 589824
        int c = u & 255, o = (u >> 8) & 255, k = u >> 16;
        wT2[u] = (f16)w[(o * Cc + c) * KK + k];
    } else {
        int u = (b - 2304) * 256 + threadIdx.x; // < 73728
        int c = u & 255, j = (u >> 8) & 31, k = u >> 13;
        float v = (j < 18) ? w_off[((size_t)j * Cc + c) * KK + k] : 0.f;
        woffT[u] = (f16)v;
    }
}

// bilinear decomposition for one tap -> idx4/wt4 (tap-major layout)
__device__ __forceinline__ void store_tap(int k, int h, int w, float offy, float offx,
    int p, int4* __restrict__ idx4t, float4* __restrict__ wt4t)
{
    float py = (float)(h - 1 + k / 3) + offy;
    float px = (float)(w - 1 + k % 3) + offx;
    float y0f = floorf(py), x0f = floorf(px);
    float wy = py - y0f, wx = px - x0f;
    int iy0 = (int)y0f, ix0 = (int)x0f;
    float vy0 = (y0f >= 0.f && y0f <= 95.f) ? 1.f : 0.f;
    float vy1 = (y0f + 1.f >= 0.f && y0f + 1.f <= 95.f) ? 1.f : 0.f;
    float vx0 = (x0f >= 0.f && x0f <= 95.f) ? 1.f : 0.f;
    float vx1 = (x0f + 1.f >= 0.f && x0f + 1.f <= 95.f) ? 1.f : 0.f;
    int cy0 = clampi(iy0, 0, 95), cy1 = clampi(iy0 + 1, 0, 95);
    int cx0 = clampi(ix0, 0, 95), cx1 = clampi(ix0 + 1, 0, 95);
    idx4t[(size_t)k * PIX + p] = make_int4(cy0 * Wc + cx0, cy0 * Wc + cx1,
                                           cy1 * Wc + cx0, cy1 * Wc + cx1);
    wt4t[(size_t)k * PIX + p] = make_float4((1.f - wy) * (1.f - wx) * vy0 * vx0,
                                            (1.f - wy) * wx * vy0 * vx1,
                                            wy * (1.f - wx) * vy1 * vx0,
                                            wy * wx * vy1 * vx1);
}

// Offset conv as f16 MFMA GEMM, reg-staged double-buffered pipeline.
// Block: 256 threads (4 waves = 2M x 2N), tile 32 out x 64 pixels. 576 blocks.
__global__ __launch_bounds__(256) void conv_off_mfma_kernel(
    const f16* __restrict__ x16, const f16* __restrict__ woffT,
    const float* __restrict__ b_off,
    int4* __restrict__ idx4t, float4* __restrict__ wt4t)
{
    __shared__ __align__(16) f16 s_a[2][32 * 32];   // 2 x 2KB
    __shared__ __align__(16) f16 s_b[2][64 * 32];   // 2 x 4KB
    const int bid = blockIdx.x;
    const int swz = (bid & 7) * 72 + (bid >> 3);    // 576 blocks, XCD-chunked
    const int p0 = swz * 64;
    const int imgb = (p0 / HW) * HW;
    const int tid = threadIdx.x, lane = tid & 63, wid = tid >> 6;
    const int wm = wid >> 1, wn = wid & 1;
    const int qa = ((lane >> 4) ^ ((lane >> 1) & 3)) * 8;
    // A-stage mapping: row/col-quad
    const int arow = tid >> 3, acb = tid & 7;
    const int adst = arow * 32 + (((acb >> 1) ^ ((arow >> 1) & 3)) * 8) + (acb & 1) * 4;
    // B-stage mapping: 4 lanes per pixel (coalesced 64B), pixel ps, group cg
    const int ps = tid >> 2, cg = tid & 3;
    const int bdst = ps * 32 + ((cg ^ ((ps >> 1) & 3)) * 8);
    const int hwp = p0 + ps - imgb;
    const int hp = hwp / Wc, wp = hwp - hp * Wc;

#define CLOAD(q, aD, bD) do {                                                  \
    int p2_ = (q) > 71 ? 71 : (q);                                             \
    int k2_ = p2_ >> 3, c2_ = p2_ & 7;                                         \
    int ky_ = k2_ / 3, kx_ = k2_ - ky_ * 3;                                    \
    int yy_ = hp + ky_ - 1, xx_ = wp + kx_ - 1;                                \
    bool v_ = (yy_ >= 0 && yy_ < Hc && xx_ >= 0 && xx_ < Wc);                  \
    aD = *(const f16x4*)(woffT + ((size_t)(k2_ * 32 + arow)) * Cc + c2_ * 32 + acb * 4); \
    f16x8 t_ = {0, 0, 0, 0, 0, 0, 0, 0};                                       \
    if (v_) t_ = *(const f16x8*)(x16 + ((size_t)(imgb + yy_ * Wc + xx_)) * Cc + c2_ * 32 + cg * 8); \
    bD = t_;                                                                   \
} while (0)

    f32x4 acc[2];
    acc[0] = (f32x4){0.f, 0.f, 0.f, 0.f};
    acc[1] = (f32x4){0.f, 0.f, 0.f, 0.f};

    f16x4 aR0, aR1;
    f16x8 bR0, bR1;
    // prologue: phase 0 -> slot0 -> s[0]; phase 1 -> slot1 (held in regs)
    CLOAD(0, aR0, bR0);
    CLOAD(1, aR1, bR1);
    *(f16x4*)&s_a[0][adst] = aR0;
    *(f16x8*)&s_b[0][bdst] = bR0;
    asm volatile("s_waitcnt lgkmcnt(0)" ::: "memory"); SB();
    __builtin_amdgcn_s_barrier(); SB();

#define CBODY(p, aCur, bCur, aNxt, bNxt, bc, bn) do {                          \
    f16x8 af = *(const f16x8*)&s_a[bc][(wm * 16 + (lane & 15)) * 32 + qa];     \
    f16x8 bf0 = *(const f16x8*)&s_b[bc][(wn * 32 + (lane & 15)) * 32 + qa];    \
    f16x8 bf1 = *(const f16x8*)&s_b[bc][(wn * 32 + 16 + (lane & 15)) * 32 + qa];\
    CLOAD((p) + 2, aCur, bCur);                                                \
    acc[0] = __builtin_amdgcn_mfma_f32_16x16x32_f16(af, bf0, acc[0], 0, 0, 0); \
    acc[1] = __builtin_amdgcn_mfma_f32_16x16x32_f16(af, bf1, acc[1], 0, 0, 0); \
    *(f16x4*)&s_a[bn][adst] = aNxt;                                            \
    *(f16x8*)&s_b[bn][bdst] = bNxt;                                            \
    asm volatile("s_waitcnt lgkmcnt(0)" ::: "memory"); SB();                   \
    __builtin_amdgcn_s_barrier(); SB();                                        \
} while (0)

    for (int p = 0; p < 72; p += 2) {
        CBODY(p,     aR0, bR0, aR1, bR1, 0, 1);
        CBODY(p + 1, aR1, bR1, aR0, bR0, 1, 0);
    }

    // epilogue: wm=0 -> taps 0..7 (rows 4g..4g+3), wm=1 -> tap 8 (rows 16,17)
    const int g = lane >> 4;
#pragma unroll
    for (int ni = 0; ni < 2; ++ni) {
        const int p = p0 + wn * 32 + ni * 16 + (lane & 15);
        const int hwq = p - imgb;
        const int hq = hwq / Wc, wq = hwq - hq * Wc;
        if (wm == 0) {
            store_tap(2 * g,     hq, wq, acc[ni][0] + b_off[4 * g],
                                         acc[ni][1] + b_off[4 * g + 1], p, idx4t, wt4t);
            store_tap(2 * g + 1, hq, wq, acc[ni][2] + b_off[4 * g + 2],
                                         acc[ni][3] + b_off[4 * g + 3], p, idx4t, wt4t);
        } else if (g == 0) {
            store_tap(8, hq, wq, acc[ni][0] + b_off[16],
                                 acc[ni][1] + b_off[17], p, idx4t, wt4t);
        }
    }
#undef CLOAD
#undef CBODY
}

// Fused deformable sampling (f16 NHWC gathers) + f16 MFMA GEMM + ReLU.
// Block: 768 threads (12 waves), 256 out x 144 pix; wave = 64out x 48pix.
// K=64/chunk (36 chunks), 1 block/CU, weight staged once per CU (R17).
// R19 change: NO mid-chunk lgkmcnt/sched fences — the compiler emits minimal
// counted lgkm waits for bf/af->MFMA deps, so blend VALU, ds_writes and
// MFMAs overlap (R18 serialized them with a full drain each chunk; LDS-pipe
// ~2600cyc + VALU ~1650cyc were paid serially). Only fences kept: SB after
// ISSUE_W (W-before-C issue order for vmcnt accounting) and the pre-barrier
// lgkmcnt(0)+vmcnt(N)+barrier (race-free point, R15-proven).
__global__ __launch_bounds__(768, 3) void deform_mfma_kernel(
    const f16* __restrict__ x16, const f16* __restrict__ wT2,
    const int4* __restrict__ idx4t, const float4* __restrict__ wt4t,
    f16* __restrict__ o16, float* __restrict__ oN, int last)
{
    __shared__ __align__(16) f16 s_w[2][2][8192];  // [buf][half][256o x 32c swz] 64KB
    __shared__ __align__(16) f16 s_s[2][2][4608];  // [buf][half][144p x 32c swz] 36KB

    const int bid = blockIdx.x;
    const int swz = (bid & 7) * 32 + (bid >> 3); // 256 blocks, XCD-chunked
    const int p0 = swz * 144;                    // 9216/144=64 -> no straddle
    const int imgb = (p0 / HW) * HW;
    const int tid = threadIdx.x, lane = tid & 63, wid = tid >> 6;
    const int wo = wid & 3, wp = wid >> 2;       // out-group, pix-group
    const bool sampler = (wid < 9);              // tids 0..575 <=> ps 0..143
    const int ps = tid >> 2, cg = tid & 3;
    const int qa = ((lane >> 4) ^ ((lane >> 1) & 3)) * 8;
    const int qs = (cg ^ ((ps >> 1) & 3)) * 8;
    const f16* xb = x16 + (size_t)imgb * Cc;
    const int wlo = (tid >> 2) * Cc + ((tid & 3) ^ ((tid >> 3) & 3)) * 8;
    const int wds = tid * 8;                     // u0 LDS slot base (elems)

// stage 16KB weights (one 32-chan half) for (tap kt, chunk cq, half h) -> nb
#define ISSUE_W(kt, cq, h, nb) do {                                            \
    const f16* g0_ = wT2 + wlo + ((size_t)((kt) * 256)) * Cc + (cq) * 64 + (h) * 32; \
    __builtin_amdgcn_global_load_lds(                                          \
        (const __attribute__((address_space(1))) void*)g0_,                    \
        (__attribute__((address_space(3))) void*)&s_w[nb][h][wds], 16, 0, 0);  \
    if (wid < 4) {                                                             \
        const f16* g1_ = wT2 + wlo + ((size_t)((kt) * 256 + 192)) * Cc + (cq) * 64 + (h) * 32; \
        __builtin_amdgcn_global_load_lds(                                      \
            (const __attribute__((address_space(1))) void*)g1_,                \
            (__attribute__((address_space(3))) void*)&s_w[nb][h][6144 + wds], 16, 0, 0); \
    }                                                                          \
} while (0)

// 4 lanes (cg=0..3) of pixel ps read contiguous 64B per corner
#define ISSUE_C(dst, idv, co) do {                                             \
    (dst)[0] = *(const f16x8*)(xb + (size_t)(idv).x * Cc + (co) + cg * 8);     \
    (dst)[1] = *(const f16x8*)(xb + (size_t)(idv).y * Cc + (co) + cg * 8);     \
    (dst)[2] = *(const f16x8*)(xb + (size_t)(idv).z * Cc + (co) + cg * 8);     \
    (dst)[3] = *(const f16x8*)(xb + (size_t)(idv).w * Cc + (co) + cg * 8);     \
} while (0)

#define BLEND_WRITE(src, wvv, h, nb) do {                                      \
    f16x8 sv_;                                                                 \
    _Pragma("unroll")                                                          \
    for (int j_ = 0; j_ < 8; ++j_) {                                           \
        float s_ = (wvv).x * (float)(src)[0][j_] + (wvv).y * (float)(src)[1][j_]\
                 + (wvv).z * (float)(src)[2][j_] + (wvv).w * (float)(src)[3][j_];\
        sv_[j_] = (f16)s_;                                                     \
    }                                                                          \
    *(f16x8*)&s_s[nb][h][ps * 32 + qs] = sv_;                                  \
} while (0)

    f32x4 acc[4][3];
#pragma unroll
    for (int mi = 0; mi < 4; ++mi)
#pragma unroll
        for (int ni = 0; ni < 3; ++ni) acc[mi][ni] = (f32x4){0.f, 0.f, 0.f, 0.f};

    f16x8 c4a[4], c4b[4];        // next chunk's corners, one buffer per half
    int4 id;
    float4 wv;
    int4 idN;
    float4 wvN;
    if (sampler) {
        id = idx4t[p0 + ps];
        wv = wt4t[p0 + ps];
    }

    // prologue: stage W(chunk0) both halves; samplers fill s_s[0][*] from
    // C(chunk0) and leave C(chunk1) x8 in flight; non-samplers drain W.
    ISSUE_W(0, 0, 0, 0);
    ISSUE_W(0, 0, 1, 0);
    SB();
    if (sampler) {
        ISSUE_C(c4a, id, 0);               // chunk0 half0
        ISSUE_C(c4b, id, 32);              // chunk0 half1
        BLEND_WRITE(c4a, wv, 0, 0);        // counted vmcnt retires W+C as needed
        BLEND_WRITE(c4b, wv, 1, 0);
        ISSUE_C(c4a, id, 64);              // chunk1 half0
        ISSUE_C(c4b, id, 96);              // chunk1 half1
        asm volatile("s_waitcnt lgkmcnt(0)" ::: "memory"); SB();
    } else {
        asm volatile("s_waitcnt vmcnt(0)" ::: "memory"); SB();
    }
    __builtin_amdgcn_s_barrier(); SB();

    for (int k = 0; k < 9; ++k) {
        const int kn = (k < 8) ? k + 1 : 8;
#pragma unroll
        for (int ch = 0; ch < 4; ++ch) {   // chunk = 64 chans
            const int bb = ch & 1, nb = bb ^ 1;
            f16x8 bf0[3], bf1[3];
#pragma unroll
            for (int ni = 0; ni < 3; ++ni) {
                bf0[ni] = *(const f16x8*)&s_s[bb][0][(wp * 48 + ni * 16 + (lane & 15)) * 32 + qa];
                bf1[ni] = *(const f16x8*)&s_s[bb][1][(wp * 48 + ni * 16 + (lane & 15)) * 32 + qa];
            }
            if (sampler) {
                if (ch == 1) {             // late load: needed from ch2
                    idN = idx4t[(size_t)kn * PIX + p0 + ps];
                    wvN = wt4t[(size_t)kn * PIX + p0 + ps];
                }
                ISSUE_W((ch == 3) ? kn : k, (ch + 1) & 3, 0, nb);
                ISSUE_W((ch == 3) ? kn : k, (ch + 1) & 3, 1, nb);
                SB();                      // pin W (and idwv) before C issue
                // blend corners for chunk t+1 (counted vmcnt), reissue same
                // regs for chunk t+2 (WAR). No fences after: compiler
                // interleaves these VALU/ds_writes with the MFMAs below.
                {
                    const float4 wvu = (ch == 3) ? wvN : wv;
                    const int4 idu = (ch >= 2) ? idN : id;
                    const int co2 = ((ch + 2) & 3) * 64;
                    BLEND_WRITE(c4a, wvu, 0, nb);
                    ISSUE_C(c4a, idu, co2);
                    BLEND_WRITE(c4b, wvu, 1, nb);
                    ISSUE_C(c4b, idu, co2 + 32);
                }
            } else {
                ISSUE_W((ch == 3) ? kn : k, (ch + 1) & 3, 0, nb);
                ISSUE_W((ch == 3) ? kn : k, (ch + 1) & 3, 1, nb);
                SB();
            }
            // MFMAs: 24 (two halves), af streamed per-mi; compiler inserts
            // minimal counted lgkm waits for af/bf deps.
#pragma unroll
            for (int mi = 0; mi < 4; ++mi) {
                f16x8 af = *(const f16x8*)&s_w[bb][0][(wo * 64 + mi * 16 + (lane & 15)) * 32 + qa];
#pragma unroll
                for (int ni = 0; ni < 3; ++ni)
                    acc[mi][ni] = __builtin_amdgcn_mfma_f32_16x16x32_f16(
                        af, bf0[ni], acc[mi][ni], 0, 0, 0);
            }
#pragma unroll
            for (int mi = 0; mi < 4; ++mi) {
                f16x8 af = *(const f16x8*)&s_w[bb][1][(wo * 64 + mi * 16 + (lane & 15)) * 32 + qa];
#pragma unroll
                for (int ni = 0; ni < 3; ++ni)
                    acc[mi][ni] = __builtin_amdgcn_mfma_f32_16x16x32_f16(
                        af, bf1[ni], acc[mi][ni], 0, 0, 0);
            }
            // RACE-FREE POINT: drain own ds_writes (lgkm) and own W-to-LDS
            // (vmcnt) BEFORE the barrier. Samplers: queue = [(idwv,) W x2-4
            // old, C x8] -> vmcnt(8). Non-samplers: [W x2] -> vmcnt(0).
            asm volatile("s_waitcnt lgkmcnt(0)" ::: "memory"); SB();
            if (sampler) {
                asm volatile("s_waitcnt vmcnt(8)" ::: "memory"); SB();
            } else {
                asm volatile("s_waitcnt vmcnt(0)" ::: "memory"); SB();
            }
            __builtin_amdgcn_s_barrier(); SB();
        }
        if (sampler) { id = idN; wv = wvN; }
    }

    // epilogue: ReLU; D row = output = (lane>>4)*4+j, col = pixel = lane&15
    if (!last) {
#pragma unroll
        for (int ni = 0; ni < 3; ++ni) {
            const int p = p0 + wp * 48 + ni * 16 + (lane & 15);
#pragma unroll
            for (int mi = 0; mi < 4; ++mi) {
                const int o0 = wo * 64 + mi * 16 + (lane >> 4) * 4;
                f32x4 v = acc[mi][ni];
                f16x4 h = {(f16)fmaxf(v[0], 0.f), (f16)fmaxf(v[1], 0.f),
                           (f16)fmaxf(v[2], 0.f), (f16)fmaxf(v[3], 0.f)};
                *(f16x4*)&o16[(size_t)p * Cc + o0] = h;
            }
        }
    } else {
        const int bimg = imgb / HW;
#pragma unroll
        for (int ni = 0; ni < 3; ++ni) {
            const int p = p0 + wp * 48 + ni * 16 + (lane & 15);
            const int hwl = p - imgb;
#pragma unroll
            for (int mi = 0; mi < 4; ++mi) {
                const int o0 = wo * 64 + mi * 16 + (lane >> 4) * 4;
#pragma unroll
                for (int j = 0; j < 4; ++j)
                    oN[((size_t)(bimg * Cc + o0 + j)) * HW + hwl] =
                        fmaxf(acc[mi][ni][j], 0.f);
            }
        }
    }
#undef ISSUE_W
#undef ISSUE_C
#undef BLEND_WRITE
}

extern "C" void kernel_launch(void* const* d_in, const int* in_sizes, int n_in,
                              void* d_out, int out_size, void* d_ws, size_t ws_size,
                              hipStream_t stream)
{
    const float* x0 = (const float*)d_in[0];
    float* out = (float*)d_out;

    f16*   x16a = (f16*)d_ws;                          // PIX*Cc f16
    f16*   x16b = x16a + (size_t)PIX * Cc;             // PIX*Cc f16
    f16*   wT2  = x16b + (size_t)PIX * Cc;             // CK*Cc f16
    f16*   woffT = wT2 + (size_t)CK * Cc;              // 9*32*256 f16
    int4*  idx4t = (int4*)(woffT + (size_t)9 * 32 * Cc);
    float4* wt4t = (float4*)(idx4t + (size_t)KK * PIX);

    nhwc_prep_kernel<<<dim3(HW / 64, Cc / 64, Bc), 256, 0, stream>>>(x0, x16a);

    const f16* xin = x16a;
    for (int L = 0; L < 3; ++L) {
        const float* w_off = (const float*)d_in[1 + 3 * L];
        const float* b_off = (const float*)d_in[2 + 3 * L];
        const float* w     = (const float*)d_in[3 + 3 * L];
        const int last = (L == 2);
        f16* xo = (L == 0) ? x16b : x16a;

        wprep_kernel<<<2592, 256, 0, stream>>>(w, w_off, wT2, woffT);
        conv_off_mfma_kernel<<<PIX / 64, 256, 0, stream>>>(xin, woffT, b_off, idx4t, wt4t);
        deform_mfma_kernel<<<PIX / 144, 768, 0, stream>>>(
            xin, wT2, idx4t, wt4t, xo, out, last);

        xin = xo;
    }
}

// Round 20
// 287.495 us; speedup vs baseline: 1.8481x; 1.1140x over previous
//
#include <hip/hip_runtime.h>

#define Hc 96
#define Wc 96
#define Cc 256
#define Bc 4
#define KK 9
#define HW 9216          // Hc*Wc
#define PIX 36864        // Bc*HW
#define CK 2304          // Cc*KK

typedef _Float16 f16;
typedef __attribute__((ext_vector_type(4))) _Float16 f16x4;
typedef __attribute__((ext_vector_type(8))) _Float16 f16x8;
typedef __attribute__((ext_vector_type(4))) float f32x4;

__device__ __forceinline__ int clampi(int v, int lo, int hi) {
    return v < lo ? lo : (v > hi ? hi : v);
}

#define SB() __builtin_amdgcn_sched_barrier(0)

// ---------- prep: NCHW fp32 -> NHWC f16 (layer 0 input) ----------
__global__ __launch_bounds__(256) void nhwc_prep_kernel(
    const float* __restrict__ x0, f16* __restrict__ x16)
{
    __shared__ float st[64][65];
    const int hw0 = blockIdx.x * 64;
    const int c0  = blockIdx.y * 64;
    const int b   = blockIdx.z;
    const int tid = threadIdx.x;
    const int a = tid & 63, r = tid >> 6;
#pragma unroll
    for (int it = 0; it < 16; ++it) {
        int cl = it * 4 + r;
        st[cl][a] = x0[((size_t)(b * Cc + c0 + cl)) * HW + hw0 + a];
    }
    __syncthreads();
#pragma unroll
    for (int it = 0; it < 16; ++it) {
        int hwl = it * 4 + r;
        x16[((size_t)(b * HW + hw0 + hwl)) * Cc + c0 + a] = (f16)st[a][hwl];
    }
}

// merged weight prep:
//  blocks 0..2303:  wT2[(k*256+o)*256+c] = (f16) w[(o*256+c)*9+k]
//  blocks 2304..2591: woffT[(k*32+j)*256+c] = (f16) w_off[(j*256+c)*9+k] (j<18)
__global__ __launch_bounds__(256) void wprep_kernel(
    const float* __restrict__ w, const float* __restrict__ w_off,
    f16* __restrict__ wT2, f16* __restrict__ woffT)
{
    int b = blockIdx.x;
    if (b < 2304) {
        int u = b * 256 + threadIdx.x;        // < 589824
        int c = u & 255, o = (u >> 8) & 255, k = u >> 16;
        wT2[u] = (f16)w[(o * Cc + c) * KK + k];
    } else {
        int u = (b - 2304) * 256 + threadIdx.x; // < 73728
        int c = u & 255, j = (u >> 8) & 31, k = u >> 13;
        float v = (j < 18) ? w_off[((size_t)j * Cc + c) * KK + k] : 0.f;
        woffT[u] = (f16)v;
    }
}

// bilinear decomposition for one tap -> idx4/wt4 (tap-major layout)
__device__ __forceinline__ void store_tap(int k, int h, int w, float offy, float offx,
    int p, int4* __restrict__ idx4t, float4* __restrict__ wt4t)
{
    float py = (float)(h - 1 + k / 3) + offy;
    float px = (float)(w - 1 + k % 3) + offx;
    float y0f = floorf(py), x0f = floorf(px);
    float wy = py - y0f, wx = px - x0f;
    int iy0 = (int)y0f, ix0 = (int)x0f;
    float vy0 = (y0f >= 0.f && y0f <= 95.f) ? 1.f : 0.f;
    float vy1 = (y0f + 1.f >= 0.f && y0f + 1.f <= 95.f) ? 1.f : 0.f;
    float vx0 = (x0f >= 0.f && x0f <= 95.f) ? 1.f : 0.f;
    float vx1 = (x0f + 1.f >= 0.f && x0f + 1.f <= 95.f) ? 1.f : 0.f;
    int cy0 = clampi(iy0, 0, 95), cy1 = clampi(iy0 + 1, 0, 95);
    int cx0 = clampi(ix0, 0, 95), cx1 = clampi(ix0 + 1, 0, 95);
    idx4t[(size_t)k * PIX + p] = make_int4(cy0 * Wc + cx0, cy0 * Wc + cx1,
                                           cy1 * Wc + cx0, cy1 * Wc + cx1);
    wt4t[(size_t)k * PIX + p] = make_float4((1.f - wy) * (1.f - wx) * vy0 * vx0,
                                            (1.f - wy) * wx * vy0 * vx1,
                                            wy * (1.f - wx) * vy1 * vx0,
                                            wy * wx * vy1 * vx1);
}

// Offset conv as f16 MFMA GEMM, reg-staged double-buffered pipeline.
// Block: 256 threads (4 waves = 2M x 2N), tile 32 out x 64 pixels. 576 blocks.
__global__ __launch_bounds__(256) void conv_off_mfma_kernel(
    const f16* __restrict__ x16, const f16* __restrict__ woffT,
    const float* __restrict__ b_off,
    int4* __restrict__ idx4t, float4* __restrict__ wt4t)
{
    __shared__ __align__(16) f16 s_a[2][32 * 32];   // 2 x 2KB
    __shared__ __align__(16) f16 s_b[2][64 * 32];   // 2 x 4KB
    const int bid = blockIdx.x;
    const int swz = (bid & 7) * 72 + (bid >> 3);    // 576 blocks, XCD-chunked
    const int p0 = swz * 64;
    const int imgb = (p0 / HW) * HW;
    const int tid = threadIdx.x, lane = tid & 63, wid = tid >> 6;
    const int wm = wid >> 1, wn = wid & 1;
    const int qa = ((lane >> 4) ^ ((lane >> 1) & 3)) * 8;
    // A-stage mapping: row/col-quad
    const int arow = tid >> 3, acb = tid & 7;
    const int adst = arow * 32 + (((acb >> 1) ^ ((arow >> 1) & 3)) * 8) + (acb & 1) * 4;
    // B-stage mapping: 4 lanes per pixel (coalesced 64B), pixel ps, group cg
    const int ps = tid >> 2, cg = tid & 3;
    const int bdst = ps * 32 + ((cg ^ ((ps >> 1) & 3)) * 8);
    const int hwp = p0 + ps - imgb;
    const int hp = hwp / Wc, wp = hwp - hp * Wc;

#define CLOAD(q, aD, bD) do {                                                  \
    int p2_ = (q) > 71 ? 71 : (q);                                             \
    int k2_ = p2_ >> 3, c2_ = p2_ & 7;                                         \
    int ky_ = k2_ / 3, kx_ = k2_ - ky_ * 3;                                    \
    int yy_ = hp + ky_ - 1, xx_ = wp + kx_ - 1;                                \
    bool v_ = (yy_ >= 0 && yy_ < Hc && xx_ >= 0 && xx_ < Wc);                  \
    aD = *(const f16x4*)(woffT + ((size_t)(k2_ * 32 + arow)) * Cc + c2_ * 32 + acb * 4); \
    f16x8 t_ = {0, 0, 0, 0, 0, 0, 0, 0};                                       \
    if (v_) t_ = *(const f16x8*)(x16 + ((size_t)(imgb + yy_ * Wc + xx_)) * Cc + c2_ * 32 + cg * 8); \
    bD = t_;                                                                   \
} while (0)

    f32x4 acc[2];
    acc[0] = (f32x4){0.f, 0.f, 0.f, 0.f};
    acc[1] = (f32x4){0.f, 0.f, 0.f, 0.f};

    f16x4 aR0, aR1;
    f16x8 bR0, bR1;
    // prologue: phase 0 -> slot0 -> s[0]; phase 1 -> slot1 (held in regs)
    CLOAD(0, aR0, bR0);
    CLOAD(1, aR1, bR1);
    *(f16x4*)&s_a[0][adst] = aR0;
    *(f16x8*)&s_b[0][bdst] = bR0;
    asm volatile("s_waitcnt lgkmcnt(0)" ::: "memory"); SB();
    __builtin_amdgcn_s_barrier(); SB();

#define CBODY(p, aCur, bCur, aNxt, bNxt, bc, bn) do {                          \
    f16x8 af = *(const f16x8*)&s_a[bc][(wm * 16 + (lane & 15)) * 32 + qa];     \
    f16x8 bf0 = *(const f16x8*)&s_b[bc][(wn * 32 + (lane & 15)) * 32 + qa];    \
    f16x8 bf1 = *(const f16x8*)&s_b[bc][(wn * 32 + 16 + (lane & 15)) * 32 + qa];\
    CLOAD((p) + 2, aCur, bCur);                                                \
    acc[0] = __builtin_amdgcn_mfma_f32_16x16x32_f16(af, bf0, acc[0], 0, 0, 0); \
    acc[1] = __builtin_amdgcn_mfma_f32_16x16x32_f16(af, bf1, acc[1], 0, 0, 0); \
    *(f16x4*)&s_a[bn][adst] = aNxt;                                            \
    *(f16x8*)&s_b[bn][bdst] = bNxt;                                            \
    asm volatile("s_waitcnt lgkmcnt(0)" ::: "memory"); SB();                   \
    __builtin_amdgcn_s_barrier(); SB();                                        \
} while (0)

    for (int p = 0; p < 72; p += 2) {
        CBODY(p,     aR0, bR0, aR1, bR1, 0, 1);
        CBODY(p + 1, aR1, bR1, aR0, bR0, 1, 0);
    }

    // epilogue: wm=0 -> taps 0..7 (rows 4g..4g+3), wm=1 -> tap 8 (rows 16,17)
    const int g = lane >> 4;
#pragma unroll
    for (int ni = 0; ni < 2; ++ni) {
        const int p = p0 + wn * 32 + ni * 16 + (lane & 15);
        const int hwq = p - imgb;
        const int hq = hwq / Wc, wq = hwq - hq * Wc;
        if (wm == 0) {
            store_tap(2 * g,     hq, wq, acc[ni][0] + b_off[4 * g],
                                         acc[ni][1] + b_off[4 * g + 1], p, idx4t, wt4t);
            store_tap(2 * g + 1, hq, wq, acc[ni][2] + b_off[4 * g + 2],
                                         acc[ni][3] + b_off[4 * g + 3], p, idx4t, wt4t);
        } else if (g == 0) {
            store_tap(8, hq, wq, acc[ni][0] + b_off[16],
                                 acc[ni][1] + b_off[17], p, idx4t, wt4t);
        }
    }
#undef CLOAD
#undef CBODY
}

// Fused deformable sampling (f16 NHWC gathers) + f16 MFMA GEMM + ReLU.
// Block: 768 threads (12 waves), 256 out x 144 pix; wave = 64out x 48pix.
// K=64/chunk (36 chunks), 1 block/CU, weight staged once per CU.
// R20 changes vs R19:
//  - bilinear blend in PACKED f16 (v_pk_mul/fma via f16x8 vector arith):
//    12 pk ops/half vs 32 f32 ops + 8 cvts -> sampler VALU phase ~-60%.
//  - extra weight lane-loads (rows 192..255) moved from sampler waves 0-3
//    to waves 8-11 (9-11 were idlest). vmcnt per class re-derived:
//    waves 0-7 [Wx2,Cx8]->vmcnt(8); wave 8 [Wx4,Cx8]->vmcnt(8);
//    waves 9-11 [Wx4]->vmcnt(0). Race-free drain-before-barrier kept.
__global__ __launch_bounds__(768, 3) void deform_mfma_kernel(
    const f16* __restrict__ x16, const f16* __restrict__ wT2,
    const int4* __restrict__ idx4t, const float4* __restrict__ wt4t,
    f16* __restrict__ o16, float* __restrict__ oN, int last)
{
    __shared__ __align__(16) f16 s_w[2][2][8192];  // [buf][half][256o x 32c swz] 64KB
    __shared__ __align__(16) f16 s_s[2][2][4608];  // [buf][half][144p x 32c swz] 36KB

    const int bid = blockIdx.x;
    const int swz = (bid & 7) * 32 + (bid >> 3); // 256 blocks, XCD-chunked
    const int p0 = swz * 144;                    // 9216/144=64 -> no straddle
    const int imgb = (p0 / HW) * HW;
    const int tid = threadIdx.x, lane = tid & 63, wid = tid >> 6;
    const int wo = wid & 3, wp = wid >> 2;       // out-group, pix-group
    const bool sampler = (wid < 9);              // tids 0..575 <=> ps 0..143
    const int ps = tid >> 2, cg = tid & 3;
    const int qa = ((lane >> 4) ^ ((lane >> 1) & 3)) * 8;
    const int qs = (cg ^ ((ps >> 1) & 3)) * 8;
    const f16* xb = x16 + (size_t)imgb * Cc;
    const int wlo = (tid >> 2) * Cc + ((tid & 3) ^ ((tid >> 3) & 3)) * 8;
    const int wds = tid * 8;                     // u0 LDS slot base (elems)

// stage 16KB weights (one 32-chan half) for (tap kt, chunk cq, half h) -> nb.
// Rows 0..191: all 768 threads. Rows 192..255: waves 8-11 (row = tid>>2 + 64,
// slot = 2048 + wds; colq invariant since (tid-512)>>3 == tid>>3 mod 4).
#define ISSUE_W(kt, cq, h, nb) do {                                            \
    const f16* g0_ = wT2 + wlo + ((size_t)((kt) * 256)) * Cc + (cq) * 64 + (h) * 32; \
    __builtin_amdgcn_global_load_lds(                                          \
        (const __attribute__((address_space(1))) void*)g0_,                    \
        (__attribute__((address_space(3))) void*)&s_w[nb][h][wds], 16, 0, 0);  \
    if (wid >= 8) {                                                            \
        const f16* g1_ = wT2 + wlo + ((size_t)((kt) * 256 + 64)) * Cc + (cq) * 64 + (h) * 32; \
        __builtin_amdgcn_global_load_lds(                                      \
            (const __attribute__((address_space(1))) void*)g1_,                \
            (__attribute__((address_space(3))) void*)&s_w[nb][h][2048 + wds], 16, 0, 0); \
    }                                                                          \
} while (0)

// 4 lanes (cg=0..3) of pixel ps read contiguous 64B per corner
#define ISSUE_C(dst, idv, co) do {                                             \
    (dst)[0] = *(const f16x8*)(xb + (size_t)(idv).x * Cc + (co) + cg * 8);     \
    (dst)[1] = *(const f16x8*)(xb + (size_t)(idv).y * Cc + (co) + cg * 8);     \
    (dst)[2] = *(const f16x8*)(xb + (size_t)(idv).z * Cc + (co) + cg * 8);     \
    (dst)[3] = *(const f16x8*)(xb + (size_t)(idv).w * Cc + (co) + cg * 8);     \
} while (0)

// packed-f16 bilinear blend: 4 pk_mul + 12 pk_fma equivalent (clang lowers
// f16x8 vector arith to v_pk_* on gfx950); weights converted f32->f16 once
// per use (CSE'd across the two halves).
#define BLEND_WRITE(src, wvv, h, nb) do {                                      \
    f16x8 sv_ = (src)[0] * (f16)(wvv).x + (src)[1] * (f16)(wvv).y              \
              + (src)[2] * (f16)(wvv).z + (src)[3] * (f16)(wvv).w;             \
    *(f16x8*)&s_s[nb][h][ps * 32 + qs] = sv_;                                  \
} while (0)

    f32x4 acc[4][3];
#pragma unroll
    for (int mi = 0; mi < 4; ++mi)
#pragma unroll
        for (int ni = 0; ni < 3; ++ni) acc[mi][ni] = (f32x4){0.f, 0.f, 0.f, 0.f};

    f16x8 c4a[4], c4b[4];        // next chunk's corners, one buffer per half
    int4 id;
    float4 wv;
    int4 idN;
    float4 wvN;
    if (sampler) {
        id = idx4t[p0 + ps];
        wv = wt4t[p0 + ps];
    }

    // prologue: stage W(chunk0) both halves; samplers fill s_s[0][*] from
    // C(chunk0) and leave C(chunk1) x8 in flight; non-samplers drain W.
    ISSUE_W(0, 0, 0, 0);
    ISSUE_W(0, 0, 1, 0);
    SB();
    if (sampler) {
        ISSUE_C(c4a, id, 0);               // chunk0 half0
        ISSUE_C(c4b, id, 32);              // chunk0 half1
        BLEND_WRITE(c4a, wv, 0, 0);        // counted vmcnt retires W+C as needed
        BLEND_WRITE(c4b, wv, 1, 0);
        ISSUE_C(c4a, id, 64);              // chunk1 half0
        ISSUE_C(c4b, id, 96);              // chunk1 half1
        asm volatile("s_waitcnt lgkmcnt(0)" ::: "memory"); SB();
        if (wid == 8) {
            asm volatile("s_waitcnt vmcnt(8)" ::: "memory"); SB();
        }
    } else {
        asm volatile("s_waitcnt vmcnt(0)" ::: "memory"); SB();
    }
    __builtin_amdgcn_s_barrier(); SB();

    for (int k = 0; k < 9; ++k) {
        const int kn = (k < 8) ? k + 1 : 8;
#pragma unroll
        for (int ch = 0; ch < 4; ++ch) {   // chunk = 64 chans
            const int bb = ch & 1, nb = bb ^ 1;
            f16x8 bf0[3], bf1[3];
#pragma unroll
            for (int ni = 0; ni < 3; ++ni) {
                bf0[ni] = *(const f16x8*)&s_s[bb][0][(wp * 48 + ni * 16 + (lane & 15)) * 32 + qa];
                bf1[ni] = *(const f16x8*)&s_s[bb][1][(wp * 48 + ni * 16 + (lane & 15)) * 32 + qa];
            }
            if (sampler) {
                if (ch == 1) {             // late load: needed from ch2
                    idN = idx4t[(size_t)kn * PIX + p0 + ps];
                    wvN = wt4t[(size_t)kn * PIX + p0 + ps];
                }
                ISSUE_W((ch == 3) ? kn : k, (ch + 1) & 3, 0, nb);
                ISSUE_W((ch == 3) ? kn : k, (ch + 1) & 3, 1, nb);
                SB();                      // pin W (and idwv) before C issue
                // blend corners for chunk t+1 (counted vmcnt), reissue same
                // regs for chunk t+2 (WAR)
                {
                    const float4 wvu = (ch == 3) ? wvN : wv;
                    const int4 idu = (ch >= 2) ? idN : id;
                    const int co2 = ((ch + 2) & 3) * 64;
                    BLEND_WRITE(c4a, wvu, 0, nb);
                    ISSUE_C(c4a, idu, co2);
                    BLEND_WRITE(c4b, wvu, 1, nb);
                    ISSUE_C(c4b, idu, co2 + 32);
                }
            } else {
                ISSUE_W((ch == 3) ? kn : k, (ch + 1) & 3, 0, nb);
                ISSUE_W((ch == 3) ? kn : k, (ch + 1) & 3, 1, nb);
                SB();
            }
            // MFMAs: 24 (two halves), af streamed per-mi; compiler inserts
            // minimal counted lgkm waits for af/bf deps.
#pragma unroll
            for (int mi = 0; mi < 4; ++mi) {
                f16x8 af = *(const f16x8*)&s_w[bb][0][(wo * 64 + mi * 16 + (lane & 15)) * 32 + qa];
#pragma unroll
                for (int ni = 0; ni < 3; ++ni)
                    acc[mi][ni] = __builtin_amdgcn_mfma_f32_16x16x32_f16(
                        af, bf0[ni], acc[mi][ni], 0, 0, 0);
            }
#pragma unroll
            for (int mi = 0; mi < 4; ++mi) {
                f16x8 af = *(const f16x8*)&s_w[bb][1][(wo * 64 + mi * 16 + (lane & 15)) * 32 + qa];
#pragma unroll
                for (int ni = 0; ni < 3; ++ni)
                    acc[mi][ni] = __builtin_amdgcn_mfma_f32_16x16x32_f16(
                        af, bf1[ni], acc[mi][ni], 0, 0, 0);
            }
            // RACE-FREE POINT: drain own ds_writes (lgkm) and own W-to-LDS
            // (vmcnt) BEFORE the barrier. Waves 0-8: queue = [(idwv,) W old,
            // C x8] -> vmcnt(8). Waves 9-11: [W x4] -> vmcnt(0).
            asm volatile("s_waitcnt lgkmcnt(0)" ::: "memory"); SB();
            if (sampler) {
                asm volatile("s_waitcnt vmcnt(8)" ::: "memory"); SB();
            } else {
                asm volatile("s_waitcnt vmcnt(0)" ::: "memory"); SB();
            }
            __builtin_amdgcn_s_barrier(); SB();
        }
        if (sampler) { id = idN; wv = wvN; }
    }

    // epilogue: ReLU; D row = output = (lane>>4)*4+j, col = pixel = lane&15
    if (!last) {
#pragma unroll
        for (int ni = 0; ni < 3; ++ni) {
            const int p = p0 + wp * 48 + ni * 16 + (lane & 15);
#pragma unroll
            for (int mi = 0; mi < 4; ++mi) {
                const int o0 = wo * 64 + mi * 16 + (lane >> 4) * 4;
                f32x4 v = acc[mi][ni];
                f16x4 h = {(f16)fmaxf(v[0], 0.f), (f16)fmaxf(v[1], 0.f),
                           (f16)fmaxf(v[2], 0.f), (f16)fmaxf(v[3], 0.f)};
                *(f16x4*)&o16[(size_t)p * Cc + o0] = h;
            }
        }
    } else {
        const int bimg = imgb / HW;
#pragma unroll
        for (int ni = 0; ni < 3; ++ni) {
            const int p = p0 + wp * 48 + ni * 16 + (lane & 15);
            const int hwl = p - imgb;
#pragma unroll
            for (int mi = 0; mi < 4; ++mi) {
                const int o0 = wo * 64 + mi * 16 + (lane >> 4) * 4;
#pragma unroll
                for (int j = 0; j < 4; ++j)
                    oN[((size_t)(bimg * Cc + o0 + j)) * HW + hwl] =
                        fmaxf(acc[mi][ni][j], 0.f);
            }
        }
    }
#undef ISSUE_W
#undef ISSUE_C
#undef BLEND_WRITE
}

extern "C" void kernel_launch(void* const* d_in, const int* in_sizes, int n_in,
                              void* d_out, int out_size, void* d_ws, size_t ws_size,
                              hipStream_t stream)
{
    const float* x0 = (const float*)d_in[0];
    float* out = (float*)d_out;

    f16*   x16a = (f16*)d_ws;                          // PIX*Cc f16
    f16*   x16b = x16a + (size_t)PIX * Cc;             // PIX*Cc f16
    f16*   wT2  = x16b + (size_t)PIX * Cc;             // CK*Cc f16
    f16*   woffT = wT2 + (size_t)CK * Cc;              // 9*32*256 f16
    int4*  idx4t = (int4*)(woffT + (size_t)9 * 32 * Cc);
    float4* wt4t = (float4*)(idx4t + (size_t)KK * PIX);

    nhwc_prep_kernel<<<dim3(HW / 64, Cc / 64, Bc), 256, 0, stream>>>(x0, x16a);

    const f16* xin = x16a;
    for (int L = 0; L < 3; ++L) {
        const float* w_off = (const float*)d_in[1 + 3 * L];
        const float* b_off = (const float*)d_in[2 + 3 * L];
        const float* w     = (const float*)d_in[3 + 3 * L];
        const int last = (L == 2);
        f16* xo = (L == 0) ? x16b : x16a;

        wprep_kernel<<<2592, 256, 0, stream>>>(w, w_off, wT2, woffT);
        conv_off_mfma_kernel<<<PIX / 64, 256, 0, stream>>>(xin, woffT, b_off, idx4t, wt4t);
        deform_mfma_kernel<<<PIX / 144, 768, 0, stream>>>(
            xin, wT2, idx4t, wt4t, xo, out, last);

        xin = xo;
    }
}

// Round 21
// 282.097 us; speedup vs baseline: 1.8834x; 1.0191x over previous
//
#include <hip/hip_runtime.h>

#define Hc 96
#define Wc 96
#define Cc 256
#define Bc 4
#define KK 9
#define HW 9216          // Hc*Wc
#define PIX 36864        // Bc*HW
#define CK 2304          // Cc*KK

typedef _Float16 f16;
typedef __attribute__((ext_vector_type(4))) _Float16 f16x4;
typedef __attribute__((ext_vector_type(8))) _Float16 f16x8;
typedef __attribute__((ext_vector_type(4))) float f32x4;

__device__ __forceinline__ int clampi(int v, int lo, int hi) {
    return v < lo ? lo : (v > hi ? hi : v);
}

#define SB() __builtin_amdgcn_sched_barrier(0)

// ---------- prep: NCHW fp32 -> NHWC f16 (layer 0 input) ----------
__global__ __launch_bounds__(256) void nhwc_prep_kernel(
    const float* __restrict__ x0, f16* __restrict__ x16)
{
    __shared__ float st[64][65];
    const int hw0 = blockIdx.x * 64;
    const int c0  = blockIdx.y * 64;
    const int b   = blockIdx.z;
    const int tid = threadIdx.x;
    const int a = tid & 63, r = tid >> 6;
#pragma unroll
    for (int it = 0; it < 16; ++it) {
        int cl = it * 4 + r;
        st[cl][a] = x0[((size_t)(b * Cc + c0 + cl)) * HW + hw0 + a];
    }
    __syncthreads();
#pragma unroll
    for (int it = 0; it < 16; ++it) {
        int hwl = it * 4 + r;
        x16[((size_t)(b * HW + hw0 + hwl)) * Cc + c0 + a] = (f16)st[a][hwl];
    }
}

// merged weight prep:
//  blocks 0..2303:  wT2[(k*256+o)*256+c] = (f16) w[(o*256+c)*9+k]
//  blocks 2304..2591: woffT[(k*32+j)*256+c] = (f16) w_off[(j*256+c)*9+k] (j<18)
__global__ __launch_bounds__(256) void wprep_kernel(
    const float* __restrict__ w, const float* __restrict__ w_off,
    f16* __restrict__ wT2, f16* __restrict__ woffT)
{
    int b = blockIdx.x;
    if (b < 2304) {
        int u = b * 256 + threadIdx.x;        // < 589824
        int c = u & 255, o = (u >> 8) & 255, k = u >> 16;
        wT2[u] = (f16)w[(o * Cc + c) * KK + k];
    } else {
        int u = (b - 2304) * 256 + threadIdx.x; // < 73728
        int c = u & 255, j = (u >> 8) & 31, k = u >> 13;
        float v = (j < 18) ? w_off[((size_t)j * Cc + c) * KK + k] : 0.f;
        woffT[u] = (f16)v;
    }
}

// bilinear decomposition for one tap -> idx4/wt4 (tap-major layout)
__device__ __forceinline__ void store_tap(int k, int h, int w, float offy, float offx,
    int p, int4* __restrict__ idx4t, float4* __restrict__ wt4t)
{
    float py = (float)(h - 1 + k / 3) + offy;
    float px = (float)(w - 1 + k % 3) + offx;
    float y0f = floorf(py), x0f = floorf(px);
    float wy = py - y0f, wx = px - x0f;
    int iy0 = (int)y0f, ix0 = (int)x0f;
    float vy0 = (y0f >= 0.f && y0f <= 95.f) ? 1.f : 0.f;
    float vy1 = (y0f + 1.f >= 0.f && y0f + 1.f <= 95.f) ? 1.f : 0.f;
    float vx0 = (x0f >= 0.f && x0f <= 95.f) ? 1.f : 0.f;
    float vx1 = (x0f + 1.f >= 0.f && x0f + 1.f <= 95.f) ? 1.f : 0.f;
    int cy0 = clampi(iy0, 0, 95), cy1 = clampi(iy0 + 1, 0, 95);
    int cx0 = clampi(ix0, 0, 95), cx1 = clampi(ix0 + 1, 0, 95);
    idx4t[(size_t)k * PIX + p] = make_int4(cy0 * Wc + cx0, cy0 * Wc + cx1,
                                           cy1 * Wc + cx0, cy1 * Wc + cx1);
    wt4t[(size_t)k * PIX + p] = make_float4((1.f - wy) * (1.f - wx) * vy0 * vx0,
                                            (1.f - wy) * wx * vy0 * vx1,
                                            wy * (1.f - wx) * vy1 * vx0,
                                            wy * wx * vy1 * vx1);
}

// Offset conv as f16 MFMA GEMM, reg-staged double-buffered pipeline.
// Block: 256 threads (4 waves = 2M x 2N), tile 32 out x 64 pixels. 576 blocks.
// R21: K=64 per phase -> 36 phases x 1 barrier (was 72 x 2). A = 32r x 64c
// (1 f16x8/thread), B = 64px x 64c (2 f16x8/thread: px = tid>>3 and +32,
// chan-group g = tid&7). Swizzle: dst = row*32 + ((colq ^ ((row>>1)&3))*8),
// matching the frag-read qa convention. LDS 24KB.
__global__ __launch_bounds__(256) void conv_off_mfma_kernel(
    const f16* __restrict__ x16, const f16* __restrict__ woffT,
    const float* __restrict__ b_off,
    int4* __restrict__ idx4t, float4* __restrict__ wt4t)
{
    __shared__ __align__(16) f16 s_a[2][2][1024];   // [buf][half][32r x 32c swz] 8KB
    __shared__ __align__(16) f16 s_b[2][2][2048];   // [buf][half][64p x 32c swz] 16KB
    const int bid = blockIdx.x;
    const int swz = (bid & 7) * 72 + (bid >> 3);    // 576 blocks, XCD-chunked
    const int p0 = swz * 64;
    const int imgb = (p0 / HW) * HW;
    const int tid = threadIdx.x, lane = tid & 63, wid = tid >> 6;
    const int wm = wid >> 1, wn = wid & 1;
    const int qa = ((lane >> 4) ^ ((lane >> 1) & 3)) * 8;
    // A-stage: row arow (32 rows), chan-octet acb (8 f16 each)
    const int arow = tid >> 3, acb = tid & 7;
    const int ah = acb >> 2, aq = acb & 3;
    const int adst = arow * 32 + ((aq ^ ((arow >> 1) & 3)) * 8);
    // B-stage: 2 pixels per thread (px0, px0+32), chan-group g
    const int px0 = tid >> 3, g = tid & 7;
    const int bh = g >> 2, bq = g & 3;
    const int bdst0 = px0 * 32 + ((bq ^ ((px0 >> 1) & 3)) * 8);
    const int px1 = px0 + 32;
    const int bdst1 = px1 * 32 + ((bq ^ ((px1 >> 1) & 3)) * 8);
    const int hw0 = p0 + px0 - imgb, hw1 = p0 + px1 - imgb;
    const int hp0 = hw0 / Wc, wp0 = hw0 - hp0 * Wc;
    const int hp1 = hw1 / Wc, wp1 = hw1 - hp1 * Wc;

#define CLOAD(q, aD, b0D, b1D) do {                                            \
    int q_ = (q) > 35 ? 35 : (q);                                              \
    int k2_ = q_ >> 2, cq_ = q_ & 3;                                           \
    int ky_ = k2_ / 3, kx_ = k2_ - ky_ * 3;                                    \
    aD = *(const f16x8*)(woffT + ((size_t)(k2_ * 32 + arow)) * Cc + cq_ * 64 + acb * 8); \
    int yy0_ = hp0 + ky_ - 1, xx0_ = wp0 + kx_ - 1;                            \
    f16x8 t0_ = {0, 0, 0, 0, 0, 0, 0, 0};                                      \
    if (yy0_ >= 0 && yy0_ < Hc && xx0_ >= 0 && xx0_ < Wc)                      \
        t0_ = *(const f16x8*)(x16 + ((size_t)(imgb + yy0_ * Wc + xx0_)) * Cc + cq_ * 64 + g * 8); \
    b0D = t0_;                                                                 \
    int yy1_ = hp1 + ky_ - 1, xx1_ = wp1 + kx_ - 1;                            \
    f16x8 t1_ = {0, 0, 0, 0, 0, 0, 0, 0};                                      \
    if (yy1_ >= 0 && yy1_ < Hc && xx1_ >= 0 && xx1_ < Wc)                      \
        t1_ = *(const f16x8*)(x16 + ((size_t)(imgb + yy1_ * Wc + xx1_)) * Cc + cq_ * 64 + g * 8); \
    b1D = t1_;                                                                 \
} while (0)

#define WSTAGE(aR, b0R, b1R, bn) do {                                          \
    *(f16x8*)&s_a[bn][ah][adst] = aR;                                          \
    *(f16x8*)&s_b[bn][bh][bdst0] = b0R;                                        \
    *(f16x8*)&s_b[bn][bh][bdst1] = b1R;                                        \
} while (0)

    f32x4 acc[2];
    acc[0] = (f32x4){0.f, 0.f, 0.f, 0.f};
    acc[1] = (f32x4){0.f, 0.f, 0.f, 0.f};

    f16x8 aR, b0R, b1R;
    // prologue: phase 0 staged to buf0
    CLOAD(0, aR, b0R, b1R);
    WSTAGE(aR, b0R, b1R, 0);
    asm volatile("s_waitcnt lgkmcnt(0)" ::: "memory"); SB();
    __builtin_amdgcn_s_barrier(); SB();

    for (int p = 0; p < 36; ++p) {
        const int bb = p & 1, nb = bb ^ 1;
        f16x8 af0 = *(const f16x8*)&s_a[bb][0][(wm * 16 + (lane & 15)) * 32 + qa];
        f16x8 af1 = *(const f16x8*)&s_a[bb][1][(wm * 16 + (lane & 15)) * 32 + qa];
        f16x8 bf0[2], bf1[2];
#pragma unroll
        for (int ni = 0; ni < 2; ++ni) {
            bf0[ni] = *(const f16x8*)&s_b[bb][0][(wn * 32 + ni * 16 + (lane & 15)) * 32 + qa];
            bf1[ni] = *(const f16x8*)&s_b[bb][1][(wn * 32 + ni * 16 + (lane & 15)) * 32 + qa];
        }
        CLOAD(p + 1, aR, b0R, b1R);
#pragma unroll
        for (int ni = 0; ni < 2; ++ni) {
            acc[ni] = __builtin_amdgcn_mfma_f32_16x16x32_f16(af0, bf0[ni], acc[ni], 0, 0, 0);
            acc[ni] = __builtin_amdgcn_mfma_f32_16x16x32_f16(af1, bf1[ni], acc[ni], 0, 0, 0);
        }
        WSTAGE(aR, b0R, b1R, nb);
        asm volatile("s_waitcnt lgkmcnt(0)" ::: "memory"); SB();
        __builtin_amdgcn_s_barrier(); SB();
    }

    // epilogue: wm=0 -> taps 0..7 (rows 4g..4g+3), wm=1 -> tap 8 (rows 16,17)
    const int eg = lane >> 4;
#pragma unroll
    for (int ni = 0; ni < 2; ++ni) {
        const int p = p0 + wn * 32 + ni * 16 + (lane & 15);
        const int hwq = p - imgb;
        const int hq = hwq / Wc, wq = hwq - hq * Wc;
        if (wm == 0) {
            store_tap(2 * eg,     hq, wq, acc[ni][0] + b_off[4 * eg],
                                          acc[ni][1] + b_off[4 * eg + 1], p, idx4t, wt4t);
            store_tap(2 * eg + 1, hq, wq, acc[ni][2] + b_off[4 * eg + 2],
                                          acc[ni][3] + b_off[4 * eg + 3], p, idx4t, wt4t);
        } else if (eg == 0) {
            store_tap(8, hq, wq, acc[ni][0] + b_off[16],
                                 acc[ni][1] + b_off[17], p, idx4t, wt4t);
        }
    }
#undef CLOAD
#undef WSTAGE
}

// Fused deformable sampling (f16 NHWC gathers) + f16 MFMA GEMM + ReLU.
// Block: 768 threads (12 waves), 256 out x 144 pix; wave = 64out x 48pix.
// K=64/chunk (36 chunks), 1 block/CU, weight staged once per CU. Packed-f16
// bilinear blend; weight row 192..255 loads on waves 8-11. (R20, passing.)
__global__ __launch_bounds__(768, 3) void deform_mfma_kernel(
    const f16* __restrict__ x16, const f16* __restrict__ wT2,
    const int4* __restrict__ idx4t, const float4* __restrict__ wt4t,
    f16* __restrict__ o16, float* __restrict__ oN, int last)
{
    __shared__ __align__(16) f16 s_w[2][2][8192];  // [buf][half][256o x 32c swz] 64KB
    __shared__ __align__(16) f16 s_s[2][2][4608];  // [buf][half][144p x 32c swz] 36KB

    const int bid = blockIdx.x;
    const int swz = (bid & 7) * 32 + (bid >> 3); // 256 blocks, XCD-chunked
    const int p0 = swz * 144;                    // 9216/144=64 -> no straddle
    const int imgb = (p0 / HW) * HW;
    const int tid = threadIdx.x, lane = tid & 63, wid = tid >> 6;
    const int wo = wid & 3, wp = wid >> 2;       // out-group, pix-group
    const bool sampler = (wid < 9);              // tids 0..575 <=> ps 0..143
    const int ps = tid >> 2, cg = tid & 3;
    const int qa = ((lane >> 4) ^ ((lane >> 1) & 3)) * 8;
    const int qs = (cg ^ ((ps >> 1) & 3)) * 8;
    const f16* xb = x16 + (size_t)imgb * Cc;
    const int wlo = (tid >> 2) * Cc + ((tid & 3) ^ ((tid >> 3) & 3)) * 8;
    const int wds = tid * 8;                     // u0 LDS slot base (elems)

#define ISSUE_W(kt, cq, h, nb) do {                                            \
    const f16* g0_ = wT2 + wlo + ((size_t)((kt) * 256)) * Cc + (cq) * 64 + (h) * 32; \
    __builtin_amdgcn_global_load_lds(                                          \
        (const __attribute__((address_space(1))) void*)g0_,                    \
        (__attribute__((address_space(3))) void*)&s_w[nb][h][wds], 16, 0, 0);  \
    if (wid >= 8) {                                                            \
        const f16* g1_ = wT2 + wlo + ((size_t)((kt) * 256 + 64)) * Cc + (cq) * 64 + (h) * 32; \
        __builtin_amdgcn_global_load_lds(                                      \
            (const __attribute__((address_space(1))) void*)g1_,                \
            (__attribute__((address_space(3))) void*)&s_w[nb][h][2048 + wds], 16, 0, 0); \
    }                                                                          \
} while (0)

// 4 lanes (cg=0..3) of pixel ps read contiguous 64B per corner
#define ISSUE_C(dst, idv, co) do {                                             \
    (dst)[0] = *(const f16x8*)(xb + (size_t)(idv).x * Cc + (co) + cg * 8);     \
    (dst)[1] = *(const f16x8*)(xb + (size_t)(idv).y * Cc + (co) + cg * 8);     \
    (dst)[2] = *(const f16x8*)(xb + (size_t)(idv).z * Cc + (co) + cg * 8);     \
    (dst)[3] = *(const f16x8*)(xb + (size_t)(idv).w * Cc + (co) + cg * 8);     \
} while (0)

// packed-f16 bilinear blend (v_pk_mul/fma via f16x8 vector arith)
#define BLEND_WRITE(src, wvv, h, nb) do {                                      \
    f16x8 sv_ = (src)[0] * (f16)(wvv).x + (src)[1] * (f16)(wvv).y              \
              + (src)[2] * (f16)(wvv).z + (src)[3] * (f16)(wvv).w;             \
    *(f16x8*)&s_s[nb][h][ps * 32 + qs] = sv_;                                  \
} while (0)

    f32x4 acc[4][3];
#pragma unroll
    for (int mi = 0; mi < 4; ++mi)
#pragma unroll
        for (int ni = 0; ni < 3; ++ni) acc[mi][ni] = (f32x4){0.f, 0.f, 0.f, 0.f};

    f16x8 c4a[4], c4b[4];        // next chunk's corners, one buffer per half
    int4 id;
    float4 wv;
    int4 idN;
    float4 wvN;
    if (sampler) {
        id = idx4t[p0 + ps];
        wv = wt4t[p0 + ps];
    }

    // prologue: stage W(chunk0) both halves; samplers fill s_s[0][*] from
    // C(chunk0) and leave C(chunk1) x8 in flight; non-samplers drain W.
    ISSUE_W(0, 0, 0, 0);
    ISSUE_W(0, 0, 1, 0);
    SB();
    if (sampler) {
        ISSUE_C(c4a, id, 0);               // chunk0 half0
        ISSUE_C(c4b, id, 32);              // chunk0 half1
        BLEND_WRITE(c4a, wv, 0, 0);        // counted vmcnt retires W+C as needed
        BLEND_WRITE(c4b, wv, 1, 0);
        ISSUE_C(c4a, id, 64);              // chunk1 half0
        ISSUE_C(c4b, id, 96);              // chunk1 half1
        asm volatile("s_waitcnt lgkmcnt(0)" ::: "memory"); SB();
        if (wid == 8) {
            asm volatile("s_waitcnt vmcnt(8)" ::: "memory"); SB();
        }
    } else {
        asm volatile("s_waitcnt vmcnt(0)" ::: "memory"); SB();
    }
    __builtin_amdgcn_s_barrier(); SB();

    for (int k = 0; k < 9; ++k) {
        const int kn = (k < 8) ? k + 1 : 8;
#pragma unroll
        for (int ch = 0; ch < 4; ++ch) {   // chunk = 64 chans
            const int bb = ch & 1, nb = bb ^ 1;
            f16x8 bf0[3], bf1[3];
#pragma unroll
            for (int ni = 0; ni < 3; ++ni) {
                bf0[ni] = *(const f16x8*)&s_s[bb][0][(wp * 48 + ni * 16 + (lane & 15)) * 32 + qa];
                bf1[ni] = *(const f16x8*)&s_s[bb][1][(wp * 48 + ni * 16 + (lane & 15)) * 32 + qa];
            }
            if (sampler) {
                if (ch == 1) {             // late load: needed from ch2
                    idN = idx4t[(size_t)kn * PIX + p0 + ps];
                    wvN = wt4t[(size_t)kn * PIX + p0 + ps];
                }
                ISSUE_W((ch == 3) ? kn : k, (ch + 1) & 3, 0, nb);
                ISSUE_W((ch == 3) ? kn : k, (ch + 1) & 3, 1, nb);
                SB();                      // pin W (and idwv) before C issue
                {
                    const float4 wvu = (ch == 3) ? wvN : wv;
                    const int4 idu = (ch >= 2) ? idN : id;
                    const int co2 = ((ch + 2) & 3) * 64;
                    BLEND_WRITE(c4a, wvu, 0, nb);
                    ISSUE_C(c4a, idu, co2);
                    BLEND_WRITE(c4b, wvu, 1, nb);
                    ISSUE_C(c4b, idu, co2 + 32);
                }
            } else {
                ISSUE_W((ch == 3) ? kn : k, (ch + 1) & 3, 0, nb);
                ISSUE_W((ch == 3) ? kn : k, (ch + 1) & 3, 1, nb);
                SB();
            }
            // MFMAs: 24 (two halves), af streamed per-mi
#pragma unroll
            for (int mi = 0; mi < 4; ++mi) {
                f16x8 af = *(const f16x8*)&s_w[bb][0][(wo * 64 + mi * 16 + (lane & 15)) * 32 + qa];
#pragma unroll
                for (int ni = 0; ni < 3; ++ni)
                    acc[mi][ni] = __builtin_amdgcn_mfma_f32_16x16x32_f16(
                        af, bf0[ni], acc[mi][ni], 0, 0, 0);
            }
#pragma unroll
            for (int mi = 0; mi < 4; ++mi) {
                f16x8 af = *(const f16x8*)&s_w[bb][1][(wo * 64 + mi * 16 + (lane & 15)) * 32 + qa];
#pragma unroll
                for (int ni = 0; ni < 3; ++ni)
                    acc[mi][ni] = __builtin_amdgcn_mfma_f32_16x16x32_f16(
                        af, bf1[ni], acc[mi][ni], 0, 0, 0);
            }
            // RACE-FREE POINT: drain own ds_writes (lgkm) and own W-to-LDS
            // (vmcnt) BEFORE the barrier. Waves 0-8: queue = [(idwv,) W old,
            // C x8] -> vmcnt(8). Waves 9-11: [W x4] -> vmcnt(0).
            asm volatile("s_waitcnt lgkmcnt(0)" ::: "memory"); SB();
            if (sampler) {
                asm volatile("s_waitcnt vmcnt(8)" ::: "memory"); SB();
            } else {
                asm volatile("s_waitcnt vmcnt(0)" ::: "memory"); SB();
            }
            __builtin_amdgcn_s_barrier(); SB();
        }
        if (sampler) { id = idN; wv = wvN; }
    }

    // epilogue: ReLU; D row = output = (lane>>4)*4+j, col = pixel = lane&15
    if (!last) {
#pragma unroll
        for (int ni = 0; ni < 3; ++ni) {
            const int p = p0 + wp * 48 + ni * 16 + (lane & 15);
#pragma unroll
            for (int mi = 0; mi < 4; ++mi) {
                const int o0 = wo * 64 + mi * 16 + (lane >> 4) * 4;
                f32x4 v = acc[mi][ni];
                f16x4 h = {(f16)fmaxf(v[0], 0.f), (f16)fmaxf(v[1], 0.f),
                           (f16)fmaxf(v[2], 0.f), (f16)fmaxf(v[3], 0.f)};
                *(f16x4*)&o16[(size_t)p * Cc + o0] = h;
            }
        }
    } else {
        const int bimg = imgb / HW;
#pragma unroll
        for (int ni = 0; ni < 3; ++ni) {
            const int p = p0 + wp * 48 + ni * 16 + (lane & 15);
            const int hwl = p - imgb;
#pragma unroll
            for (int mi = 0; mi < 4; ++mi) {
                const int o0 = wo * 64 + mi * 16 + (lane >> 4) * 4;
#pragma unroll
                for (int j = 0; j < 4; ++j)
                    oN[((size_t)(bimg * Cc + o0 + j)) * HW + hwl] =
                        fmaxf(acc[mi][ni][j], 0.f);
            }
        }
    }
#undef ISSUE_W
#undef ISSUE_C
#undef BLEND_WRITE
}

extern "C" void kernel_launch(void* const* d_in, const int* in_sizes, int n_in,
                              void* d_out, int out_size, void* d_ws, size_t ws_size,
                              hipStream_t stream)
{
    const float* x0 = (const float*)d_in[0];
    float* out = (float*)d_out;

    f16*   x16a = (f16*)d_ws;                          // PIX*Cc f16
    f16*   x16b = x16a + (size_t)PIX * Cc;             // PIX*Cc f16
    f16*   wT2  = x16b + (size_t)PIX * Cc;             // CK*Cc f16
    f16*   woffT = wT2 + (size_t)CK * Cc;              // 9*32*256 f16
    int4*  idx4t = (int4*)(woffT + (size_t)9 * 32 * Cc);
    float4* wt4t = (float4*)(idx4t + (size_t)KK * PIX);

    nhwc_prep_kernel<<<dim3(HW / 64, Cc / 64, Bc), 256, 0, stream>>>(x0, x16a);

    const f16* xin = x16a;
    for (int L = 0; L < 3; ++L) {
        const float* w_off = (const float*)d_in[1 + 3 * L];
        const float* b_off = (const float*)d_in[2 + 3 * L];
        const float* w     = (const float*)d_in[3 + 3 * L];
        const int last = (L == 2);
        f16* xo = (L == 0) ? x16b : x16a;

        wprep_kernel<<<2592, 256, 0, stream>>>(w, w_off, wT2, woffT);
        conv_off_mfma_kernel<<<PIX / 64, 256, 0, stream>>>(xin, woffT, b_off, idx4t, wt4t);
        deform_mfma_kernel<<<PIX / 144, 768, 0, stream>>>(
            xin, wT2, idx4t, wt4t, xo, out, last);

        xin = xo;
    }
}

// Round 22
// 258.182 us; speedup vs baseline: 2.0579x; 1.0926x over previous
//
#include <hip/hip_runtime.h>

#define Hc 96
#define Wc 96
#define Cc 256
#define Bc 4
#define KK 9
#define HW 9216          // Hc*Wc
#define PIX 36864        // Bc*HW
#define CK 2304          // Cc*KK

typedef _Float16 f16;
typedef __attribute__((ext_vector_type(4))) _Float16 f16x4;
typedef __attribute__((ext_vector_type(8))) _Float16 f16x8;
typedef __attribute__((ext_vector_type(4))) float f32x4;

__device__ __forceinline__ int clampi(int v, int lo, int hi) {
    return v < lo ? lo : (v > hi ? hi : v);
}

#define SB() __builtin_amdgcn_sched_barrier(0)

// ---------- prep: NCHW fp32 -> NHWC f16 (layer 0 input) ----------
__global__ __launch_bounds__(256) void nhwc_prep_kernel(
    const float* __restrict__ x0, f16* __restrict__ x16)
{
    __shared__ float st[64][65];
    const int hw0 = blockIdx.x * 64;
    const int c0  = blockIdx.y * 64;
    const int b   = blockIdx.z;
    const int tid = threadIdx.x;
    const int a = tid & 63, r = tid >> 6;
#pragma unroll
    for (int it = 0; it < 16; ++it) {
        int cl = it * 4 + r;
        st[cl][a] = x0[((size_t)(b * Cc + c0 + cl)) * HW + hw0 + a];
    }
    __syncthreads();
#pragma unroll
    for (int it = 0; it < 16; ++it) {
        int hwl = it * 4 + r;
        x16[((size_t)(b * HW + hw0 + hwl)) * Cc + c0 + a] = (f16)st[a][hwl];
    }
}

// all-layer weight prep in ONE launch:
// per layer l: blocks 0..2303 -> wT2_l ; blocks 2304..2591 -> woffT_l
__global__ __launch_bounds__(256) void wprep_all_kernel(
    const float* __restrict__ w0, const float* __restrict__ wo0,
    const float* __restrict__ w1, const float* __restrict__ wo1,
    const float* __restrict__ w2, const float* __restrict__ wo2,
    f16* __restrict__ wT2, f16* __restrict__ woffT)
{
    int bb = blockIdx.x;
    int l = bb / 2592, b = bb - l * 2592;
    const float* w = (l == 0) ? w0 : (l == 1) ? w1 : w2;
    const float* wo = (l == 0) ? wo0 : (l == 1) ? wo1 : wo2;
    if (b < 2304) {
        int u = b * 256 + threadIdx.x;        // < 589824
        int c = u & 255, o = (u >> 8) & 255, k = u >> 16;
        wT2[(size_t)l * CK * Cc + u] = (f16)w[(o * Cc + c) * KK + k];
    } else {
        int u = (b - 2304) * 256 + threadIdx.x; // < 73728
        int c = u & 255, j = (u >> 8) & 31, k = u >> 13;
        float v = (j < 18) ? wo[((size_t)j * Cc + c) * KK + k] : 0.f;
        woffT[(size_t)l * 9 * 32 * Cc + u] = (f16)v;
    }
}

// FUSED: offset-conv (phase A) + deformable sampling + GEMM + ReLU (phase B).
// Block: 768 threads (12 waves), 256 out x 144 pix. Grid = 256 = 1 block/CU.
// Phase A: 32(off-rows) x 144(px) x 2304 f16 MFMA GEMM; waves 0-8 own one
// 16-px column (mi=0,1), waves 9-11 stage the A operand; store_tap results
// go to LDS s_id/s_wt (no global idx/wt round-trip, no separate launch).
// Phase B: R20-proven deform loop; id/wv now LDS reads (vmcnt accounting
// simplifies: sampler queue = [W x1-2, C x8] -> vmcnt(8) retires W).
__global__ __launch_bounds__(768, 3) void fused_layer_kernel(
    const f16* __restrict__ x16, const f16* __restrict__ wT2,
    const f16* __restrict__ woffT, const float* __restrict__ b_off,
    f16* __restrict__ o16, float* __restrict__ oN, int last)
{
    __shared__ __align__(16) f16 s_w[2][2][8192];  // 64KB  [buf][half][256o x 32c swz]
    __shared__ __align__(16) f16 s_s[2][2][4608];  // 36KB  [buf][half][144p x 32c swz]
    __shared__ __align__(16) f16 s_a[2][2][1024];  // 8KB   [buf][half][32r x 32c swz]
    __shared__ int4   s_id[9][144];                // 20.25KB
    __shared__ float4 s_wt[9][144];                // 20.25KB

    const int bid = blockIdx.x;
    const int swz = (bid & 7) * 32 + (bid >> 3); // 256 blocks, XCD-chunked
    const int p0 = swz * 144;                    // no image straddle
    const int imgb = (p0 / HW) * HW;
    const int tid = threadIdx.x, lane = tid & 63, wid = tid >> 6;
    const int wo = wid & 3, wp = wid >> 2;
    const bool sampler = (wid < 9);              // tids 0..575 <=> ps 0..143
    const int ps = tid >> 2, cg = tid & 3;
    const int qa = ((lane >> 4) ^ ((lane >> 1) & 3)) * 8;
    const int qs = (cg ^ ((ps >> 1) & 3)) * 8;
    const f16* xb = x16 + (size_t)imgb * Cc;
    const int wlo = (tid >> 2) * Cc + ((tid & 3) ^ ((tid >> 3) & 3)) * 8;
    const int wds = tid * 8;
    // sampler pixel coords (valid for tid<576)
    const int hwp = p0 + ps - imgb;
    const int hp = hwp / Wc, wp_ = hwp - hp * Wc;
    // phase-A A-stage mapping (tids 576..767; tids 576..639 take a 2nd slot)
    const int au0 = tid - 576;
    const int arow0 = au0 >> 3, acb0 = au0 & 7;
    const int ah0 = acb0 >> 2, aq0 = acb0 & 3;
    const int adst0 = arow0 * 32 + ((aq0 ^ ((arow0 >> 1) & 3)) * 8);
    const int arow1 = arow0 + 24;
    const int adst1 = arow1 * 32 + ((aq0 ^ ((arow1 >> 1) & 3)) * 8);

    // ================= PHASE A: offset conv =================
    {
        f32x4 accA[2];
        accA[0] = (f32x4){0.f, 0.f, 0.f, 0.f};
        accA[1] = (f32x4){0.f, 0.f, 0.f, 0.f};
        f16x8 bR0, bR1, aR0, aR1;

#define PA_LOAD(q) do {                                                        \
    int q_ = (q) > 35 ? 35 : (q);                                              \
    int k2_ = q_ >> 2, cq_ = q_ & 3;                                           \
    int ky_ = k2_ / 3, kx_ = k2_ - ky_ * 3;                                    \
    if (sampler) {                                                             \
        int yy_ = hp + ky_ - 1, xx_ = wp_ + kx_ - 1;                           \
        f16x8 t0_ = {0,0,0,0,0,0,0,0}, t1_ = {0,0,0,0,0,0,0,0};                \
        if (yy_ >= 0 && yy_ < Hc && xx_ >= 0 && xx_ < Wc) {                    \
            const f16* s_ = x16 + ((size_t)(imgb + yy_ * Wc + xx_)) * Cc + cq_ * 64 + cg * 8; \
            t0_ = *(const f16x8*)s_;                                           \
            t1_ = *(const f16x8*)(s_ + 32);                                    \
        }                                                                      \
        bR0 = t0_; bR1 = t1_;                                                  \
    } else {                                                                   \
        aR0 = *(const f16x8*)(woffT + ((size_t)(k2_ * 32 + arow0)) * Cc + cq_ * 64 + acb0 * 8); \
        if (tid < 640)                                                         \
            aR1 = *(const f16x8*)(woffT + ((size_t)(k2_ * 32 + arow1)) * Cc + cq_ * 64 + acb0 * 8); \
    }                                                                          \
} while (0)

#define PA_STAGE(nb) do {                                                      \
    if (sampler) {                                                             \
        *(f16x8*)&s_s[nb][0][ps * 32 + qs] = bR0;                              \
        *(f16x8*)&s_s[nb][1][ps * 32 + qs] = bR1;                              \
    } else {                                                                   \
        *(f16x8*)&s_a[nb][ah0][adst0] = aR0;                                   \
        if (tid < 640) *(f16x8*)&s_a[nb][ah0][adst1] = aR1;                    \
    }                                                                          \
} while (0)

        PA_LOAD(0);
        PA_STAGE(0);
        asm volatile("s_waitcnt lgkmcnt(0)" ::: "memory"); SB();
        __builtin_amdgcn_s_barrier(); SB();

        for (int p = 0; p < 36; ++p) {
            const int bb = p & 1, nb = bb ^ 1;
            f16x8 af0, af1, bf0, bf1;
            if (sampler) {
                af0 = *(const f16x8*)&s_a[bb][0][((lane & 15)) * 32 + qa];
                af1 = *(const f16x8*)&s_a[bb][0][((16 + (lane & 15))) * 32 + qa];
                bf0 = *(const f16x8*)&s_s[bb][0][(wid * 16 + (lane & 15)) * 32 + qa];
            }
            PA_LOAD(p + 1);
            if (sampler) {
                accA[0] = __builtin_amdgcn_mfma_f32_16x16x32_f16(af0, bf0, accA[0], 0, 0, 0);
                accA[1] = __builtin_amdgcn_mfma_f32_16x16x32_f16(af1, bf0, accA[1], 0, 0, 0);
                af0 = *(const f16x8*)&s_a[bb][1][((lane & 15)) * 32 + qa];
                af1 = *(const f16x8*)&s_a[bb][1][((16 + (lane & 15))) * 32 + qa];
                bf1 = *(const f16x8*)&s_s[bb][1][(wid * 16 + (lane & 15)) * 32 + qa];
                accA[0] = __builtin_amdgcn_mfma_f32_16x16x32_f16(af0, bf1, accA[0], 0, 0, 0);
                accA[1] = __builtin_amdgcn_mfma_f32_16x16x32_f16(af1, bf1, accA[1], 0, 0, 0);
            }
            PA_STAGE(nb);
            asm volatile("s_waitcnt lgkmcnt(0)" ::: "memory"); SB();
            __builtin_amdgcn_s_barrier(); SB();
        }

        // epilogue A: rows 4q..4q+3 -> taps 2q,2q+1 ; rows 16,17 (q==0) -> tap 8
        if (sampler) {
            const int q = lane >> 4;
            const int pxl = wid * 16 + (lane & 15);
            const int hwq = p0 + pxl - imgb;
            const int hq = hwq / Wc, wq = hwq - hq * Wc;
#define STORE_TAP_LDS(kk, offy, offx) do {                                     \
    float py_ = (float)(hq - 1 + (kk) / 3) + (offy);                           \
    float px_ = (float)(wq - 1 + (kk) % 3) + (offx);                           \
    float y0f_ = floorf(py_), x0f_ = floorf(px_);                              \
    float wy_ = py_ - y0f_, wx_ = px_ - x0f_;                                  \
    int iy0_ = (int)y0f_, ix0_ = (int)x0f_;                                    \
    float vy0_ = (y0f_ >= 0.f && y0f_ <= 95.f) ? 1.f : 0.f;                    \
    float vy1_ = (y0f_ + 1.f >= 0.f && y0f_ + 1.f <= 95.f) ? 1.f : 0.f;        \
    float vx0_ = (x0f_ >= 0.f && x0f_ <= 95.f) ? 1.f : 0.f;                    \
    float vx1_ = (x0f_ + 1.f >= 0.f && x0f_ + 1.f <= 95.f) ? 1.f : 0.f;        \
    int cy0_ = clampi(iy0_, 0, 95), cy1_ = clampi(iy0_ + 1, 0, 95);            \
    int cx0_ = clampi(ix0_, 0, 95), cx1_ = clampi(ix0_ + 1, 0, 95);            \
    s_id[kk][pxl] = make_int4(cy0_ * Wc + cx0_, cy0_ * Wc + cx1_,              \
                              cy1_ * Wc + cx0_, cy1_ * Wc + cx1_);             \
    s_wt[kk][pxl] = make_float4((1.f - wy_) * (1.f - wx_) * vy0_ * vx0_,       \
                                (1.f - wy_) * wx_ * vy0_ * vx1_,               \
                                wy_ * (1.f - wx_) * vy1_ * vx0_,               \
                                wy_ * wx_ * vy1_ * vx1_);                      \
} while (0)
            STORE_TAP_LDS(2 * q,     accA[0][0] + b_off[4 * q],
                                     accA[0][1] + b_off[4 * q + 1]);
            STORE_TAP_LDS(2 * q + 1, accA[0][2] + b_off[4 * q + 2],
                                     accA[0][3] + b_off[4 * q + 3]);
            if (q == 0)
                STORE_TAP_LDS(8, accA[1][0] + b_off[16], accA[1][1] + b_off[17]);
#undef STORE_TAP_LDS
        }
        asm volatile("s_waitcnt lgkmcnt(0)" ::: "memory"); SB();
        __builtin_amdgcn_s_barrier(); SB();
    }

    // ================= PHASE B: deform (R20-proven) =================
#define ISSUE_W(kt, cq, h, nb) do {                                            \
    const f16* g0_ = wT2 + wlo + ((size_t)((kt) * 256)) * Cc + (cq) * 64 + (h) * 32; \
    __builtin_amdgcn_global_load_lds(                                          \
        (const __attribute__((address_space(1))) void*)g0_,                    \
        (__attribute__((address_space(3))) void*)&s_w[nb][h][wds], 16, 0, 0);  \
    if (wid >= 8) {                                                            \
        const f16* g1_ = wT2 + wlo + ((size_t)((kt) * 256 + 64)) * Cc + (cq) * 64 + (h) * 32; \
        __builtin_amdgcn_global_load_lds(                                      \
            (const __attribute__((address_space(1))) void*)g1_,                \
            (__attribute__((address_space(3))) void*)&s_w[nb][h][2048 + wds], 16, 0, 0); \
    }                                                                          \
} while (0)

#define ISSUE_C(dst, idv, co) do {                                             \
    (dst)[0] = *(const f16x8*)(xb + (size_t)(idv).x * Cc + (co) + cg * 8);     \
    (dst)[1] = *(const f16x8*)(xb + (size_t)(idv).y * Cc + (co) + cg * 8);     \
    (dst)[2] = *(const f16x8*)(xb + (size_t)(idv).z * Cc + (co) + cg * 8);     \
    (dst)[3] = *(const f16x8*)(xb + (size_t)(idv).w * Cc + (co) + cg * 8);     \
} while (0)

#define BLEND_WRITE(src, wvv, h, nb) do {                                      \
    f16x8 sv_ = (src)[0] * (f16)(wvv).x + (src)[1] * (f16)(wvv).y              \
              + (src)[2] * (f16)(wvv).z + (src)[3] * (f16)(wvv).w;             \
    *(f16x8*)&s_s[nb][h][ps * 32 + qs] = sv_;                                  \
} while (0)

    f32x4 acc[4][3];
#pragma unroll
    for (int mi = 0; mi < 4; ++mi)
#pragma unroll
        for (int ni = 0; ni < 3; ++ni) acc[mi][ni] = (f32x4){0.f, 0.f, 0.f, 0.f};

    f16x8 c4a[4], c4b[4];
    int4 id;
    float4 wv;
    int4 idN;
    float4 wvN;
    if (sampler) {
        id = s_id[0][ps];
        wv = s_wt[0][ps];
    }

    ISSUE_W(0, 0, 0, 0);
    ISSUE_W(0, 0, 1, 0);
    SB();
    if (sampler) {
        ISSUE_C(c4a, id, 0);
        ISSUE_C(c4b, id, 32);
        BLEND_WRITE(c4a, wv, 0, 0);
        BLEND_WRITE(c4b, wv, 1, 0);
        ISSUE_C(c4a, id, 64);
        ISSUE_C(c4b, id, 96);
        asm volatile("s_waitcnt lgkmcnt(0)" ::: "memory"); SB();
        if (wid == 8) {
            asm volatile("s_waitcnt vmcnt(8)" ::: "memory"); SB();
        }
    } else {
        asm volatile("s_waitcnt vmcnt(0)" ::: "memory"); SB();
    }
    __builtin_amdgcn_s_barrier(); SB();

    for (int k = 0; k < 9; ++k) {
        const int kn = (k < 8) ? k + 1 : 8;
#pragma unroll
        for (int ch = 0; ch < 4; ++ch) {
            const int bb = ch & 1, nb = bb ^ 1;
            f16x8 bf0[3], bf1[3];
#pragma unroll
            for (int ni = 0; ni < 3; ++ni) {
                bf0[ni] = *(const f16x8*)&s_s[bb][0][(wp * 48 + ni * 16 + (lane & 15)) * 32 + qa];
                bf1[ni] = *(const f16x8*)&s_s[bb][1][(wp * 48 + ni * 16 + (lane & 15)) * 32 + qa];
            }
            if (sampler) {
                if (ch == 1) {             // LDS read; needed from ch2
                    idN = s_id[kn][ps];
                    wvN = s_wt[kn][ps];
                }
                ISSUE_W((ch == 3) ? kn : k, (ch + 1) & 3, 0, nb);
                ISSUE_W((ch == 3) ? kn : k, (ch + 1) & 3, 1, nb);
                SB();
                {
                    const float4 wvu = (ch == 3) ? wvN : wv;
                    const int4 idu = (ch >= 2) ? idN : id;
                    const int co2 = ((ch + 2) & 3) * 64;
                    BLEND_WRITE(c4a, wvu, 0, nb);
                    ISSUE_C(c4a, idu, co2);
                    BLEND_WRITE(c4b, wvu, 1, nb);
                    ISSUE_C(c4b, idu, co2 + 32);
                }
            } else {
                ISSUE_W((ch == 3) ? kn : k, (ch + 1) & 3, 0, nb);
                ISSUE_W((ch == 3) ? kn : k, (ch + 1) & 3, 1, nb);
                SB();
            }
#pragma unroll
            for (int mi = 0; mi < 4; ++mi) {
                f16x8 af = *(const f16x8*)&s_w[bb][0][(wo * 64 + mi * 16 + (lane & 15)) * 32 + qa];
#pragma unroll
                for (int ni = 0; ni < 3; ++ni)
                    acc[mi][ni] = __builtin_amdgcn_mfma_f32_16x16x32_f16(
                        af, bf0[ni], acc[mi][ni], 0, 0, 0);
            }
#pragma unroll
            for (int mi = 0; mi < 4; ++mi) {
                f16x8 af = *(const f16x8*)&s_w[bb][1][(wo * 64 + mi * 16 + (lane & 15)) * 32 + qa];
#pragma unroll
                for (int ni = 0; ni < 3; ++ni)
                    acc[mi][ni] = __builtin_amdgcn_mfma_f32_16x16x32_f16(
                        af, bf1[ni], acc[mi][ni], 0, 0, 0);
            }
            // RACE-FREE POINT: drain own ds_writes + own W-to-LDS before the
            // barrier. Waves 0-8: [W x1-2, C x8] -> vmcnt(8). 9-11: vmcnt(0).
            asm volatile("s_waitcnt lgkmcnt(0)" ::: "memory"); SB();
            if (sampler) {
                asm volatile("s_waitcnt vmcnt(8)" ::: "memory"); SB();
            } else {
                asm volatile("s_waitcnt vmcnt(0)" ::: "memory"); SB();
            }
            __builtin_amdgcn_s_barrier(); SB();
        }
        if (sampler) { id = idN; wv = wvN; }
    }

    // epilogue: ReLU; D row = output = (lane>>4)*4+j, col = pixel = lane&15
    if (!last) {
#pragma unroll
        for (int ni = 0; ni < 3; ++ni) {
            const int p = p0 + wp * 48 + ni * 16 + (lane & 15);
#pragma unroll
            for (int mi = 0; mi < 4; ++mi) {
                const int o0 = wo * 64 + mi * 16 + (lane >> 4) * 4;
                f32x4 v = acc[mi][ni];
                f16x4 h = {(f16)fmaxf(v[0], 0.f), (f16)fmaxf(v[1], 0.f),
                           (f16)fmaxf(v[2], 0.f), (f16)fmaxf(v[3], 0.f)};
                *(f16x4*)&o16[(size_t)p * Cc + o0] = h;
            }
        }
    } else {
        const int bimg = imgb / HW;
#pragma unroll
        for (int ni = 0; ni < 3; ++ni) {
            const int p = p0 + wp * 48 + ni * 16 + (lane & 15);
            const int hwl = p - imgb;
#pragma unroll
            for (int mi = 0; mi < 4; ++mi) {
                const int o0 = wo * 64 + mi * 16 + (lane >> 4) * 4;
#pragma unroll
                for (int j = 0; j < 4; ++j)
                    oN[((size_t)(bimg * Cc + o0 + j)) * HW + hwl] =
                        fmaxf(acc[mi][ni][j], 0.f);
            }
        }
    }
#undef ISSUE_W
#undef ISSUE_C
#undef BLEND_WRITE
#undef PA_LOAD
#undef PA_STAGE
}

extern "C" void kernel_launch(void* const* d_in, const int* in_sizes, int n_in,
                              void* d_out, int out_size, void* d_ws, size_t ws_size,
                              hipStream_t stream)
{
    const float* x0 = (const float*)d_in[0];
    float* out = (float*)d_out;

    f16*   x16a = (f16*)d_ws;                          // PIX*Cc f16
    f16*   x16b = x16a + (size_t)PIX * Cc;             // PIX*Cc f16
    f16*   wT2  = x16b + (size_t)PIX * Cc;             // 3 * CK*Cc f16
    f16*   woffT = wT2 + (size_t)3 * CK * Cc;          // 3 * 9*32*256 f16

    nhwc_prep_kernel<<<dim3(HW / 64, Cc / 64, Bc), 256, 0, stream>>>(x0, x16a);
    wprep_all_kernel<<<3 * 2592, 256, 0, stream>>>(
        (const float*)d_in[3], (const float*)d_in[1],
        (const float*)d_in[6], (const float*)d_in[4],
        (const float*)d_in[9], (const float*)d_in[7],
        wT2, woffT);

    const f16* xin = x16a;
    for (int L = 0; L < 3; ++L) {
        const float* b_off = (const float*)d_in[2 + 3 * L];
        const int last = (L == 2);
        f16* xo = (L == 0) ? x16b : x16a;

        fused_layer_kernel<<<PIX / 144, 768, 0, stream>>>(
            xin, wT2 + (size_t)L * CK * Cc, woffT + (size_t)L * 9 * 32 * Cc,
            b_off, xo, out, last);

        xin = xo;
    }
}

// Round 24
// 241.698 us; speedup vs baseline: 2.1982x; 1.0682x over previous
//
#include <hip/hip_runtime.h>

#define Hc 96
#define Wc 96
#define Cc 256
#define Bc 4
#define KK 9
#define HW 9216          // Hc*Wc
#define PIX 36864        // Bc*HW
#define CK 2304          // Cc*KK

typedef _Float16 f16;
typedef __attribute__((ext_vector_type(4))) _Float16 f16x4;
typedef __attribute__((ext_vector_type(8))) _Float16 f16x8;
typedef __attribute__((ext_vector_type(4))) float f32x4;

__device__ __forceinline__ int clampi(int v, int lo, int hi) {
    return v < lo ? lo : (v > hi ? hi : v);
}

#define SB() __builtin_amdgcn_sched_barrier(0)

// ---------- merged prep: NCHW->NHWC f16 (blocks 0..2303) + all-layer weight
// transpose (blocks 2304..10079) in ONE launch ----------
__global__ __launch_bounds__(256) void prep_all_kernel(
    const float* __restrict__ x0,
    const float* __restrict__ w0, const float* __restrict__ wo0,
    const float* __restrict__ w1, const float* __restrict__ wo1,
    const float* __restrict__ w2, const float* __restrict__ wo2,
    f16* __restrict__ x16, f16* __restrict__ wT2, f16* __restrict__ woffT)
{
    const int blk = blockIdx.x;
    const int tid = threadIdx.x;
    if (blk < 2304) {
        __shared__ float st[64][65];
        const int hw0 = (blk % 144) * 64;
        const int c0  = ((blk / 144) & 3) * 64;
        const int b   = blk / 576;
        const int a = tid & 63, r = tid >> 6;
#pragma unroll
        for (int it = 0; it < 16; ++it) {
            int cl = it * 4 + r;
            st[cl][a] = x0[((size_t)(b * Cc + c0 + cl)) * HW + hw0 + a];
        }
        __syncthreads();
#pragma unroll
        for (int it = 0; it < 16; ++it) {
            int hwl = it * 4 + r;
            x16[((size_t)(b * HW + hw0 + hwl)) * Cc + c0 + a] = (f16)st[a][hwl];
        }
    } else {
        const int bb = blk - 2304;
        const int l = bb / 2592, b = bb - l * 2592;
        const float* w = (l == 0) ? w0 : (l == 1) ? w1 : w2;
        const float* wo = (l == 0) ? wo0 : (l == 1) ? wo1 : wo2;
        if (b < 2304) {
            int u = b * 256 + tid;            // < 589824
            int c = u & 255, o = (u >> 8) & 255, k = u >> 16;
            wT2[(size_t)l * CK * Cc + u] = (f16)w[(o * Cc + c) * KK + k];
        } else {
            int u = (b - 2304) * 256 + tid;   // < 73728
            int c = u & 255, j = (u >> 8) & 31, k = u >> 13;
            float v = (j < 18) ? wo[((size_t)j * Cc + c) * KK + k] : 0.f;
            woffT[(size_t)l * 9 * 32 * Cc + u] = (f16)v;
        }
    }
}

// FUSED: offset-conv (phase A) + deformable sampling + GEMM + ReLU (phase B).
// Block: 768 threads (12 waves), 256 out x 144 pix. Grid = 256 = 1 block/CU.
// Phase A (R24): SINGLE-buffer stage-then-reissue pipeline (the proven c4
// pattern): stage X (holds p+1, loaded a full phase earlier), then reload X
// for p+2. R23's two-buffer alternation desynchronized (staged stale data).
// Phase B: R20-proven deform loop; id/wv from LDS (s_id/s_wt).
__global__ __launch_bounds__(768, 3) void fused_layer_kernel(
    const f16* __restrict__ x16, const f16* __restrict__ wT2,
    const f16* __restrict__ woffT, const float* __restrict__ b_off,
    f16* __restrict__ o16, float* __restrict__ oN, int last)
{
    __shared__ __align__(16) f16 s_w[2][2][8192];  // 64KB  [buf][half][256o x 32c swz]
    __shared__ __align__(16) f16 s_s[2][2][4608];  // 36KB  [buf][half][144p x 32c swz]
    __shared__ __align__(16) f16 s_a[2][2][1024];  // 8KB   [buf][half][32r x 32c swz]
    __shared__ int4   s_id[9][144];                // 20.25KB
    __shared__ float4 s_wt[9][144];                // 20.25KB

    const int bid = blockIdx.x;
    const int swz = (bid & 7) * 32 + (bid >> 3); // 256 blocks, XCD-chunked
    const int p0 = swz * 144;                    // no image straddle
    const int imgb = (p0 / HW) * HW;
    const int tid = threadIdx.x, lane = tid & 63, wid = tid >> 6;
    const int wo = wid & 3, wp = wid >> 2;
    const bool sampler = (wid < 9);              // tids 0..575 <=> ps 0..143
    const int ps = tid >> 2, cg = tid & 3;
    const int qa = ((lane >> 4) ^ ((lane >> 1) & 3)) * 8;
    const int qs = (cg ^ ((ps >> 1) & 3)) * 8;
    const f16* xb = x16 + (size_t)imgb * Cc;
    const int wlo = (tid >> 2) * Cc + ((tid & 3) ^ ((tid >> 3) & 3)) * 8;
    const int wds = tid * 8;
    // sampler pixel coords (valid for tid<576)
    const int hwp = p0 + ps - imgb;
    const int hp = hwp / Wc, wp_ = hwp - hp * Wc;
    // phase-A A-stage mapping (tids 576..767; tids 576..639 take a 2nd slot)
    const int au0 = tid - 576;
    const int arow0 = au0 >> 3, acb0 = au0 & 7;
    const int ah0 = acb0 >> 2, aq0 = acb0 & 3;
    const int adst0 = arow0 * 32 + ((aq0 ^ ((arow0 >> 1) & 3)) * 8);
    const int arow1 = arow0 + 24;
    const int adst1 = arow1 * 32 + ((aq0 ^ ((arow1 >> 1) & 3)) * 8);

    // ================= PHASE A: offset conv =================
    {
        f32x4 accA[2];
        accA[0] = (f32x4){0.f, 0.f, 0.f, 0.f};
        accA[1] = (f32x4){0.f, 0.f, 0.f, 0.f};
        f16x8 X0, X1;           // single reg pipeline buffer (stage->reissue)

#define PA_LOAD(q) do {                                                        \
    int q_ = (q) > 35 ? 35 : (q);                                              \
    int k2_ = q_ >> 2, cq_ = q_ & 3;                                           \
    int ky_ = k2_ / 3, kx_ = k2_ - ky_ * 3;                                    \
    if (sampler) {                                                             \
        int yy_ = hp + ky_ - 1, xx_ = wp_ + kx_ - 1;                           \
        f16x8 t0_ = {0,0,0,0,0,0,0,0}, t1_ = {0,0,0,0,0,0,0,0};                \
        if (yy_ >= 0 && yy_ < Hc && xx_ >= 0 && xx_ < Wc) {                    \
            const f16* s_ = x16 + ((size_t)(imgb + yy_ * Wc + xx_)) * Cc + cq_ * 64 + cg * 8; \
            t0_ = *(const f16x8*)s_;                                           \
            t1_ = *(const f16x8*)(s_ + 32);                                    \
        }                                                                      \
        X0 = t0_; X1 = t1_;                                                    \
    } else {                                                                   \
        X0 = *(const f16x8*)(woffT + ((size_t)(k2_ * 32 + arow0)) * Cc + cq_ * 64 + acb0 * 8); \
        if (tid < 640)                                                         \
            X1 = *(const f16x8*)(woffT + ((size_t)(k2_ * 32 + arow1)) * Cc + cq_ * 64 + acb0 * 8); \
    }                                                                          \
} while (0)

#define PA_STAGE(nb) do {                                                      \
    if (sampler) {                                                             \
        *(f16x8*)&s_s[nb][0][ps * 32 + qs] = X0;                               \
        *(f16x8*)&s_s[nb][1][ps * 32 + qs] = X1;                               \
    } else {                                                                   \
        *(f16x8*)&s_a[nb][ah0][adst0] = X0;                                    \
        if (tid < 640) *(f16x8*)&s_a[nb][ah0][adst1] = X1;                     \
    }                                                                          \
} while (0)

        PA_LOAD(0);
        PA_STAGE(0);                       // waits phase-0 loads
        PA_LOAD(1);                        // reissue: phase 1 in flight
        asm volatile("s_waitcnt lgkmcnt(0)" ::: "memory"); SB();
        __builtin_amdgcn_s_barrier(); SB();

        for (int p = 0; p < 36; ++p) {
            const int bb = p & 1, nb = bb ^ 1;
            f16x8 af0, af1, bf0, bf1;
            if (sampler) {
                af0 = *(const f16x8*)&s_a[bb][0][((lane & 15)) * 32 + qa];
                af1 = *(const f16x8*)&s_a[bb][0][((16 + (lane & 15))) * 32 + qa];
                bf0 = *(const f16x8*)&s_s[bb][0][(wid * 16 + (lane & 15)) * 32 + qa];
            }
            // stage X (holds p+1, loaded one full phase ago), reload for p+2
            PA_STAGE(nb);
            PA_LOAD(p + 2);
            if (sampler) {
                accA[0] = __builtin_amdgcn_mfma_f32_16x16x32_f16(af0, bf0, accA[0], 0, 0, 0);
                accA[1] = __builtin_amdgcn_mfma_f32_16x16x32_f16(af1, bf0, accA[1], 0, 0, 0);
                af0 = *(const f16x8*)&s_a[bb][1][((lane & 15)) * 32 + qa];
                af1 = *(const f16x8*)&s_a[bb][1][((16 + (lane & 15))) * 32 + qa];
                bf1 = *(const f16x8*)&s_s[bb][1][(wid * 16 + (lane & 15)) * 32 + qa];
                accA[0] = __builtin_amdgcn_mfma_f32_16x16x32_f16(af0, bf1, accA[0], 0, 0, 0);
                accA[1] = __builtin_amdgcn_mfma_f32_16x16x32_f16(af1, bf1, accA[1], 0, 0, 0);
            }
            asm volatile("s_waitcnt lgkmcnt(0)" ::: "memory"); SB();
            __builtin_amdgcn_s_barrier(); SB();
        }

        // epilogue A: rows 4q..4q+3 -> taps 2q,2q+1 ; rows 16,17 (q==0) -> tap 8
        if (sampler) {
            const int q = lane >> 4;
            const int pxl = wid * 16 + (lane & 15);
            const int hwq = p0 + pxl - imgb;
            const int hq = hwq / Wc, wq = hwq - hq * Wc;
#define STORE_TAP_LDS(kk, offy, offx) do {                                     \
    float py_ = (float)(hq - 1 + (kk) / 3) + (offy);                           \
    float px_ = (float)(wq - 1 + (kk) % 3) + (offx);                           \
    float y0f_ = floorf(py_), x0f_ = floorf(px_);                              \
    float wy_ = py_ - y0f_, wx_ = px_ - x0f_;                                  \
    int iy0_ = (int)y0f_, ix0_ = (int)x0f_;                                    \
    float vy0_ = (y0f_ >= 0.f && y0f_ <= 95.f) ? 1.f : 0.f;                    \
    float vy1_ = (y0f_ + 1.f >= 0.f && y0f_ + 1.f <= 95.f) ? 1.f : 0.f;        \
    float vx0_ = (x0f_ >= 0.f && x0f_ <= 95.f) ? 1.f : 0.f;                    \
    float vx1_ = (x0f_ + 1.f >= 0.f && x0f_ + 1.f <= 95.f) ? 1.f : 0.f;        \
    int cy0_ = clampi(iy0_, 0, 95), cy1_ = clampi(iy0_ + 1, 0, 95);            \
    int cx0_ = clampi(ix0_, 0, 95), cx1_ = clampi(ix0_ + 1, 0, 95);            \
    s_id[kk][pxl] = make_int4(cy0_ * Wc + cx0_, cy0_ * Wc + cx1_,              \
                              cy1_ * Wc + cx0_, cy1_ * Wc + cx1_);             \
    s_wt[kk][pxl] = make_float4((1.f - wy_) * (1.f - wx_) * vy0_ * vx0_,       \
                                (1.f - wy_) * wx_ * vy0_ * vx1_,               \
                                wy_ * (1.f - wx_) * vy1_ * vx0_,               \
                                wy_ * wx_ * vy1_ * vx1_);                      \
} while (0)
            STORE_TAP_LDS(2 * q,     accA[0][0] + b_off[4 * q],
                                     accA[0][1] + b_off[4 * q + 1]);
            STORE_TAP_LDS(2 * q + 1, accA[0][2] + b_off[4 * q + 2],
                                     accA[0][3] + b_off[4 * q + 3]);
            if (q == 0)
                STORE_TAP_LDS(8, accA[1][0] + b_off[16], accA[1][1] + b_off[17]);
#undef STORE_TAP_LDS
        }
        asm volatile("s_waitcnt lgkmcnt(0)" ::: "memory"); SB();
        __builtin_amdgcn_s_barrier(); SB();
    }

    // ================= PHASE B: deform (R20-proven) =================
#define ISSUE_W(kt, cq, h, nb) do {                                            \
    const f16* g0_ = wT2 + wlo + ((size_t)((kt) * 256)) * Cc + (cq) * 64 + (h) * 32; \
    __builtin_amdgcn_global_load_lds(                                          \
        (const __attribute__((address_space(1))) void*)g0_,                    \
        (__attribute__((address_space(3))) void*)&s_w[nb][h][wds], 16, 0, 0);  \
    if (wid >= 8) {                                                            \
        const f16* g1_ = wT2 + wlo + ((size_t)((kt) * 256 + 64)) * Cc + (cq) * 64 + (h) * 32; \
        __builtin_amdgcn_global_load_lds(                                      \
            (const __attribute__((address_space(1))) void*)g1_,                \
            (__attribute__((address_space(3))) void*)&s_w[nb][h][2048 + wds], 16, 0, 0); \
    }                                                                          \
} while (0)

#define ISSUE_C(dst, idv, co) do {                                             \
    (dst)[0] = *(const f16x8*)(xb + (size_t)(idv).x * Cc + (co) + cg * 8);     \
    (dst)[1] = *(const f16x8*)(xb + (size_t)(idv).y * Cc + (co) + cg * 8);     \
    (dst)[2] = *(const f16x8*)(xb + (size_t)(idv).z * Cc + (co) + cg * 8);     \
    (dst)[3] = *(const f16x8*)(xb + (size_t)(idv).w * Cc + (co) + cg * 8);     \
} while (0)

#define BLEND_WRITE(src, wvv, h, nb) do {                                      \
    f16x8 sv_ = (src)[0] * (f16)(wvv).x + (src)[1] * (f16)(wvv).y              \
              + (src)[2] * (f16)(wvv).z + (src)[3] * (f16)(wvv).w;             \
    *(f16x8*)&s_s[nb][h][ps * 32 + qs] = sv_;                                  \
} while (0)

    f32x4 acc[4][3];
#pragma unroll
    for (int mi = 0; mi < 4; ++mi)
#pragma unroll
        for (int ni = 0; ni < 3; ++ni) acc[mi][ni] = (f32x4){0.f, 0.f, 0.f, 0.f};

    f16x8 c4a[4], c4b[4];
    int4 id;
    float4 wv;
    int4 idN;
    float4 wvN;
    if (sampler) {
        id = s_id[0][ps];
        wv = s_wt[0][ps];
    }

    ISSUE_W(0, 0, 0, 0);
    ISSUE_W(0, 0, 1, 0);
    SB();
    if (sampler) {
        ISSUE_C(c4a, id, 0);
        ISSUE_C(c4b, id, 32);
        BLEND_WRITE(c4a, wv, 0, 0);
        BLEND_WRITE(c4b, wv, 1, 0);
        ISSUE_C(c4a, id, 64);
        ISSUE_C(c4b, id, 96);
        asm volatile("s_waitcnt lgkmcnt(0)" ::: "memory"); SB();
        if (wid == 8) {
            asm volatile("s_waitcnt vmcnt(8)" ::: "memory"); SB();
        }
    } else {
        asm volatile("s_waitcnt vmcnt(0)" ::: "memory"); SB();
    }
    __builtin_amdgcn_s_barrier(); SB();

    for (int k = 0; k < 9; ++k) {
        const int kn = (k < 8) ? k + 1 : 8;
#pragma unroll
        for (int ch = 0; ch < 4; ++ch) {
            const int bb = ch & 1, nb = bb ^ 1;
            f16x8 bf0[3], bf1[3];
#pragma unroll
            for (int ni = 0; ni < 3; ++ni) {
                bf0[ni] = *(const f16x8*)&s_s[bb][0][(wp * 48 + ni * 16 + (lane & 15)) * 32 + qa];
                bf1[ni] = *(const f16x8*)&s_s[bb][1][(wp * 48 + ni * 16 + (lane & 15)) * 32 + qa];
            }
            if (sampler) {
                if (ch == 1) {             // LDS read; needed from ch2
                    idN = s_id[kn][ps];
                    wvN = s_wt[kn][ps];
                }
                ISSUE_W((ch == 3) ? kn : k, (ch + 1) & 3, 0, nb);
                ISSUE_W((ch == 3) ? kn : k, (ch + 1) & 3, 1, nb);
                SB();
                {
                    const float4 wvu = (ch == 3) ? wvN : wv;
                    const int4 idu = (ch >= 2) ? idN : id;
                    const int co2 = ((ch + 2) & 3) * 64;
                    BLEND_WRITE(c4a, wvu, 0, nb);
                    ISSUE_C(c4a, idu, co2);
                    BLEND_WRITE(c4b, wvu, 1, nb);
                    ISSUE_C(c4b, idu, co2 + 32);
                }
            } else {
                ISSUE_W((ch == 3) ? kn : k, (ch + 1) & 3, 0, nb);
                ISSUE_W((ch == 3) ? kn : k, (ch + 1) & 3, 1, nb);
                SB();
            }
#pragma unroll
            for (int mi = 0; mi < 4; ++mi) {
                f16x8 af = *(const f16x8*)&s_w[bb][0][(wo * 64 + mi * 16 + (lane & 15)) * 32 + qa];
#pragma unroll
                for (int ni = 0; ni < 3; ++ni)
                    acc[mi][ni] = __builtin_amdgcn_mfma_f32_16x16x32_f16(
                        af, bf0[ni], acc[mi][ni], 0, 0, 0);
            }
#pragma unroll
            for (int mi = 0; mi < 4; ++mi) {
                f16x8 af = *(const f16x8*)&s_w[bb][1][(wo * 64 + mi * 16 + (lane & 15)) * 32 + qa];
#pragma unroll
                for (int ni = 0; ni < 3; ++ni)
                    acc[mi][ni] = __builtin_amdgcn_mfma_f32_16x16x32_f16(
                        af, bf1[ni], acc[mi][ni], 0, 0, 0);
            }
            // RACE-FREE POINT: drain own ds_writes + own W-to-LDS before the
            // barrier. Waves 0-8: [W x1-2, C x8] -> vmcnt(8). 9-11: vmcnt(0).
            asm volatile("s_waitcnt lgkmcnt(0)" ::: "memory"); SB();
            if (sampler) {
                asm volatile("s_waitcnt vmcnt(8)" ::: "memory"); SB();
            } else {
                asm volatile("s_waitcnt vmcnt(0)" ::: "memory"); SB();
            }
            __builtin_amdgcn_s_barrier(); SB();
        }
        if (sampler) { id = idN; wv = wvN; }
    }

    // epilogue: ReLU; D row = output = (lane>>4)*4+j, col = pixel = lane&15
    if (!last) {
#pragma unroll
        for (int ni = 0; ni < 3; ++ni) {
            const int p = p0 + wp * 48 + ni * 16 + (lane & 15);
#pragma unroll
            for (int mi = 0; mi < 4; ++mi) {
                const int o0 = wo * 64 + mi * 16 + (lane >> 4) * 4;
                f32x4 v = acc[mi][ni];
                f16x4 h = {(f16)fmaxf(v[0], 0.f), (f16)fmaxf(v[1], 0.f),
                           (f16)fmaxf(v[2], 0.f), (f16)fmaxf(v[3], 0.f)};
                *(f16x4*)&o16[(size_t)p * Cc + o0] = h;
            }
        }
    } else {
        const int bimg = imgb / HW;
#pragma unroll
        for (int ni = 0; ni < 3; ++ni) {
            const int p = p0 + wp * 48 + ni * 16 + (lane & 15);
            const int hwl = p - imgb;
#pragma unroll
            for (int mi = 0; mi < 4; ++mi) {
                const int o0 = wo * 64 + mi * 16 + (lane >> 4) * 4;
#pragma unroll
                for (int j = 0; j < 4; ++j)
                    oN[((size_t)(bimg * Cc + o0 + j)) * HW + hwl] =
                        fmaxf(acc[mi][ni][j], 0.f);
            }
        }
    }
#undef ISSUE_W
#undef ISSUE_C
#undef BLEND_WRITE
#undef PA_LOAD
#undef PA_STAGE
}

extern "C" void kernel_launch(void* const* d_in, const int* in_sizes, int n_in,
                              void* d_out, int out_size, void* d_ws, size_t ws_size,
                              hipStream_t stream)
{
    const float* x0 = (const float*)d_in[0];
    float* out = (float*)d_out;

    f16*   x16a = (f16*)d_ws;                          // PIX*Cc f16
    f16*   x16b = x16a + (size_t)PIX * Cc;             // PIX*Cc f16
    f16*   wT2  = x16b + (size_t)PIX * Cc;             // 3 * CK*Cc f16
    f16*   woffT = wT2 + (size_t)3 * CK * Cc;          // 3 * 9*32*256 f16

    prep_all_kernel<<<2304 + 3 * 2592, 256, 0, stream>>>(
        x0,
        (const float*)d_in[3], (const float*)d_in[1],
        (const float*)d_in[6], (const float*)d_in[4],
        (const float*)d_in[9], (const float*)d_in[7],
        x16a, wT2, woffT);

    const f16* xin = x16a;
    for (int L = 0; L < 3; ++L) {
        const float* b_off = (const float*)d_in[2 + 3 * L];
        const int last = (L == 2);
        f16* xo = (L == 0) ? x16b : x16a;

        fused_layer_kernel<<<PIX / 144, 768, 0, stream>>>(
            xin, wT2 + (size_t)L * CK * Cc, woffT + (size_t)L * 9 * 32 * Cc,
            b_off, xo, out, last);

        xin = xo;
    }
}